// Round 12
// baseline (320.206 us; speedup 1.0000x reference)
//
#include <hip/hip_runtime.h>
#include <cstdint>
#include <cstddef>

typedef unsigned long long u64;
typedef unsigned int u32;
typedef unsigned short u16;
typedef unsigned char u8;

#define R_ANCH 96000
#define R4     24000 // R_ANCH / 4 (float4 units)
#define NIMG   8
#define KMIX   5
#define PRE    2000
#define POST   1000
#define NGT    32
#define NCHUNK 375   // R_ANCH / 256 (label/loss kernels)
#define ACHUNK 94    // ceil(R4 / 256) — kA main blocks (4 anchors/thread)
#define NBLK   48    // blocks per image for parallel scan kernels
#define MROW   2048  // maskLT row stride (padded PRE)
#define SCAP   16    // per-row suppressor-list capacity (overflow -> dense path)
#define BIG_TH 64    // kRank: bins larger than this get level-1 split
#define CAP_BIN 6144 // refinement trigger: crossing-bin count above this -> refine
#define CAND_CAP 8192// global/LDS candidate capacity (PRE-1 + CAP_BIN = 8143 max)
#define GC_STRIDE 16 // gcnt padding: 64 B per image

#define IMG_SZ        1280.0f
#define NMS_T         0.7f
#define SCALE_CLAMP_F 4.135166556742356f
#define HALF_L2PI     0.9189385332046727f

__device__ __forceinline__ u64 make_key(float s, int r) {
  u32 u = __float_as_uint(s);
  u = (u & 0x80000000u) ? ~u : (u | 0x80000000u);
  return ((u64)u << 32) | (u64)(0xFFFFFFFFu - (u32)r);
}

__device__ __forceinline__ float dec_score(u64 key) {
  u32 o = (u32)(key >> 32);
  u32 bits = (o & 0x80000000u) ? (o ^ 0x80000000u) : ~o;
  return __uint_as_float(bits);
}

// EXACT-PATH IoU (NMS only): must match reference bit-for-bit since NMS
// decisions select whole boxes. Label-path code uses division-free
// cross-multiplied compares (loss-only, high tolerance).
__device__ __forceinline__ float iou_pair(float a0,float a1,float a2,float a3,
                                          float b0,float b1,float b2,float b3) {
#pragma clang fp contract(off)
  float areaA = (a2-a0)*(a3-a1);
  float areaB = (b2-b0)*(b3-b1);
  float lx=fmaxf(a0,b0), ly=fmaxf(a1,b1);
  float rx=fminf(a2,b2), ry=fminf(a3,b3);
  float iw=fmaxf(rx-lx,0.0f), ih=fmaxf(ry-ly,0.0f);
  float inter=iw*ih;
  return inter / fmaxf(areaA+areaB-inter, 1e-9f);
}

// pick: from a 2048-bin histogram (bin d high = higher keys), find the bin
// containing the k-th largest key. 256 threads. s_i >= 8 ints, s_u >= 3 u32.
__device__ __forceinline__ void pick2048(const u32* __restrict__ hist, int k,
                                         int* s_i, u32* s_u,
                                         int& d_out, int& k_out, u32& cnt_out) {
  int tid = threadIdx.x;
  int lane = tid & 63, w = tid >> 6;
  u32 h[8]; u32 ssum = 0;
#pragma unroll
  for (int i=0;i<8;++i){ h[i] = hist[2047 - (tid*8 + i)]; ssum += h[i]; }
  u32 incl = ssum;
  for (int off=1; off<64; off<<=1){
    u32 t = (u32)__shfl_up((int)incl, off, 64);
    if (lane >= off) incl += t;
  }
  if (lane==63) s_i[w] = (int)incl;
  __syncthreads();
  u32 base = 0;
  for (int ww=0; ww<w; ++ww) base += (u32)s_i[ww];
  u32 run = base + incl - ssum;              // exclusive prefix (descending keys)
#pragma unroll
  for (int i=0;i<8;++i){
    u32 nr = run + h[i];
    if (run < (u32)k && nr >= (u32)k){       // unique crossing thread
      s_u[0] = (u32)(2047 - (tid*8+i));
      s_u[1] = (u32)k - run;
      s_u[2] = h[i];
    }
    run = nr;
  }
  __syncthreads();
  d_out = (int)s_u[0]; k_out = (int)s_u[1]; cnt_out = s_u[2];
  __syncthreads();
}

// descending exclusive prefix over 2048 bins, 1024 threads (2 bins/thread).
// Caller must __syncthreads() before (h ready) and after (off ready).
__device__ __forceinline__ void scan2048_desc(const u32* __restrict__ h,
                                              u32* __restrict__ off,
                                              u32* __restrict__ wsum, int tid) {
  int b_hi = 2047 - 2*tid, b_lo = b_hi - 1;
  u32 h_hi = h[b_hi], h_lo = h[b_lo];
  u32 sum = h_hi + h_lo;
  u32 incl = sum;
  int lane = tid & 63, wv = tid >> 6;
  for (int o=1; o<64; o<<=1){
    u32 t = (u32)__shfl_up((int)incl, o, 64);
    if (lane >= o) incl += t;
  }
  if (lane==63) wsum[wv] = incl;
  __syncthreads();
  u32 base = 0;
  for (int w=0; w<wv; ++w) base += wsum[w];
  u32 excl = base + incl - sum;
  off[b_hi] = excl;
  off[b_lo] = excl + h_hi;
}

// ---------------- zero: contiguous workspace region -----------------------
__global__ void kZero(u32* z, int nwords) {
  for (int i = blockIdx.x*256 + threadIdx.x; i < nwords; i += gridDim.x*256)
    z[i] = 0u;
}

// ---------------- A: MDN moments + hist0 — float4 (4 anchors/thread) ------
// R9 post-mortem: VGPR_Count=56 < the ~100 needed to keep 15 float4 loads
// live — compiler serialized loads (and likely spilled vmax[32] in the L1
// branch). Grid is only ~4.4 blocks/CU so high-occupancy reg cap buys
// nothing: __launch_bounds__(256,4) -> 128-VGPR cap, all 15 loads in
// flight, one waitcnt. Arithmetic unchanged.
// blocks [0, ACHUNK): main body; [ACHUNK, ACHUNK+NBLK): fused L1 best-gt.
__global__ __launch_bounds__(256, 4) void kA_mdn(
    const float* __restrict__ pi, const float* __restrict__ mu,
    const float* __restrict__ sigma, float* __restrict__ logits,
    float* __restrict__ epis, float* __restrict__ alea,
    u32* __restrict__ hist0,
    const float* __restrict__ anchors, const float* __restrict__ gt,
    int* __restrict__ best) {
  __shared__ u32 s_h[2048];
  __shared__ float s_gt[NGT*4];
  __shared__ float s_ga[NGT];
  __shared__ int s_best[NGT];
  int tid = threadIdx.x;
  int img = blockIdx.y;

  if (blockIdx.x >= ACHUNK) {
    // ---------------- fused L1 body (block-uniform branch) ----------------
    int bx = blockIdx.x - ACHUNK;
    if (tid < NGT*4) s_gt[tid] = gt[img*NGT*4 + tid];
    if (tid < NGT){
      const float* g4 = gt + img*NGT*4 + tid*4;
      s_ga[tid] = (g4[2]-g4[0])*(g4[3]-g4[1]);
      s_best[tid] = 0;
    }
    __syncthreads();
    float4 an[8]; float aA[8];
#pragma unroll
    for (int q=0; q<8; ++q){
      int r = bx*256 + tid + q*(NBLK*256);
      an[q] = (r < R_ANCH) ? ((const float4*)anchors)[r]
                           : make_float4(0.f,0.f,0.f,0.f);   // IoU=0, inert
      aA[q] = (an[q].z-an[q].x)*(an[q].w-an[q].y);
    }
    float vmax[NGT];
#pragma unroll 2
    for (int g=0; g<NGT; ++g){
      float g0=s_gt[g*4], g1=s_gt[g*4+1], g2=s_gt[g*4+2], g3=s_gt[g*4+3];
      float ga=s_ga[g];
      float bi=0.0f, bu=1.0f;               // v=0 baseline
#pragma unroll
      for (int q=0; q<8; ++q){
        float lx=fmaxf(g0,an[q].x), ly=fmaxf(g1,an[q].y);
        float rx=fminf(g2,an[q].z), ry=fminf(g3,an[q].w);
        float iw=fmaxf(rx-lx,0.0f), ih=fmaxf(ry-ly,0.0f);
        float inter=iw*ih;
        float uni=fmaxf(ga+aA[q]-inter,1e-9f);
        if (inter*bu > bi*uni){ bi=inter; bu=uni; }
      }
      vmax[g] = bi/bu;
    }
    int lane = tid & 63;
#pragma unroll
    for (int g=0; g<NGT; ++g){
      float v = vmax[g];
      v = fmaxf(v, __shfl_xor(v, 1, 64));
      v = fmaxf(v, __shfl_xor(v, 2, 64));
      v = fmaxf(v, __shfl_xor(v, 4, 64));
      v = fmaxf(v, __shfl_xor(v, 8, 64));
      v = fmaxf(v, __shfl_xor(v,16, 64));
      v = fmaxf(v, __shfl_xor(v,32, 64));
      if (lane==0 && v > 0.0f) atomicMax(&s_best[g], __float_as_int(v));
    }
    __syncthreads();
    if (tid < NGT) atomicMax(&best[img*NGT + tid], s_best[tid]);
    return;
  }

  // ---------------- main MDN body: 4 anchors per thread ----------------
  int r4 = blockIdx.x*256 + tid;             // float4 index within image
  bool act = (r4 < R4);
  for (int b=tid; b<2048; b+=256) s_h[b]=0u;
  float4 lg4, ep4, al4;
  u64 keys[4];
  if (act){
    const float4* pi4 = (const float4*)pi;
    const float4* mu4 = (const float4*)mu;
    const float4* sg4 = (const float4*)sigma;
    size_t base = (size_t)img*KMIX*R4 + r4;
    float4 p4[KMIX], m4[KMIX], s4[KMIX];
#pragma unroll
    for (int k=0;k<KMIX;k++){
      p4[k]=pi4[base+(size_t)k*R4];
      m4[k]=mu4[base+(size_t)k*R4];
      s4[k]=sg4[base+(size_t)k*R4];
    }
    float lg_[4], ep_[4], al_[4];
#pragma unroll
    for (int j=0;j<4;++j){
      float p[KMIX], m[KMIX], s[KMIX];
#pragma unroll
      for (int k=0;k<KMIX;k++){
        p[k] = (&p4[k].x)[j];
        m[k] = (&m4[k].x)[j];
        s[k] = (&s4[k].x)[j];
      }
      float mx = p[0];
#pragma unroll
      for (int k=1;k<KMIX;k++) mx = fmaxf(mx,p[k]);
      float e[KMIX]; float sum = 0.0f;
#pragma unroll
      for (int k=0;k<KMIX;k++){ e[k]=expf(p[k]-mx); sum += e[k]; }
      float w[KMIX]; float lg = 0.0f;
#pragma unroll
      for (int k=0;k<KMIX;k++){ w[k]=e[k]/sum; lg += w[k]*m[k]; }
      float ep = 0.0f, al = 0.0f;
#pragma unroll
      for (int k=0;k<KMIX;k++){ float d=m[k]-lg; ep += w[k]*d*d; al += w[k]*s[k]*s[k]; }
      lg_[j]=lg; ep_[j]=ep; al_[j]=al;
      keys[j] = make_key(lg, r4*4 + j);
    }
    lg4 = make_float4(lg_[0],lg_[1],lg_[2],lg_[3]);
    ep4 = make_float4(ep_[0],ep_[1],ep_[2],ep_[3]);
    al4 = make_float4(al_[0],al_[1],al_[2],al_[3]);
    size_t o4 = (size_t)img*R4 + r4;
    ((float4*)logits)[o4] = lg4;
    ((float4*)epis)[o4]   = ep4;
    ((float4*)alea)[o4]   = al4;
  }
  __syncthreads();                           // s_h zero complete
  if (act){
#pragma unroll
    for (int j=0;j<4;++j)
      atomicAdd(&s_h[(u32)(keys[j]>>53)], 1u);
  }
  __syncthreads();
  for (int b=tid; b<2048; b+=256){ u32 v=s_h[b]; if(v) atomicAdd(&hist0[img*2048+b], v); }
}

// ---------------- P1: refine level-1 histogram (rare: c0 > CAP_BIN) -------
__global__ __launch_bounds__(256) void kP1(const float* __restrict__ logits,
                                           const u32* __restrict__ hist0,
                                           u32* __restrict__ hist1) {
  __shared__ u32 s_h[2048];
  __shared__ int s_i[8]; __shared__ u32 s_u[3];
  int img = blockIdx.y, tid = threadIdx.x;
  int d0,k0; u32 c0;
  pick2048(hist0 + img*2048, PRE, s_i, s_u, d0,k0,c0);
  if (c0 <= CAP_BIN) return;                 // block-uniform (common case)
  for (int b=tid; b<2048; b+=256) s_h[b]=0u;
  __syncthreads();
  const float* sc = logits + (size_t)img*R_ANCH;
  for (int r = blockIdx.x*256 + tid; r < R_ANCH; r += NBLK*256){
    u64 key = make_key(sc[r], r);
    if ((int)(key>>53) == d0) atomicAdd(&s_h[(u32)(key>>42)&2047u], 1u);
  }
  __syncthreads();
  for (int b=tid; b<2048; b+=256){ u32 v=s_h[b]; if(v) atomicAdd(&hist1[img*2048+b], v); }
}

// ---------------- P2: refine level-2 histogram (essentially never) --------
__global__ __launch_bounds__(256) void kP2(const float* __restrict__ logits,
                                           const u32* __restrict__ hist0,
                                           const u32* __restrict__ hist1,
                                           u32* __restrict__ hist2) {
  __shared__ u32 s_h[2048];
  __shared__ int s_i[8]; __shared__ u32 s_u[3];
  int img = blockIdx.y, tid = threadIdx.x;
  int d0,k0; u32 c0;
  pick2048(hist0 + img*2048, PRE, s_i, s_u, d0,k0,c0);
  if (c0 <= CAP_BIN) return;
  int d1,k1; u32 c1;
  pick2048(hist1 + img*2048, k0, s_i, s_u, d1,k1,c1);
  if (c1 <= CAP_BIN) return;
  u64 p1 = ((u64)d0<<11) | (u64)d1;
  for (int b=tid; b<2048; b+=256) s_h[b]=0u;
  __syncthreads();
  const float* sc = logits + (size_t)img*R_ANCH;
  for (int r = blockIdx.x*256 + tid; r < R_ANCH; r += NBLK*256){
    u64 key = make_key(sc[r], r);
    if ((key>>42) == p1) atomicAdd(&s_h[(u32)(key>>31)&2047u], 1u);
  }
  __syncthreads();
  for (int b=tid; b<2048; b+=256){ u32 v=s_h[b]; if(v) atomicAdd(&hist2[img*2048+b], v); }
}

// ---------------- G: gather candidates, block-compacted (parallel) --------
__global__ __launch_bounds__(256) void kGather(const float* __restrict__ logits,
    const u32* __restrict__ hist0, const u32* __restrict__ hist1,
    const u32* __restrict__ hist2, u64* __restrict__ cand, u32* __restrict__ gcnt) {
  __shared__ int s_i[8]; __shared__ u32 s_u[3];
  __shared__ u64 s_cand[2048];               // 16 KB staging (block take <= 2048)
  __shared__ u32 s_cnt, s_base;
  int img = blockIdx.y, tid = threadIdx.x;
  if (tid==0) s_cnt = 0u;
  int d,kk; u32 c;
  pick2048(hist0 + img*2048, PRE, s_i, s_u, d,kk,c);   // has syncthreads
  u64 p = (u64)d; int L = 0;
  if (c > CAP_BIN){
    pick2048(hist1 + img*2048, kk, s_i, s_u, d,kk,c);
    p = (p<<11)|(u64)d; L = 1;
    if (c > CAP_BIN){
      pick2048(hist2 + img*2048, kk, s_i, s_u, d,kk,c);
      p = (p<<11)|(u64)d; L = 2;
    }
  }
  u64 T = p << (64 - 11*(L+1));              // total candidates <= 8143
  const float* sc = logits + (size_t)img*R_ANCH;
  int lane = tid & 63;
  for (int r = blockIdx.x*256 + tid; r < R_ANCH; r += NBLK*256){
    u64 key = make_key(sc[r], r);
    bool take = (key >= T);
    u64 b = __ballot(take);
    if (b){
      u32 base = 0;
      if (lane==0) base = atomicAdd(&s_cnt, (u32)__popcll(b));   // LDS atomic
      base = (u32)__shfl((int)base, 0, 64);
      if (take){
        u32 pos = base + (u32)__popcll(b & ((1ull<<lane)-1ull));
        if (pos < 2048u) s_cand[pos] = key;
        else {                               // correctness net (block take > 2048)
          u32 gp = atomicAdd(&gcnt[img*GC_STRIDE], 1u);
          if (gp < CAND_CAP) cand[(size_t)img*CAND_CAP + gp] = key;
        }
      }
    }
  }
  __syncthreads();
  u32 n = s_cnt < 2048u ? s_cnt : 2048u;
  if (tid==0) s_base = atomicAdd(&gcnt[img*GC_STRIDE], n);  // 1 atomic/block
  __syncthreads();
  u32 gb = s_base;
  for (u32 i=tid; i<n; i+=256)
    cand[(size_t)img*CAND_CAP + gb + i] = s_cand[i];
}

// ---------------- R: hierarchical exact bucket-rank + epilogue ------------
// Bins > BIG_TH members get a sequential level-1 split by digit1 (bits
// 52..42) -> sub-bins of ~1-3; compare loops trivial. Bins with base >= PRE
// pruned. Exact. Capacity 8192 (CAP_BIN=6144 + PRE-1 = 8143 max).
__global__ __launch_bounds__(1024) void kRank(
    const u64* __restrict__ cand, const u32* __restrict__ gcnt,
    const float* __restrict__ epis, const float* __restrict__ alea,
    const float* __restrict__ deltas, const float* __restrict__ anchors,
    float* __restrict__ tb, float* __restrict__ tu, float* __restrict__ ts) {
  __shared__ u64 s_key[CAND_CAP];            // 64 KB
  __shared__ u16 s_idx0[CAND_CAP];           // 16 KB
  __shared__ u16 s_idx1[CAND_CAP];           // 16 KB (per big bin, reused)
  __shared__ u32 s_h0[2048];                 // 8 KB
  __shared__ u32 s_off0[2048];               // 8 KB (excl; scatter makes base+size)
  __shared__ u32 s_h1[2048];                 // 8 KB
  __shared__ u32 s_off1[2048];               // 8 KB
  __shared__ u32 s_wsum[16];
  __shared__ u32 s_nbig;
  __shared__ u16 s_big[128];
  int tid = threadIdx.x, img = blockIdx.x;
  u32 cnt = gcnt[img*GC_STRIDE];
  if (cnt > (u32)CAND_CAP) cnt = CAND_CAP;
  const u64* cp = cand + (size_t)img*CAND_CAP;
  for (int i=tid; i<CAND_CAP; i+=1024) s_key[i] = (i < (int)cnt) ? cp[i] : 0ull;
  for (int b=tid; b<2048; b+=1024){ s_h0[b] = 0u; }
  if (tid==0) s_nbig = 0u;
  __syncthreads();
  for (int i=tid; i<(int)cnt; i+=1024)
    atomicAdd(&s_h0[(u32)(s_key[i]>>53)], 1u);
  __syncthreads();
  scan2048_desc(s_h0, s_off0, s_wsum, tid);
  __syncthreads();
  // collect big bins that can contribute ranks < PRE
  for (int b=tid; b<2048; b+=1024){
    u32 sz = s_h0[b];
    if (sz > BIG_TH && s_off0[b] < PRE){
      u32 q = atomicAdd(&s_nbig, 1u);
      if (q < 128u) s_big[q] = (u16)b;
    }
  }
  __syncthreads();                           // collect/scatter ordering
  // scatter candidates into digit0-bucket order
  for (int i=tid; i<(int)cnt; i+=1024){
    u32 d = (u32)(s_key[i]>>53);
    u32 slot = atomicAdd(&s_off0[d], 1u);    // post: s_off0[d] = base + size
    s_idx0[slot] = (u16)i;
  }
  __syncthreads();
  // epilogue writer
  auto emit = [&](u64 my, u32 rank){
    if (rank < PRE){
      int p = (int)rank;
      u32 idx = 0xFFFFFFFFu - (u32)(my & 0xFFFFFFFFull);
      ts[img*PRE + p] = dec_score(my);
      float4 a = ((const float4*)anchors)[idx];
      float4 dd = ((const float4*)deltas)[(size_t)img*R_ANCH + idx];
      float w = a.z - a.x, h = a.w - a.y;
      float cx = a.x + 0.5f*w, cy = a.y + 0.5f*h;
      float dw = fminf(dd.z, SCALE_CLAMP_F), dh = fminf(dd.w, SCALE_CLAMP_F);
      float pcx = dd.x*w + cx, pcy = dd.y*h + cy;
      float pw = expf(dw)*w, ph = expf(dh)*h;
      float x0 = fminf(fmaxf(pcx - 0.5f*pw, 0.0f), IMG_SZ);
      float y0 = fminf(fmaxf(pcy - 0.5f*ph, 0.0f), IMG_SZ);
      float x1 = fminf(fmaxf(pcx + 0.5f*pw, 0.0f), IMG_SZ);
      float y1 = fminf(fmaxf(pcy + 0.5f*ph, 0.0f), IMG_SZ);
      ((float4*)tb)[(size_t)img*PRE + p] = make_float4(x0,y0,x1,y1);
      size_t o = (size_t)img*R_ANCH + idx;
      ((float2*)tu)[(size_t)img*PRE + p] = make_float2(epis[o], alea[o]);
    }
  };
  // small bins: direct compare loop (size <= BIG_TH)
  for (int i=tid; i<(int)cnt; i+=1024){
    u64 my = s_key[i];
    u32 d = (u32)(my>>53);
    u32 size = s_h0[d];
    if (size > BIG_TH) continue;             // handled below
    u32 bs = s_off0[d] - size;
    if (bs >= PRE) continue;                 // cannot produce rank < PRE
    u32 rank = bs;
    for (u32 q=bs; q<bs+size; ++q)
      rank += (s_key[s_idx0[q]] > my) ? 1u : 0u;
    emit(my, rank);
  }
  __syncthreads();
  u32 nbig = s_nbig < 128u ? s_nbig : 128u;
  for (u32 bb=0; bb<nbig; ++bb){             // block-uniform sequential loop
    u32 B = s_big[bb];
    u32 size = s_h0[B];
    u32 base0 = s_off0[B] - size;
    for (int b=tid; b<2048; b+=1024) s_h1[b] = 0u;
    __syncthreads();
    for (u32 q=tid; q<size; q+=1024){
      u64 k = s_key[s_idx0[base0+q]];
      atomicAdd(&s_h1[(u32)(k>>42)&2047u], 1u);
    }
    __syncthreads();
    scan2048_desc(s_h1, s_off1, s_wsum, tid);
    __syncthreads();
    for (u32 q=tid; q<size; q+=1024){
      u16 ci = s_idx0[base0+q];
      u64 k = s_key[ci];
      u32 slot = atomicAdd(&s_off1[(u32)(k>>42)&2047u], 1u);
      s_idx1[slot] = ci;
    }
    __syncthreads();
    for (u32 q=tid; q<size; q+=1024){
      u16 ci = s_idx1[q];
      u64 my = s_key[ci];
      u32 d1 = (u32)(my>>42)&2047u;
      u32 ssz = s_h1[d1];
      u32 sbs = s_off1[d1] - ssz;            // sub-bin base (within bin)
      u32 rank = base0 + sbs;
      for (u32 t2=sbs; t2<sbs+ssz; ++t2)
        rank += (s_key[s_idx1[t2]] > my) ? 1u : 0u;
      emit(my, rank);
    }
    __syncthreads();                         // s_h1/s_off1/s_idx1 reuse
  }
}

// ---------------- D: masks + sparse suppressor lists (EXACT IoU) ----------
__global__ __launch_bounds__(1024) void kD_mask(const float* __restrict__ tb,
                                                u64* __restrict__ maskLT,
                                                u32* __restrict__ scnt,
                                                u16* __restrict__ slist) {
  __shared__ float4 s_tile[64];
  int tid = threadIdx.x;
  int a = blockIdx.x, img = blockIdx.y;
  const float4* tbi = (const float4*)tb + (size_t)img*PRE;
  if (tid < 64){
    int i = a*64 + tid;
    s_tile[tid] = (i < PRE) ? tbi[i] : make_float4(0.f,0.f,0.f,0.f);
  }
  __syncthreads();
  u64* outp = maskLT + ((size_t)img*32 + a)*MROW;
  u32* cnts = scnt + (size_t)img*2048;
  u16* lst  = slist + (size_t)img*2048*SCAP;
  int bmax = min(64, PRE - a*64);
  for (int j = a*64 + tid; j < MROW; j += 1024){
    u64 m = 0ull;
    if (j < PRE){
      float4 B = tbi[j];
      int blim = min(bmax, j - a*64);        // only b with a*64+b < j
      for (int b = 0; b < blim; ++b){
        float4 A = s_tile[b];
        float v = iou_pair(A.x,A.y,A.z,A.w, B.x,B.y,B.z,B.w);
        m |= (u64)(v > NMS_T) << b;
      }
    }
    outp[j] = m;
    u64 mm = m;
    while (mm){
      int b = __builtin_ctzll(mm); mm &= mm - 1ull;
      u32 slot = atomicAdd(&cnts[j], 1u);
      if (slot < SCAP) lst[(size_t)j*SCAP + slot] = (u16)(a*64 + b);
    }
  }
}

// ---------------- EF: greedy NMS fixpoint + final compaction + losses -----
__global__ __launch_bounds__(1024) void kEF_nms(const u64* __restrict__ maskLT,
    const u32* __restrict__ scnt, const u16* __restrict__ slist,
    const float* __restrict__ tb, const float* __restrict__ tu,
    const float* __restrict__ ts, const float* __restrict__ acc,
    float* __restrict__ out) {
  __shared__ u64 s_list64[2048*SCAP/4];      // 64 KB staged lists
  __shared__ u16 s_cnt[2048];                // 4 KB
  __shared__ u8  kbuf[2][2048];              // 4 KB
  __shared__ u64 s_kw[32];
  __shared__ int s_change, s_ovf;
  __shared__ int s_wk[16], s_wn[16];
  __shared__ int s_kc, s_runk, s_runn;
  int img = blockIdx.x, tid = threadIdx.x;
  int lane = tid & 63, wid = tid >> 6;
  const u64* gl = (const u64*)(slist + (size_t)img*2048*SCAP);
  for (int i=tid; i<2048*SCAP/4; i+=1024) s_list64[i] = gl[i];
  const u32* gc = scnt + (size_t)img*2048;
  for (int i=tid; i<2048; i+=1024) s_cnt[i] = (u16)gc[i];
  if (tid==0){ s_change = 0; s_ovf = 0; }
  __syncthreads();
  bool myovf = false;
#pragma unroll
  for (int q=0; q<2; ++q){
    int j = tid + q*1024;
    if (s_cnt[j] > SCAP) myovf = true;
    kbuf[0][j] = (j < PRE) ? 1 : 0;
  }
  if (myovf) s_ovf = 1;                      // benign race
  __syncthreads();
  const u64* MT = maskLT + (size_t)img*32*MROW;
  int cur = 0;
  for (int iter=0; iter<2048; ++iter){
    bool ovf = (s_ovf != 0);                 // stable after init barrier
    if (ovf && tid < 32){
      u64 w = 0ull;
      for (int b=0; b<64; ++b) w |= (u64)(kbuf[cur][tid*64+b] & 1) << b;
      s_kw[tid] = w;
    }
    __syncthreads();                         // A: s_change reset + kw visible
    bool changed = false;
#pragma unroll
    for (int q=0; q<2; ++q){
      int j = tid + q*1024;
      u8 old = kbuf[cur][j];
      u8 nk = (j < PRE) ? 1 : 0;
      if (nk){
        int cnt = s_cnt[j];
        if (cnt <= SCAP){
          const u16* lp = (const u16*)&s_list64[j*(SCAP/4)];
          for (int i=0; i<cnt; ++i){
            if (kbuf[cur][lp[i]]){ nk = 0; break; }
          }
        } else {
          int amax = j >> 6;
          for (int a=0; a<=amax; ++a){
            if (MT[(size_t)a*MROW + j] & s_kw[a]){ nk = 0; break; }
          }
        }
      }
      kbuf[1-cur][j] = nk;
      changed |= (nk != old);
    }
    if (changed) s_change = 1;
    __syncthreads();                         // B: all writes done
    int ch = s_change;
    __syncthreads();                         // C: all have read ch
    if (tid==0) s_change = 0;                // reset (visible by next A)
    if (!ch) break;                          // uniform
    cur ^= 1;
  }
  // ---- compaction (old kF), keep bits live in kbuf[cur] ----
  __syncthreads();
  const float4* tbi = (const float4*)tb + (size_t)img*PRE;
  const float NEG_INF = __uint_as_float(0xff800000u);
  u8* kf = kbuf[1-cur];                      // free buffer: keep&valid flags
#pragma unroll
  for (int cch=0; cch<2; ++cch){
    int pp = cch*1024 + tid;
    bool kp = false;
    if (pp < PRE && kbuf[cur][pp]){
      float4 b = tbi[pp];
      kp = (b.z > b.x) && (b.w > b.y);
    }
    kf[pp] = kp ? 1 : 0;
  }
  __syncthreads();
  {
    int cc = (int)kf[tid] + (int)kf[1024 + tid];
    for (int of=32; of>0; of>>=1) cc += __shfl_down(cc, of, 64);
    if (lane==0) s_wk[wid] = cc;
  }
  __syncthreads();
  if (tid==0){
    int t=0; for (int w=0; w<16; ++w) t += s_wk[w];
    s_kc = t; s_runk = 0; s_runn = 0;
  }
  __syncthreads();
  int kc = s_kc;
#pragma unroll
  for (int cch=0; cch<2; ++cch){
    int pp = cch*1024 + tid;
    bool kp = kf[pp] != 0;
    u64 bk = __ballot(kp), bn = __ballot(!kp);
    if (lane==0){ s_wk[wid]=__popcll(bk); s_wn[wid]=__popcll(bn); }
    __syncthreads();
    int pk = s_runk, pn = s_runn;
    for (int w=0; w<wid; ++w){ pk += s_wk[w]; pn += s_wn[w]; }
    u64 lm = (1ull<<lane) - 1ull;
    pk += __popcll(bk & lm);
    pn += __popcll(bn & lm);
    int slot = kp ? pk : (kc + pn);
    if (slot < POST && pp < PRE){
      ((float4*)out)[img*POST + slot] = tbi[pp];
      out[32000 + img*POST + slot] = kp ? ts[img*PRE + pp] : NEG_INF;
      ((float2*)(out + 40000))[img*POST + slot] = ((const float2*)tu)[(size_t)img*PRE + pp];
    }
    __syncthreads();
    if (tid==0){
      int tk=0, tn=0;
      for (int w=0; w<16; ++w){ tk += s_wk[w]; tn += s_wn[w]; }
      s_runk += tk; s_runn += tn;
    }
    __syncthreads();
  }
  if (img==0 && tid<2) out[56000+tid] = acc[tid] * (1.0f/2048.0f);
}

// ---------------- L2lite: labels (division-light) + chunk counts ----------
__global__ __launch_bounds__(256) void kL2_label(
    const float* __restrict__ anchors, const float* __restrict__ gt,
    const int* __restrict__ best,
    signed char* __restrict__ label, int* __restrict__ cpos, int* __restrict__ cneg) {
  __shared__ float s_gt[NGT*4];
  __shared__ float s_ga[NGT];
  __shared__ float s_bg[NGT];
  __shared__ int s_w[8];
  int tid = threadIdx.x, img = blockIdx.y;
  int r = blockIdx.x*256 + tid;
  if (tid < NGT*4) s_gt[tid] = gt[img*NGT*4 + tid];
  if (tid < NGT){
    const float* g4 = gt + img*NGT*4 + tid*4;
    s_ga[tid] = (g4[2]-g4[0])*(g4[3]-g4[1]);
    s_bg[tid] = __int_as_float(best[img*NGT + tid]);
  }
  __syncthreads();
  float4 a = ((const float4*)anchors)[r];
  float aA = (a.z-a.x)*(a.w-a.y);
  float bi=-1.0f, bu=1.0f; bool lq = false;
#pragma unroll 4
  for (int g=0; g<NGT; ++g){
    float g0=s_gt[g*4], g1=s_gt[g*4+1], g2=s_gt[g*4+2], g3=s_gt[g*4+3];
    float lx=fmaxf(g0,a.x), ly=fmaxf(g1,a.y);
    float rx=fminf(g2,a.z), ry=fminf(g3,a.w);
    float iw=fmaxf(rx-lx,0.0f), ih=fmaxf(ry-ly,0.0f);
    float inter=iw*ih;
    float uni = fmaxf(s_ga[g] + aA - inter, 1e-9f);
    if (inter*bu > bi*uni){ bi=inter; bu=uni; }
    float bg = s_bg[g];
    lq = lq || ((inter >= (bg - 1e-7f)*uni) && (bg > 0.0f));
  }
  float vbest = bi/bu;
  int lab = lq ? 1 : (vbest >= 0.7f ? 1 : (vbest >= 0.3f ? -1 : 0));
  label[(size_t)img*R_ANCH + r] = (signed char)lab;
  u64 bp = __ballot(lab==1), bn = __ballot(lab==0);
  int wid = tid>>6, lane = tid&63;
  if (lane==0){ s_w[wid*2]=__popcll(bp); s_w[wid*2+1]=__popcll(bn); }
  __syncthreads();
  if (tid==0){
    cpos[img*NCHUNK + blockIdx.x] = s_w[0]+s_w[2]+s_w[4]+s_w[6];
    cneg[img*NCHUNK + blockIdx.x] = s_w[1]+s_w[3]+s_w[5]+s_w[7];
  }
}

// ---------------- L4: quota sampling + ON-DEMAND loss for kept anchors ----
// NLL/loc computed only for the <=256 kept anchors per image (0.27% of the
// old full-grid cost). Arithmetic verbatim from the original kA body.
__global__ __launch_bounds__(256) void kL4_accum(
    const signed char* __restrict__ label,
    const float* __restrict__ pi, const float* __restrict__ mu,
    const float* __restrict__ sigma, const float* __restrict__ anchors,
    const float* __restrict__ gt, const float* __restrict__ deltas,
    const int* __restrict__ cpos, const int* __restrict__ cneg,
    float* __restrict__ acc) {
  __shared__ int s_wp[4], s_wn[4];
  __shared__ int s_r[12];
  __shared__ float s_red[8];
  __shared__ float s_gt[NGT*4];
  int tid = threadIdx.x, img = blockIdx.y, bx = blockIdx.x;
  int lane = tid & 63, wid = tid >> 6;
  if (tid < NGT*4) s_gt[tid] = gt[img*NGT*4 + tid];
  // inline prefix over chunks: vp/vn = counts before this chunk; tp = total pos
  int vp=0, vn=0, tp=0;
  for (int k=tid; k<NCHUNK; k+=256){
    int cp = cpos[img*NCHUNK + k];
    int cn = cneg[img*NCHUNK + k];
    tp += cp;
    if (k < bx){ vp += cp; vn += cn; }
  }
  for (int of=32; of>0; of>>=1){
    vp += __shfl_down(vp, of, 64);
    vn += __shfl_down(vn, of, 64);
    tp += __shfl_down(tp, of, 64);
  }
  if (lane==0){ s_r[wid]=vp; s_r[4+wid]=vn; s_r[8+wid]=tp; }
  __syncthreads();                           // also covers s_gt
  int pre_p = s_r[0]+s_r[1]+s_r[2]+s_r[3];
  int pre_n = s_r[4]+s_r[5]+s_r[6]+s_r[7];
  int totp  = s_r[8]+s_r[9]+s_r[10]+s_r[11];
  int np = totp < 128 ? totp : 128;
  int nn = 256 - np;
  int r = bx*256 + tid;
  size_t o = (size_t)img*R_ANCH + r;
  int lab = label[o];
  bool pos = (lab==1), neg = (lab==0);
  u64 bp = __ballot(pos), bn = __ballot(neg);
  if (lane==0){ s_wp[wid]=__popcll(bp); s_wn[wid]=__popcll(bn); }
  __syncthreads();
  for (int w=0; w<wid; ++w){ pre_p += s_wp[w]; pre_n += s_wn[w]; }
  u64 lm = (1ull<<lane) - 1ull;
  pre_p += __popcll(bp & lm);
  pre_n += __popcll(bn & lm);
  bool kp = pos && (pre_p < np);
  bool kn = neg && (pre_n < nn);
  float c_cls = 0.0f, c_loc = 0.0f;
  if (kp || kn){
    // ---- per-anchor best IoU (verbatim old-kA arithmetic) ----
    float4 a = ((const float4*)anchors)[r];
    float aA = (a.z-a.x)*(a.w-a.y);
    float bi = -1.0f, bu = 1.0f; int idx = 0;
#pragma unroll 4
    for (int g=0; g<NGT; ++g){
      float g0=s_gt[g*4], g1=s_gt[g*4+1], g2=s_gt[g*4+2], g3=s_gt[g*4+3];
      float ga=(g2-g0)*(g3-g1);
      float lx=fmaxf(g0,a.x), ly=fmaxf(g1,a.y);
      float rx=fminf(g2,a.z), ry=fminf(g3,a.w);
      float iw=fmaxf(rx-lx,0.0f), ih=fmaxf(ry-ly,0.0f);
      float inter=iw*ih;
      float uni = fmaxf(ga + aA - inter, 1e-9f);
      if (inter*bu > bi*uni){ bi=inter; bu=uni; idx=g; }
    }
    float vbest = bi/bu;
    // ---- NLL (verbatim old-kA arithmetic) ----
    size_t base = (size_t)img*KMIX*R_ANCH + r;
    float p[KMIX], m[KMIX], s[KMIX];
#pragma unroll
    for (int k=0;k<KMIX;k++){
      p[k]=pi[base+(size_t)k*R_ANCH];
      m[k]=mu[base+(size_t)k*R_ANCH];
      s[k]=sigma[base+(size_t)k*R_ANCH];
    }
    float mx = p[0];
#pragma unroll
    for (int k=1;k<KMIX;k++) mx = fmaxf(mx,p[k]);
    float e[KMIX]; float sum = 0.0f;
#pragma unroll
    for (int k=0;k<KMIX;k++){ e[k]=expf(p[k]-mx); sum += e[k]; }
    float lsum = logf(sum);
    float t_ = fminf(fmaxf(vbest, 0.0f), 1.0f);
    float comp[KMIX];
#pragma unroll
    for (int k=0;k<KMIX;k++){
      float z = (t_ - m[k]) / s[k];
      comp[k] = (p[k]-mx-lsum) - 0.5f*z*z - logf(s[k]) - HALF_L2PI;
    }
    float cm = comp[0];
#pragma unroll
    for (int k=1;k<KMIX;k++) cm = fmaxf(cm, comp[k]);
    float se = 0.0f;
#pragma unroll
    for (int k=0;k<KMIX;k++) se += expf(comp[k]-cm);
    c_cls = -(cm + logf(se));
    if (kp){
      // ---- loc L1 vs matched gt (verbatim old-kA arithmetic) ----
      const float* gb = &s_gt[idx*4];
      float sw = a.z-a.x, sh = a.w-a.y;
      float scx = a.x+0.5f*sw, scy = a.y+0.5f*sh;
      float tw = gb[2]-gb[0], th = gb[3]-gb[1];
      float tcx = gb[0]+0.5f*tw, tcy = gb[1]+0.5f*th;
      float4 d = ((const float4*)deltas)[(size_t)img*R_ANCH + r];
      c_loc = fabsf(d.x-(tcx-scx)/sw) + fabsf(d.y-(tcy-scy)/sh)
            + fabsf(d.z-logf(tw/sw)) + fabsf(d.w-logf(th/sh));
    }
  }
  for (int of=32; of>0; of>>=1){
    c_cls += __shfl_down(c_cls, of, 64);
    c_loc += __shfl_down(c_loc, of, 64);
  }
  if (lane==0){ s_red[wid]=c_cls; s_red[4+wid]=c_loc; }
  __syncthreads();
  if (tid==0){
    float a = s_red[0]+s_red[1]+s_red[2]+s_red[3];
    float b = s_red[4]+s_red[5]+s_red[6]+s_red[7];
    if (a != 0.0f) atomicAdd(&acc[0], a);
    if (b != 0.0f) atomicAdd(&acc[1], b);
  }
}

// ---------------- host-side launch ----------------------------------------
extern "C" void kernel_launch(void* const* d_in, const int* in_sizes, int n_in,
                              void* d_out, int out_size, void* d_ws, size_t ws_size,
                              hipStream_t stream) {
  const float* anchors = (const float*)d_in[0];
  const float* pi      = (const float*)d_in[1];
  const float* mu      = (const float*)d_in[2];
  const float* sigma   = (const float*)d_in[3];
  const float* deltas  = (const float*)d_in[4];
  const float* gt      = (const float*)d_in[5];
  float* out = (float*)d_out;

  char* ws = (char*)d_ws;
  size_t off = 0;
  auto alloc = [&](size_t bytes) -> void* {
    void* p = (void*)(ws + off);
    off += (bytes + 255) & ~(size_t)255;
    return p;
  };
  float* logits = (float*)alloc((size_t)NIMG*R_ANCH*4);
  float* epis   = (float*)alloc((size_t)NIMG*R_ANCH*4);
  float* alea   = (float*)alloc((size_t)NIMG*R_ANCH*4);
  float* tb     = (float*)alloc((size_t)NIMG*PRE*4*4);
  float* tu     = (float*)alloc((size_t)NIMG*PRE*2*4);
  float* ts     = (float*)alloc((size_t)NIMG*PRE*4);
  u64*   maskLT = (u64*)  alloc((size_t)NIMG*32*MROW*8);
  u16*   slist  = (u16*)  alloc((size_t)NIMG*2048*SCAP*2);
  u64*   cand   = (u64*)  alloc((size_t)NIMG*CAND_CAP*8);
  int*   cpos   = (int*)  alloc((size_t)NIMG*NCHUNK*4);
  int*   cneg   = (int*)  alloc((size_t)NIMG*NCHUNK*4);
  // ---- contiguous zero region ----
  size_t zstart = off;
  u32*   hist0  = (u32*)  alloc((size_t)NIMG*2048*4);
  u32*   hist1  = (u32*)  alloc((size_t)NIMG*2048*4);
  u32*   hist2  = (u32*)  alloc((size_t)NIMG*2048*4);
  u32*   gcnt   = (u32*)  alloc((size_t)NIMG*GC_STRIDE*4);
  int*   best   = (int*)  alloc((size_t)NIMG*NGT*4);
  u32*   scnt   = (u32*)  alloc((size_t)NIMG*2048*4);
  float* acc    = (float*)alloc(8);
  int zwords = (int)((off - zstart) / 4);
  // label aliases logits: logits last read in kGather; kL2 runs after it.
  signed char* label = (signed char*)logits;

  kZero<<<dim3(64), dim3(256), 0, stream>>>((u32*)(ws + zstart), zwords);
  kA_mdn<<<dim3(ACHUNK+NBLK, NIMG), dim3(256), 0, stream>>>(pi, mu, sigma, logits, epis, alea,
                                                            hist0, anchors, gt, best);
  kP1<<<dim3(NBLK, NIMG), dim3(256), 0, stream>>>(logits, hist0, hist1);
  kP2<<<dim3(NBLK, NIMG), dim3(256), 0, stream>>>(logits, hist0, hist1, hist2);
  kGather<<<dim3(NBLK, NIMG), dim3(256), 0, stream>>>(logits, hist0, hist1, hist2, cand, gcnt);
  kRank<<<dim3(NIMG), dim3(1024), 0, stream>>>(cand, gcnt, epis, alea, deltas, anchors, tb, tu, ts);
  kD_mask<<<dim3(32, NIMG), dim3(1024), 0, stream>>>(tb, maskLT, scnt, slist);
  kL2_label<<<dim3(NCHUNK, NIMG), dim3(256), 0, stream>>>(anchors, gt, best, label, cpos, cneg);
  kL4_accum<<<dim3(NCHUNK, NIMG), dim3(256), 0, stream>>>(label, pi, mu, sigma, anchors, gt, deltas,
                                                          cpos, cneg, acc);
  kEF_nms<<<dim3(NIMG), dim3(1024), 0, stream>>>(maskLT, scnt, slist, tb, tu, ts, acc, out);
}

// Round 15
// 269.822 us; speedup vs baseline: 1.1867x; 1.1867x over previous
//
#include <hip/hip_runtime.h>
#include <cstdint>
#include <cstddef>

typedef unsigned long long u64;
typedef unsigned int u32;
typedef unsigned short u16;
typedef unsigned char u8;

#define R_ANCH 96000
#define R4     24000 // R_ANCH / 4 (float4 units)
#define NIMG   8
#define KMIX   5
#define PRE    2000
#define POST   1000
#define NGT    32
#define NCHUNK 375   // R_ANCH / 256 (label/loss kernels)
#define ACHUNK 94    // ceil(R4 / 256) — kA main blocks (4 anchors/thread)
#define NBLK   48    // blocks per image for parallel scan kernels
#define MROW   2048  // maskLT row stride (padded PRE)
#define SCAP   16    // per-row suppressor-list capacity (overflow -> dense path)
#define BIG_TH 64    // kRank: bins larger than this get level-1 split
#define CAP_BIN 6144 // refinement trigger: crossing-bin count above this -> refine
#define CAND_CAP 8192// global/LDS candidate capacity (PRE-1 + CAP_BIN = 8143 max)
#define GC_STRIDE 16 // gcnt padding: 64 B per image

#define IMG_SZ        1280.0f
#define NMS_T         0.7f
#define SCALE_CLAMP_F 4.135166556742356f
#define HALF_L2PI     0.9189385332046727f

__device__ __forceinline__ u64 make_key(float s, int r) {
  u32 u = __float_as_uint(s);
  u = (u & 0x80000000u) ? ~u : (u | 0x80000000u);
  return ((u64)u << 32) | (u64)(0xFFFFFFFFu - (u32)r);
}

__device__ __forceinline__ float dec_score(u64 key) {
  u32 o = (u32)(key >> 32);
  u32 bits = (o & 0x80000000u) ? (o ^ 0x80000000u) : ~o;
  return __uint_as_float(bits);
}

// EXACT-PATH IoU (NMS only): must match reference bit-for-bit since NMS
// decisions select whole boxes. Label-path code uses division-free
// cross-multiplied compares (loss-only, high tolerance).
__device__ __forceinline__ float iou_pair(float a0,float a1,float a2,float a3,
                                          float b0,float b1,float b2,float b3) {
#pragma clang fp contract(off)
  float areaA = (a2-a0)*(a3-a1);
  float areaB = (b2-b0)*(b3-b1);
  float lx=fmaxf(a0,b0), ly=fmaxf(a1,b1);
  float rx=fminf(a2,b2), ry=fminf(a3,b3);
  float iw=fmaxf(rx-lx,0.0f), ih=fmaxf(ry-ly,0.0f);
  float inter=iw*ih;
  return inter / fmaxf(areaA+areaB-inter, 1e-9f);
}

// pick: from a 2048-bin histogram (bin d high = higher keys), find the bin
// containing the k-th largest key. 256 threads. s_i >= 8 ints, s_u >= 3 u32.
__device__ __forceinline__ void pick2048(const u32* __restrict__ hist, int k,
                                         int* s_i, u32* s_u,
                                         int& d_out, int& k_out, u32& cnt_out) {
  int tid = threadIdx.x;
  int lane = tid & 63, w = tid >> 6;
  u32 h[8]; u32 ssum = 0;
#pragma unroll
  for (int i=0;i<8;++i){ h[i] = hist[2047 - (tid*8 + i)]; ssum += h[i]; }
  u32 incl = ssum;
  for (int off=1; off<64; off<<=1){
    u32 t = (u32)__shfl_up((int)incl, off, 64);
    if (lane >= off) incl += t;
  }
  if (lane==63) s_i[w] = (int)incl;
  __syncthreads();
  u32 base = 0;
  for (int ww=0; ww<w; ++ww) base += (u32)s_i[ww];
  u32 run = base + incl - ssum;              // exclusive prefix (descending keys)
#pragma unroll
  for (int i=0;i<8;++i){
    u32 nr = run + h[i];
    if (run < (u32)k && nr >= (u32)k){       // unique crossing thread
      s_u[0] = (u32)(2047 - (tid*8+i));
      s_u[1] = (u32)k - run;
      s_u[2] = h[i];
    }
    run = nr;
  }
  __syncthreads();
  d_out = (int)s_u[0]; k_out = (int)s_u[1]; cnt_out = s_u[2];
  __syncthreads();
}

// descending exclusive prefix over 2048 bins, 1024 threads (2 bins/thread).
// Caller must __syncthreads() before (h ready) and after (off ready).
__device__ __forceinline__ void scan2048_desc(const u32* __restrict__ h,
                                              u32* __restrict__ off,
                                              u32* __restrict__ wsum, int tid) {
  int b_hi = 2047 - 2*tid, b_lo = b_hi - 1;
  u32 h_hi = h[b_hi], h_lo = h[b_lo];
  u32 sum = h_hi + h_lo;
  u32 incl = sum;
  int lane = tid & 63, wv = tid >> 6;
  for (int o=1; o<64; o<<=1){
    u32 t = (u32)__shfl_up((int)incl, o, 64);
    if (lane >= o) incl += t;
  }
  if (lane==63) wsum[wv] = incl;
  __syncthreads();
  u32 base = 0;
  for (int w=0; w<wv; ++w) base += wsum[w];
  u32 excl = base + incl - sum;
  off[b_hi] = excl;
  off[b_lo] = excl + h_hi;
}

// ---------------- zero: contiguous workspace region -----------------------
__global__ void kZero(u32* z, int nwords) {
  for (int i = blockIdx.x*256 + threadIdx.x; i < nwords; i += gridDim.x*256)
    z[i] = 0u;
}

// ---------------- A: MDN moments + hist0 — float4 (4 anchors/thread) ------
// R12 post-mortem: __launch_bounds__(256,4) backfired — allocator snapped
// to the 64-VGPR occupancy step and SPILLED (WRITE_SIZE 9.3->35.8 MB,
// kA 46->98 us). Revised: (256,2) caps at 256 VGPRs — room for the ~100-130
// actually needed (15 float4 loads + vmax[32]) without spilling; natural
// landing point is the 128-reg step = 4 waves/SIMD, matching the grid.
// blocks [0, ACHUNK): main body; [ACHUNK, ACHUNK+NBLK): fused L1 best-gt.
__global__ __launch_bounds__(256, 2) void kA_mdn(
    const float* __restrict__ pi, const float* __restrict__ mu,
    const float* __restrict__ sigma, float* __restrict__ logits,
    float* __restrict__ epis, float* __restrict__ alea,
    u32* __restrict__ hist0,
    const float* __restrict__ anchors, const float* __restrict__ gt,
    int* __restrict__ best) {
  __shared__ u32 s_h[2048];
  __shared__ float s_gt[NGT*4];
  __shared__ float s_ga[NGT];
  __shared__ int s_best[NGT];
  int tid = threadIdx.x;
  int img = blockIdx.y;

  if (blockIdx.x >= ACHUNK) {
    // ---------------- fused L1 body (block-uniform branch) ----------------
    int bx = blockIdx.x - ACHUNK;
    if (tid < NGT*4) s_gt[tid] = gt[img*NGT*4 + tid];
    if (tid < NGT){
      const float* g4 = gt + img*NGT*4 + tid*4;
      s_ga[tid] = (g4[2]-g4[0])*(g4[3]-g4[1]);
      s_best[tid] = 0;
    }
    __syncthreads();
    float4 an[8]; float aA[8];
#pragma unroll
    for (int q=0; q<8; ++q){
      int r = bx*256 + tid + q*(NBLK*256);
      an[q] = (r < R_ANCH) ? ((const float4*)anchors)[r]
                           : make_float4(0.f,0.f,0.f,0.f);   // IoU=0, inert
      aA[q] = (an[q].z-an[q].x)*(an[q].w-an[q].y);
    }
    float vmax[NGT];
#pragma unroll 2
    for (int g=0; g<NGT; ++g){
      float g0=s_gt[g*4], g1=s_gt[g*4+1], g2=s_gt[g*4+2], g3=s_gt[g*4+3];
      float ga=s_ga[g];
      float bi=0.0f, bu=1.0f;               // v=0 baseline
#pragma unroll
      for (int q=0; q<8; ++q){
        float lx=fmaxf(g0,an[q].x), ly=fmaxf(g1,an[q].y);
        float rx=fminf(g2,an[q].z), ry=fminf(g3,an[q].w);
        float iw=fmaxf(rx-lx,0.0f), ih=fmaxf(ry-ly,0.0f);
        float inter=iw*ih;
        float uni=fmaxf(ga+aA[q]-inter,1e-9f);
        if (inter*bu > bi*uni){ bi=inter; bu=uni; }
      }
      vmax[g] = bi/bu;
    }
    int lane = tid & 63;
#pragma unroll
    for (int g=0; g<NGT; ++g){
      float v = vmax[g];
      v = fmaxf(v, __shfl_xor(v, 1, 64));
      v = fmaxf(v, __shfl_xor(v, 2, 64));
      v = fmaxf(v, __shfl_xor(v, 4, 64));
      v = fmaxf(v, __shfl_xor(v, 8, 64));
      v = fmaxf(v, __shfl_xor(v,16, 64));
      v = fmaxf(v, __shfl_xor(v,32, 64));
      if (lane==0 && v > 0.0f) atomicMax(&s_best[g], __float_as_int(v));
    }
    __syncthreads();
    if (tid < NGT) atomicMax(&best[img*NGT + tid], s_best[tid]);
    return;
  }

  // ---------------- main MDN body: 4 anchors per thread ----------------
  int r4 = blockIdx.x*256 + tid;             // float4 index within image
  bool act = (r4 < R4);
  for (int b=tid; b<2048; b+=256) s_h[b]=0u;
  float4 lg4, ep4, al4;
  u64 keys[4];
  if (act){
    const float4* pi4 = (const float4*)pi;
    const float4* mu4 = (const float4*)mu;
    const float4* sg4 = (const float4*)sigma;
    size_t base = (size_t)img*KMIX*R4 + r4;
    float4 p4[KMIX], m4[KMIX], s4[KMIX];
#pragma unroll
    for (int k=0;k<KMIX;k++){
      p4[k]=pi4[base+(size_t)k*R4];
      m4[k]=mu4[base+(size_t)k*R4];
      s4[k]=sg4[base+(size_t)k*R4];
    }
    float lg_[4], ep_[4], al_[4];
#pragma unroll
    for (int j=0;j<4;++j){
      float p[KMIX], m[KMIX], s[KMIX];
#pragma unroll
      for (int k=0;k<KMIX;k++){
        p[k] = (&p4[k].x)[j];
        m[k] = (&m4[k].x)[j];
        s[k] = (&s4[k].x)[j];
      }
      float mx = p[0];
#pragma unroll
      for (int k=1;k<KMIX;k++) mx = fmaxf(mx,p[k]);
      float e[KMIX]; float sum = 0.0f;
#pragma unroll
      for (int k=0;k<KMIX;k++){ e[k]=expf(p[k]-mx); sum += e[k]; }
      float w[KMIX]; float lg = 0.0f;
#pragma unroll
      for (int k=0;k<KMIX;k++){ w[k]=e[k]/sum; lg += w[k]*m[k]; }
      float ep = 0.0f, al = 0.0f;
#pragma unroll
      for (int k=0;k<KMIX;k++){ float d=m[k]-lg; ep += w[k]*d*d; al += w[k]*s[k]*s[k]; }
      lg_[j]=lg; ep_[j]=ep; al_[j]=al;
      keys[j] = make_key(lg, r4*4 + j);
    }
    lg4 = make_float4(lg_[0],lg_[1],lg_[2],lg_[3]);
    ep4 = make_float4(ep_[0],ep_[1],ep_[2],ep_[3]);
    al4 = make_float4(al_[0],al_[1],al_[2],al_[3]);
    size_t o4 = (size_t)img*R4 + r4;
    ((float4*)logits)[o4] = lg4;
    ((float4*)epis)[o4]   = ep4;
    ((float4*)alea)[o4]   = al4;
  }
  __syncthreads();                           // s_h zero complete
  if (act){
#pragma unroll
    for (int j=0;j<4;++j)
      atomicAdd(&s_h[(u32)(keys[j]>>53)], 1u);
  }
  __syncthreads();
  for (int b=tid; b<2048; b+=256){ u32 v=s_h[b]; if(v) atomicAdd(&hist0[img*2048+b], v); }
}

// ---------------- P1: refine level-1 histogram (rare: c0 > CAP_BIN) -------
__global__ __launch_bounds__(256) void kP1(const float* __restrict__ logits,
                                           const u32* __restrict__ hist0,
                                           u32* __restrict__ hist1) {
  __shared__ u32 s_h[2048];
  __shared__ int s_i[8]; __shared__ u32 s_u[3];
  int img = blockIdx.y, tid = threadIdx.x;
  int d0,k0; u32 c0;
  pick2048(hist0 + img*2048, PRE, s_i, s_u, d0,k0,c0);
  if (c0 <= CAP_BIN) return;                 // block-uniform (common case)
  for (int b=tid; b<2048; b+=256) s_h[b]=0u;
  __syncthreads();
  const float* sc = logits + (size_t)img*R_ANCH;
  for (int r = blockIdx.x*256 + tid; r < R_ANCH; r += NBLK*256){
    u64 key = make_key(sc[r], r);
    if ((int)(key>>53) == d0) atomicAdd(&s_h[(u32)(key>>42)&2047u], 1u);
  }
  __syncthreads();
  for (int b=tid; b<2048; b+=256){ u32 v=s_h[b]; if(v) atomicAdd(&hist1[img*2048+b], v); }
}

// ---------------- P2: refine level-2 histogram (essentially never) --------
__global__ __launch_bounds__(256) void kP2(const float* __restrict__ logits,
                                           const u32* __restrict__ hist0,
                                           const u32* __restrict__ hist1,
                                           u32* __restrict__ hist2) {
  __shared__ u32 s_h[2048];
  __shared__ int s_i[8]; __shared__ u32 s_u[3];
  int img = blockIdx.y, tid = threadIdx.x;
  int d0,k0; u32 c0;
  pick2048(hist0 + img*2048, PRE, s_i, s_u, d0,k0,c0);
  if (c0 <= CAP_BIN) return;
  int d1,k1; u32 c1;
  pick2048(hist1 + img*2048, k0, s_i, s_u, d1,k1,c1);
  if (c1 <= CAP_BIN) return;
  u64 p1 = ((u64)d0<<11) | (u64)d1;
  for (int b=tid; b<2048; b+=256) s_h[b]=0u;
  __syncthreads();
  const float* sc = logits + (size_t)img*R_ANCH;
  for (int r = blockIdx.x*256 + tid; r < R_ANCH; r += NBLK*256){
    u64 key = make_key(sc[r], r);
    if ((key>>42) == p1) atomicAdd(&s_h[(u32)(key>>31)&2047u], 1u);
  }
  __syncthreads();
  for (int b=tid; b<2048; b+=256){ u32 v=s_h[b]; if(v) atomicAdd(&hist2[img*2048+b], v); }
}

// ---------------- G: gather candidates, block-compacted (parallel) --------
__global__ __launch_bounds__(256) void kGather(const float* __restrict__ logits,
    const u32* __restrict__ hist0, const u32* __restrict__ hist1,
    const u32* __restrict__ hist2, u64* __restrict__ cand, u32* __restrict__ gcnt) {
  __shared__ int s_i[8]; __shared__ u32 s_u[3];
  __shared__ u64 s_cand[2048];               // 16 KB staging (block take <= 2048)
  __shared__ u32 s_cnt, s_base;
  int img = blockIdx.y, tid = threadIdx.x;
  if (tid==0) s_cnt = 0u;
  int d,kk; u32 c;
  pick2048(hist0 + img*2048, PRE, s_i, s_u, d,kk,c);   // has syncthreads
  u64 p = (u64)d; int L = 0;
  if (c > CAP_BIN){
    pick2048(hist1 + img*2048, kk, s_i, s_u, d,kk,c);
    p = (p<<11)|(u64)d; L = 1;
    if (c > CAP_BIN){
      pick2048(hist2 + img*2048, kk, s_i, s_u, d,kk,c);
      p = (p<<11)|(u64)d; L = 2;
    }
  }
  u64 T = p << (64 - 11*(L+1));              // total candidates <= 8143
  const float* sc = logits + (size_t)img*R_ANCH;
  int lane = tid & 63;
  for (int r = blockIdx.x*256 + tid; r < R_ANCH; r += NBLK*256){
    u64 key = make_key(sc[r], r);
    bool take = (key >= T);
    u64 b = __ballot(take);
    if (b){
      u32 base = 0;
      if (lane==0) base = atomicAdd(&s_cnt, (u32)__popcll(b));   // LDS atomic
      base = (u32)__shfl((int)base, 0, 64);
      if (take){
        u32 pos = base + (u32)__popcll(b & ((1ull<<lane)-1ull));
        if (pos < 2048u) s_cand[pos] = key;
        else {                               // correctness net (block take > 2048)
          u32 gp = atomicAdd(&gcnt[img*GC_STRIDE], 1u);
          if (gp < CAND_CAP) cand[(size_t)img*CAND_CAP + gp] = key;
        }
      }
    }
  }
  __syncthreads();
  u32 n = s_cnt < 2048u ? s_cnt : 2048u;
  if (tid==0) s_base = atomicAdd(&gcnt[img*GC_STRIDE], n);  // 1 atomic/block
  __syncthreads();
  u32 gb = s_base;
  for (u32 i=tid; i<n; i+=256)
    cand[(size_t)img*CAND_CAP + gb + i] = s_cand[i];
}

// ---------------- R: hierarchical exact bucket-rank + epilogue ------------
// Bins > BIG_TH members get a sequential level-1 split by digit1 (bits
// 52..42) -> sub-bins of ~1-3; compare loops trivial. Bins with base >= PRE
// pruned. Exact. Capacity 8192 (CAP_BIN=6144 + PRE-1 = 8143 max).
__global__ __launch_bounds__(1024) void kRank(
    const u64* __restrict__ cand, const u32* __restrict__ gcnt,
    const float* __restrict__ epis, const float* __restrict__ alea,
    const float* __restrict__ deltas, const float* __restrict__ anchors,
    float* __restrict__ tb, float* __restrict__ tu, float* __restrict__ ts) {
  __shared__ u64 s_key[CAND_CAP];            // 64 KB
  __shared__ u16 s_idx0[CAND_CAP];           // 16 KB
  __shared__ u16 s_idx1[CAND_CAP];           // 16 KB (per big bin, reused)
  __shared__ u32 s_h0[2048];                 // 8 KB
  __shared__ u32 s_off0[2048];               // 8 KB (excl; scatter makes base+size)
  __shared__ u32 s_h1[2048];                 // 8 KB
  __shared__ u32 s_off1[2048];               // 8 KB
  __shared__ u32 s_wsum[16];
  __shared__ u32 s_nbig;
  __shared__ u16 s_big[128];
  int tid = threadIdx.x, img = blockIdx.x;
  u32 cnt = gcnt[img*GC_STRIDE];
  if (cnt > (u32)CAND_CAP) cnt = CAND_CAP;
  const u64* cp = cand + (size_t)img*CAND_CAP;
  for (int i=tid; i<CAND_CAP; i+=1024) s_key[i] = (i < (int)cnt) ? cp[i] : 0ull;
  for (int b=tid; b<2048; b+=1024){ s_h0[b] = 0u; }
  if (tid==0) s_nbig = 0u;
  __syncthreads();
  for (int i=tid; i<(int)cnt; i+=1024)
    atomicAdd(&s_h0[(u32)(s_key[i]>>53)], 1u);
  __syncthreads();
  scan2048_desc(s_h0, s_off0, s_wsum, tid);
  __syncthreads();
  // collect big bins that can contribute ranks < PRE
  for (int b=tid; b<2048; b+=1024){
    u32 sz = s_h0[b];
    if (sz > BIG_TH && s_off0[b] < PRE){
      u32 q = atomicAdd(&s_nbig, 1u);
      if (q < 128u) s_big[q] = (u16)b;
    }
  }
  __syncthreads();                           // collect/scatter ordering
  // scatter candidates into digit0-bucket order
  for (int i=tid; i<(int)cnt; i+=1024){
    u32 d = (u32)(s_key[i]>>53);
    u32 slot = atomicAdd(&s_off0[d], 1u);    // post: s_off0[d] = base + size
    s_idx0[slot] = (u16)i;
  }
  __syncthreads();
  // epilogue writer
  auto emit = [&](u64 my, u32 rank){
    if (rank < PRE){
      int p = (int)rank;
      u32 idx = 0xFFFFFFFFu - (u32)(my & 0xFFFFFFFFull);
      ts[img*PRE + p] = dec_score(my);
      float4 a = ((const float4*)anchors)[idx];
      float4 dd = ((const float4*)deltas)[(size_t)img*R_ANCH + idx];
      float w = a.z - a.x, h = a.w - a.y;
      float cx = a.x + 0.5f*w, cy = a.y + 0.5f*h;
      float dw = fminf(dd.z, SCALE_CLAMP_F), dh = fminf(dd.w, SCALE_CLAMP_F);
      float pcx = dd.x*w + cx, pcy = dd.y*h + cy;
      float pw = expf(dw)*w, ph = expf(dh)*h;
      float x0 = fminf(fmaxf(pcx - 0.5f*pw, 0.0f), IMG_SZ);
      float y0 = fminf(fmaxf(pcy - 0.5f*ph, 0.0f), IMG_SZ);
      float x1 = fminf(fmaxf(pcx + 0.5f*pw, 0.0f), IMG_SZ);
      float y1 = fminf(fmaxf(pcy + 0.5f*ph, 0.0f), IMG_SZ);
      ((float4*)tb)[(size_t)img*PRE + p] = make_float4(x0,y0,x1,y1);
      size_t o = (size_t)img*R_ANCH + idx;
      ((float2*)tu)[(size_t)img*PRE + p] = make_float2(epis[o], alea[o]);
    }
  };
  // small bins: direct compare loop (size <= BIG_TH)
  for (int i=tid; i<(int)cnt; i+=1024){
    u64 my = s_key[i];
    u32 d = (u32)(my>>53);
    u32 size = s_h0[d];
    if (size > BIG_TH) continue;             // handled below
    u32 bs = s_off0[d] - size;
    if (bs >= PRE) continue;                 // cannot produce rank < PRE
    u32 rank = bs;
    for (u32 q=bs; q<bs+size; ++q)
      rank += (s_key[s_idx0[q]] > my) ? 1u : 0u;
    emit(my, rank);
  }
  __syncthreads();
  u32 nbig = s_nbig < 128u ? s_nbig : 128u;
  for (u32 bb=0; bb<nbig; ++bb){             // block-uniform sequential loop
    u32 B = s_big[bb];
    u32 size = s_h0[B];
    u32 base0 = s_off0[B] - size;
    for (int b=tid; b<2048; b+=1024) s_h1[b] = 0u;
    __syncthreads();
    for (u32 q=tid; q<size; q+=1024){
      u64 k = s_key[s_idx0[base0+q]];
      atomicAdd(&s_h1[(u32)(k>>42)&2047u], 1u);
    }
    __syncthreads();
    scan2048_desc(s_h1, s_off1, s_wsum, tid);
    __syncthreads();
    for (u32 q=tid; q<size; q+=1024){
      u16 ci = s_idx0[base0+q];
      u64 k = s_key[ci];
      u32 slot = atomicAdd(&s_off1[(u32)(k>>42)&2047u], 1u);
      s_idx1[slot] = ci;
    }
    __syncthreads();
    for (u32 q=tid; q<size; q+=1024){
      u16 ci = s_idx1[q];
      u64 my = s_key[ci];
      u32 d1 = (u32)(my>>42)&2047u;
      u32 ssz = s_h1[d1];
      u32 sbs = s_off1[d1] - ssz;            // sub-bin base (within bin)
      u32 rank = base0 + sbs;
      for (u32 t2=sbs; t2<sbs+ssz; ++t2)
        rank += (s_key[s_idx1[t2]] > my) ? 1u : 0u;
      emit(my, rank);
    }
    __syncthreads();                         // s_h1/s_off1/s_idx1 reuse
  }
}

// ---------------- D: masks + sparse suppressor lists (EXACT IoU) ----------
__global__ __launch_bounds__(1024) void kD_mask(const float* __restrict__ tb,
                                                u64* __restrict__ maskLT,
                                                u32* __restrict__ scnt,
                                                u16* __restrict__ slist) {
  __shared__ float4 s_tile[64];
  int tid = threadIdx.x;
  int a = blockIdx.x, img = blockIdx.y;
  const float4* tbi = (const float4*)tb + (size_t)img*PRE;
  if (tid < 64){
    int i = a*64 + tid;
    s_tile[tid] = (i < PRE) ? tbi[i] : make_float4(0.f,0.f,0.f,0.f);
  }
  __syncthreads();
  u64* outp = maskLT + ((size_t)img*32 + a)*MROW;
  u32* cnts = scnt + (size_t)img*2048;
  u16* lst  = slist + (size_t)img*2048*SCAP;
  int bmax = min(64, PRE - a*64);
  for (int j = a*64 + tid; j < MROW; j += 1024){
    u64 m = 0ull;
    if (j < PRE){
      float4 B = tbi[j];
      int blim = min(bmax, j - a*64);        // only b with a*64+b < j
      for (int b = 0; b < blim; ++b){
        float4 A = s_tile[b];
        float v = iou_pair(A.x,A.y,A.z,A.w, B.x,B.y,B.z,B.w);
        m |= (u64)(v > NMS_T) << b;
      }
    }
    outp[j] = m;
    u64 mm = m;
    while (mm){
      int b = __builtin_ctzll(mm); mm &= mm - 1ull;
      u32 slot = atomicAdd(&cnts[j], 1u);
      if (slot < SCAP) lst[(size_t)j*SCAP + slot] = (u16)(a*64 + b);
    }
  }
}

// ---------------- EF: greedy NMS fixpoint + final compaction + losses -----
__global__ __launch_bounds__(1024) void kEF_nms(const u64* __restrict__ maskLT,
    const u32* __restrict__ scnt, const u16* __restrict__ slist,
    const float* __restrict__ tb, const float* __restrict__ tu,
    const float* __restrict__ ts, const float* __restrict__ acc,
    float* __restrict__ out) {
  __shared__ u64 s_list64[2048*SCAP/4];      // 64 KB staged lists
  __shared__ u16 s_cnt[2048];                // 4 KB
  __shared__ u8  kbuf[2][2048];              // 4 KB
  __shared__ u64 s_kw[32];
  __shared__ int s_change, s_ovf;
  __shared__ int s_wk[16], s_wn[16];
  __shared__ int s_kc, s_runk, s_runn;
  int img = blockIdx.x, tid = threadIdx.x;
  int lane = tid & 63, wid = tid >> 6;
  const u64* gl = (const u64*)(slist + (size_t)img*2048*SCAP);
  for (int i=tid; i<2048*SCAP/4; i+=1024) s_list64[i] = gl[i];
  const u32* gc = scnt + (size_t)img*2048;
  for (int i=tid; i<2048; i+=1024) s_cnt[i] = (u16)gc[i];
  if (tid==0){ s_change = 0; s_ovf = 0; }
  __syncthreads();
  bool myovf = false;
#pragma unroll
  for (int q=0; q<2; ++q){
    int j = tid + q*1024;
    if (s_cnt[j] > SCAP) myovf = true;
    kbuf[0][j] = (j < PRE) ? 1 : 0;
  }
  if (myovf) s_ovf = 1;                      // benign race
  __syncthreads();
  const u64* MT = maskLT + (size_t)img*32*MROW;
  int cur = 0;
  for (int iter=0; iter<2048; ++iter){
    bool ovf = (s_ovf != 0);                 // stable after init barrier
    if (ovf && tid < 32){
      u64 w = 0ull;
      for (int b=0; b<64; ++b) w |= (u64)(kbuf[cur][tid*64+b] & 1) << b;
      s_kw[tid] = w;
    }
    __syncthreads();                         // A: s_change reset + kw visible
    bool changed = false;
#pragma unroll
    for (int q=0; q<2; ++q){
      int j = tid + q*1024;
      u8 old = kbuf[cur][j];
      u8 nk = (j < PRE) ? 1 : 0;
      if (nk){
        int cnt = s_cnt[j];
        if (cnt <= SCAP){
          const u16* lp = (const u16*)&s_list64[j*(SCAP/4)];
          for (int i=0; i<cnt; ++i){
            if (kbuf[cur][lp[i]]){ nk = 0; break; }
          }
        } else {
          int amax = j >> 6;
          for (int a=0; a<=amax; ++a){
            if (MT[(size_t)a*MROW + j] & s_kw[a]){ nk = 0; break; }
          }
        }
      }
      kbuf[1-cur][j] = nk;
      changed |= (nk != old);
    }
    if (changed) s_change = 1;
    __syncthreads();                         // B: all writes done
    int ch = s_change;
    __syncthreads();                         // C: all have read ch
    if (tid==0) s_change = 0;                // reset (visible by next A)
    if (!ch) break;                          // uniform
    cur ^= 1;
  }
  // ---- compaction (old kF), keep bits live in kbuf[cur] ----
  __syncthreads();
  const float4* tbi = (const float4*)tb + (size_t)img*PRE;
  const float NEG_INF = __uint_as_float(0xff800000u);
  u8* kf = kbuf[1-cur];                      // free buffer: keep&valid flags
#pragma unroll
  for (int cch=0; cch<2; ++cch){
    int pp = cch*1024 + tid;
    bool kp = false;
    if (pp < PRE && kbuf[cur][pp]){
      float4 b = tbi[pp];
      kp = (b.z > b.x) && (b.w > b.y);
    }
    kf[pp] = kp ? 1 : 0;
  }
  __syncthreads();
  {
    int cc = (int)kf[tid] + (int)kf[1024 + tid];
    for (int of=32; of>0; of>>=1) cc += __shfl_down(cc, of, 64);
    if (lane==0) s_wk[wid] = cc;
  }
  __syncthreads();
  if (tid==0){
    int t=0; for (int w=0; w<16; ++w) t += s_wk[w];
    s_kc = t; s_runk = 0; s_runn = 0;
  }
  __syncthreads();
  int kc = s_kc;
#pragma unroll
  for (int cch=0; cch<2; ++cch){
    int pp = cch*1024 + tid;
    bool kp = kf[pp] != 0;
    u64 bk = __ballot(kp), bn = __ballot(!kp);
    if (lane==0){ s_wk[wid]=__popcll(bk); s_wn[wid]=__popcll(bn); }
    __syncthreads();
    int pk = s_runk, pn = s_runn;
    for (int w=0; w<wid; ++w){ pk += s_wk[w]; pn += s_wn[w]; }
    u64 lm = (1ull<<lane) - 1ull;
    pk += __popcll(bk & lm);
    pn += __popcll(bn & lm);
    int slot = kp ? pk : (kc + pn);
    if (slot < POST && pp < PRE){
      ((float4*)out)[img*POST + slot] = tbi[pp];
      out[32000 + img*POST + slot] = kp ? ts[img*PRE + pp] : NEG_INF;
      ((float2*)(out + 40000))[img*POST + slot] = ((const float2*)tu)[(size_t)img*PRE + pp];
    }
    __syncthreads();
    if (tid==0){
      int tk=0, tn=0;
      for (int w=0; w<16; ++w){ tk += s_wk[w]; tn += s_wn[w]; }
      s_runk += tk; s_runn += tn;
    }
    __syncthreads();
  }
  if (img==0 && tid<2) out[56000+tid] = acc[tid] * (1.0f/2048.0f);
}

// ---------------- L2lite: labels (division-light) + chunk counts ----------
__global__ __launch_bounds__(256) void kL2_label(
    const float* __restrict__ anchors, const float* __restrict__ gt,
    const int* __restrict__ best,
    signed char* __restrict__ label, int* __restrict__ cpos, int* __restrict__ cneg) {
  __shared__ float s_gt[NGT*4];
  __shared__ float s_ga[NGT];
  __shared__ float s_bg[NGT];
  __shared__ int s_w[8];
  int tid = threadIdx.x, img = blockIdx.y;
  int r = blockIdx.x*256 + tid;
  if (tid < NGT*4) s_gt[tid] = gt[img*NGT*4 + tid];
  if (tid < NGT){
    const float* g4 = gt + img*NGT*4 + tid*4;
    s_ga[tid] = (g4[2]-g4[0])*(g4[3]-g4[1]);
    s_bg[tid] = __int_as_float(best[img*NGT + tid]);
  }
  __syncthreads();
  float4 a = ((const float4*)anchors)[r];
  float aA = (a.z-a.x)*(a.w-a.y);
  float bi=-1.0f, bu=1.0f; bool lq = false;
#pragma unroll 4
  for (int g=0; g<NGT; ++g){
    float g0=s_gt[g*4], g1=s_gt[g*4+1], g2=s_gt[g*4+2], g3=s_gt[g*4+3];
    float lx=fmaxf(g0,a.x), ly=fmaxf(g1,a.y);
    float rx=fminf(g2,a.z), ry=fminf(g3,a.w);
    float iw=fmaxf(rx-lx,0.0f), ih=fmaxf(ry-ly,0.0f);
    float inter=iw*ih;
    float uni = fmaxf(s_ga[g] + aA - inter, 1e-9f);
    if (inter*bu > bi*uni){ bi=inter; bu=uni; }
    float bg = s_bg[g];
    lq = lq || ((inter >= (bg - 1e-7f)*uni) && (bg > 0.0f));
  }
  float vbest = bi/bu;
  int lab = lq ? 1 : (vbest >= 0.7f ? 1 : (vbest >= 0.3f ? -1 : 0));
  label[(size_t)img*R_ANCH + r] = (signed char)lab;
  u64 bp = __ballot(lab==1), bn = __ballot(lab==0);
  int wid = tid>>6, lane = tid&63;
  if (lane==0){ s_w[wid*2]=__popcll(bp); s_w[wid*2+1]=__popcll(bn); }
  __syncthreads();
  if (tid==0){
    cpos[img*NCHUNK + blockIdx.x] = s_w[0]+s_w[2]+s_w[4]+s_w[6];
    cneg[img*NCHUNK + blockIdx.x] = s_w[1]+s_w[3]+s_w[5]+s_w[7];
  }
}

// ---------------- L4: quota sampling + ON-DEMAND loss for kept anchors ----
// NLL/loc computed only for the <=256 kept anchors per image (0.27% of the
// old full-grid cost). Arithmetic verbatim from the original kA body.
__global__ __launch_bounds__(256) void kL4_accum(
    const signed char* __restrict__ label,
    const float* __restrict__ pi, const float* __restrict__ mu,
    const float* __restrict__ sigma, const float* __restrict__ anchors,
    const float* __restrict__ gt, const float* __restrict__ deltas,
    const int* __restrict__ cpos, const int* __restrict__ cneg,
    float* __restrict__ acc) {
  __shared__ int s_wp[4], s_wn[4];
  __shared__ int s_r[12];
  __shared__ float s_red[8];
  __shared__ float s_gt[NGT*4];
  int tid = threadIdx.x, img = blockIdx.y, bx = blockIdx.x;
  int lane = tid & 63, wid = tid >> 6;
  if (tid < NGT*4) s_gt[tid] = gt[img*NGT*4 + tid];
  // inline prefix over chunks: vp/vn = counts before this chunk; tp = total pos
  int vp=0, vn=0, tp=0;
  for (int k=tid; k<NCHUNK; k+=256){
    int cp = cpos[img*NCHUNK + k];
    int cn = cneg[img*NCHUNK + k];
    tp += cp;
    if (k < bx){ vp += cp; vn += cn; }
  }
  for (int of=32; of>0; of>>=1){
    vp += __shfl_down(vp, of, 64);
    vn += __shfl_down(vn, of, 64);
    tp += __shfl_down(tp, of, 64);
  }
  if (lane==0){ s_r[wid]=vp; s_r[4+wid]=vn; s_r[8+wid]=tp; }
  __syncthreads();                           // also covers s_gt
  int pre_p = s_r[0]+s_r[1]+s_r[2]+s_r[3];
  int pre_n = s_r[4]+s_r[5]+s_r[6]+s_r[7];
  int totp  = s_r[8]+s_r[9]+s_r[10]+s_r[11];
  int np = totp < 128 ? totp : 128;
  int nn = 256 - np;
  int r = bx*256 + tid;
  size_t o = (size_t)img*R_ANCH + r;
  int lab = label[o];
  bool pos = (lab==1), neg = (lab==0);
  u64 bp = __ballot(pos), bn = __ballot(neg);
  if (lane==0){ s_wp[wid]=__popcll(bp); s_wn[wid]=__popcll(bn); }
  __syncthreads();
  for (int w=0; w<wid; ++w){ pre_p += s_wp[w]; pre_n += s_wn[w]; }
  u64 lm = (1ull<<lane) - 1ull;
  pre_p += __popcll(bp & lm);
  pre_n += __popcll(bn & lm);
  bool kp = pos && (pre_p < np);
  bool kn = neg && (pre_n < nn);
  float c_cls = 0.0f, c_loc = 0.0f;
  if (kp || kn){
    // ---- per-anchor best IoU (verbatim old-kA arithmetic) ----
    float4 a = ((const float4*)anchors)[r];
    float aA = (a.z-a.x)*(a.w-a.y);
    float bi = -1.0f, bu = 1.0f; int idx = 0;
#pragma unroll 4
    for (int g=0; g<NGT; ++g){
      float g0=s_gt[g*4], g1=s_gt[g*4+1], g2=s_gt[g*4+2], g3=s_gt[g*4+3];
      float ga=(g2-g0)*(g3-g1);
      float lx=fmaxf(g0,a.x), ly=fmaxf(g1,a.y);
      float rx=fminf(g2,a.z), ry=fminf(g3,a.w);
      float iw=fmaxf(rx-lx,0.0f), ih=fmaxf(ry-ly,0.0f);
      float inter=iw*ih;
      float uni = fmaxf(ga + aA - inter, 1e-9f);
      if (inter*bu > bi*uni){ bi=inter; bu=uni; idx=g; }
    }
    float vbest = bi/bu;
    // ---- NLL (verbatim old-kA arithmetic) ----
    size_t base = (size_t)img*KMIX*R_ANCH + r;
    float p[KMIX], m[KMIX], s[KMIX];
#pragma unroll
    for (int k=0;k<KMIX;k++){
      p[k]=pi[base+(size_t)k*R_ANCH];
      m[k]=mu[base+(size_t)k*R_ANCH];
      s[k]=sigma[base+(size_t)k*R_ANCH];
    }
    float mx = p[0];
#pragma unroll
    for (int k=1;k<KMIX;k++) mx = fmaxf(mx,p[k]);
    float e[KMIX]; float sum = 0.0f;
#pragma unroll
    for (int k=0;k<KMIX;k++){ e[k]=expf(p[k]-mx); sum += e[k]; }
    float lsum = logf(sum);
    float t_ = fminf(fmaxf(vbest, 0.0f), 1.0f);
    float comp[KMIX];
#pragma unroll
    for (int k=0;k<KMIX;k++){
      float z = (t_ - m[k]) / s[k];
      comp[k] = (p[k]-mx-lsum) - 0.5f*z*z - logf(s[k]) - HALF_L2PI;
    }
    float cm = comp[0];
#pragma unroll
    for (int k=1;k<KMIX;k++) cm = fmaxf(cm, comp[k]);
    float se = 0.0f;
#pragma unroll
    for (int k=0;k<KMIX;k++) se += expf(comp[k]-cm);
    c_cls = -(cm + logf(se));
    if (kp){
      // ---- loc L1 vs matched gt (verbatim old-kA arithmetic) ----
      const float* gb = &s_gt[idx*4];
      float sw = a.z-a.x, sh = a.w-a.y;
      float scx = a.x+0.5f*sw, scy = a.y+0.5f*sh;
      float tw = gb[2]-gb[0], th = gb[3]-gb[1];
      float tcx = gb[0]+0.5f*tw, tcy = gb[1]+0.5f*th;
      float4 d = ((const float4*)deltas)[(size_t)img*R_ANCH + r];
      c_loc = fabsf(d.x-(tcx-scx)/sw) + fabsf(d.y-(tcy-scy)/sh)
            + fabsf(d.z-logf(tw/sw)) + fabsf(d.w-logf(th/sh));
    }
  }
  for (int of=32; of>0; of>>=1){
    c_cls += __shfl_down(c_cls, of, 64);
    c_loc += __shfl_down(c_loc, of, 64);
  }
  if (lane==0){ s_red[wid]=c_cls; s_red[4+wid]=c_loc; }
  __syncthreads();
  if (tid==0){
    float a = s_red[0]+s_red[1]+s_red[2]+s_red[3];
    float b = s_red[4]+s_red[5]+s_red[6]+s_red[7];
    if (a != 0.0f) atomicAdd(&acc[0], a);
    if (b != 0.0f) atomicAdd(&acc[1], b);
  }
}

// ---------------- host-side launch ----------------------------------------
extern "C" void kernel_launch(void* const* d_in, const int* in_sizes, int n_in,
                              void* d_out, int out_size, void* d_ws, size_t ws_size,
                              hipStream_t stream) {
  const float* anchors = (const float*)d_in[0];
  const float* pi      = (const float*)d_in[1];
  const float* mu      = (const float*)d_in[2];
  const float* sigma   = (const float*)d_in[3];
  const float* deltas  = (const float*)d_in[4];
  const float* gt      = (const float*)d_in[5];
  float* out = (float*)d_out;

  char* ws = (char*)d_ws;
  size_t off = 0;
  auto alloc = [&](size_t bytes) -> void* {
    void* p = (void*)(ws + off);
    off += (bytes + 255) & ~(size_t)255;
    return p;
  };
  float* logits = (float*)alloc((size_t)NIMG*R_ANCH*4);
  float* epis   = (float*)alloc((size_t)NIMG*R_ANCH*4);
  float* alea   = (float*)alloc((size_t)NIMG*R_ANCH*4);
  float* tb     = (float*)alloc((size_t)NIMG*PRE*4*4);
  float* tu     = (float*)alloc((size_t)NIMG*PRE*2*4);
  float* ts     = (float*)alloc((size_t)NIMG*PRE*4);
  u64*   maskLT = (u64*)  alloc((size_t)NIMG*32*MROW*8);
  u16*   slist  = (u16*)  alloc((size_t)NIMG*2048*SCAP*2);
  u64*   cand   = (u64*)  alloc((size_t)NIMG*CAND_CAP*8);
  int*   cpos   = (int*)  alloc((size_t)NIMG*NCHUNK*4);
  int*   cneg   = (int*)  alloc((size_t)NIMG*NCHUNK*4);
  // ---- contiguous zero region ----
  size_t zstart = off;
  u32*   hist0  = (u32*)  alloc((size_t)NIMG*2048*4);
  u32*   hist1  = (u32*)  alloc((size_t)NIMG*2048*4);
  u32*   hist2  = (u32*)  alloc((size_t)NIMG*2048*4);
  u32*   gcnt   = (u32*)  alloc((size_t)NIMG*GC_STRIDE*4);
  int*   best   = (int*)  alloc((size_t)NIMG*NGT*4);
  u32*   scnt   = (u32*)  alloc((size_t)NIMG*2048*4);
  float* acc    = (float*)alloc(8);
  int zwords = (int)((off - zstart) / 4);
  // label aliases logits: logits last read in kGather; kL2 runs after it.
  signed char* label = (signed char*)logits;

  kZero<<<dim3(64), dim3(256), 0, stream>>>((u32*)(ws + zstart), zwords);
  kA_mdn<<<dim3(ACHUNK+NBLK, NIMG), dim3(256), 0, stream>>>(pi, mu, sigma, logits, epis, alea,
                                                            hist0, anchors, gt, best);
  kP1<<<dim3(NBLK, NIMG), dim3(256), 0, stream>>>(logits, hist0, hist1);
  kP2<<<dim3(NBLK, NIMG), dim3(256), 0, stream>>>(logits, hist0, hist1, hist2);
  kGather<<<dim3(NBLK, NIMG), dim3(256), 0, stream>>>(logits, hist0, hist1, hist2, cand, gcnt);
  kRank<<<dim3(NIMG), dim3(1024), 0, stream>>>(cand, gcnt, epis, alea, deltas, anchors, tb, tu, ts);
  kD_mask<<<dim3(32, NIMG), dim3(1024), 0, stream>>>(tb, maskLT, scnt, slist);
  kL2_label<<<dim3(NCHUNK, NIMG), dim3(256), 0, stream>>>(anchors, gt, best, label, cpos, cneg);
  kL4_accum<<<dim3(NCHUNK, NIMG), dim3(256), 0, stream>>>(label, pi, mu, sigma, anchors, gt, deltas,
                                                          cpos, cneg, acc);
  kEF_nms<<<dim3(NIMG), dim3(1024), 0, stream>>>(maskLT, scnt, slist, tb, tu, ts, acc, out);
}

// Round 16
// 269.008 us; speedup vs baseline: 1.1903x; 1.0030x over previous
//
#include <hip/hip_runtime.h>
#include <cstdint>
#include <cstddef>

typedef unsigned long long u64;
typedef unsigned int u32;
typedef unsigned short u16;
typedef unsigned char u8;

#define R_ANCH 96000
#define R2     48000 // R_ANCH / 2 (float2 units)
#define NIMG   8
#define KMIX   5
#define PRE    2000
#define POST   1000
#define NGT    32
#define NCHUNK 375   // R_ANCH / 256 (label/loss kernels)
#define ACHUNK 188   // ceil(R2 / 256) — kA main blocks (2 anchors/thread)
#define NBLK   48    // blocks per image for parallel scan kernels
#define MROW   2048  // maskLT row stride (padded PRE)
#define SCAP   16    // per-row suppressor-list capacity (overflow -> dense path)
#define BIG_TH 64    // kRank: bins larger than this get level-1 split
#define CAP_BIN 6144 // refinement trigger: crossing-bin count above this -> refine
#define CAND_CAP 8192// global/LDS candidate capacity (PRE-1 + CAP_BIN = 8143 max)
#define GC_STRIDE 16 // gcnt padding: 64 B per image

#define IMG_SZ        1280.0f
#define NMS_T         0.7f
#define SCALE_CLAMP_F 4.135166556742356f
#define HALF_L2PI     0.9189385332046727f

__device__ __forceinline__ u64 make_key(float s, int r) {
  u32 u = __float_as_uint(s);
  u = (u & 0x80000000u) ? ~u : (u | 0x80000000u);
  return ((u64)u << 32) | (u64)(0xFFFFFFFFu - (u32)r);
}

__device__ __forceinline__ float dec_score(u64 key) {
  u32 o = (u32)(key >> 32);
  u32 bits = (o & 0x80000000u) ? (o ^ 0x80000000u) : ~o;
  return __uint_as_float(bits);
}

// EXACT-PATH IoU (NMS only): must match reference bit-for-bit since NMS
// decisions select whole boxes. Label-path code uses division-free
// cross-multiplied compares (loss-only, high tolerance).
__device__ __forceinline__ float iou_pair(float a0,float a1,float a2,float a3,
                                          float b0,float b1,float b2,float b3) {
#pragma clang fp contract(off)
  float areaA = (a2-a0)*(a3-a1);
  float areaB = (b2-b0)*(b3-b1);
  float lx=fmaxf(a0,b0), ly=fmaxf(a1,b1);
  float rx=fminf(a2,b2), ry=fminf(a3,b3);
  float iw=fmaxf(rx-lx,0.0f), ih=fmaxf(ry-ly,0.0f);
  float inter=iw*ih;
  return inter / fmaxf(areaA+areaB-inter, 1e-9f);
}

// pick: from a 2048-bin histogram (bin d high = higher keys), find the bin
// containing the k-th largest key. 256 threads. s_i >= 8 ints, s_u >= 3 u32.
__device__ __forceinline__ void pick2048(const u32* __restrict__ hist, int k,
                                         int* s_i, u32* s_u,
                                         int& d_out, int& k_out, u32& cnt_out) {
  int tid = threadIdx.x;
  int lane = tid & 63, w = tid >> 6;
  u32 h[8]; u32 ssum = 0;
#pragma unroll
  for (int i=0;i<8;++i){ h[i] = hist[2047 - (tid*8 + i)]; ssum += h[i]; }
  u32 incl = ssum;
  for (int off=1; off<64; off<<=1){
    u32 t = (u32)__shfl_up((int)incl, off, 64);
    if (lane >= off) incl += t;
  }
  if (lane==63) s_i[w] = (int)incl;
  __syncthreads();
  u32 base = 0;
  for (int ww=0; ww<w; ++ww) base += (u32)s_i[ww];
  u32 run = base + incl - ssum;              // exclusive prefix (descending keys)
#pragma unroll
  for (int i=0;i<8;++i){
    u32 nr = run + h[i];
    if (run < (u32)k && nr >= (u32)k){       // unique crossing thread
      s_u[0] = (u32)(2047 - (tid*8+i));
      s_u[1] = (u32)k - run;
      s_u[2] = h[i];
    }
    run = nr;
  }
  __syncthreads();
  d_out = (int)s_u[0]; k_out = (int)s_u[1]; cnt_out = s_u[2];
  __syncthreads();
}

// descending exclusive prefix over 2048 bins, 1024 threads (2 bins/thread).
// Caller must __syncthreads() before (h ready) and after (off ready).
__device__ __forceinline__ void scan2048_desc(const u32* __restrict__ h,
                                              u32* __restrict__ off,
                                              u32* __restrict__ wsum, int tid) {
  int b_hi = 2047 - 2*tid, b_lo = b_hi - 1;
  u32 h_hi = h[b_hi], h_lo = h[b_lo];
  u32 sum = h_hi + h_lo;
  u32 incl = sum;
  int lane = tid & 63, wv = tid >> 6;
  for (int o=1; o<64; o<<=1){
    u32 t = (u32)__shfl_up((int)incl, o, 64);
    if (lane >= o) incl += t;
  }
  if (lane==63) wsum[wv] = incl;
  __syncthreads();
  u32 base = 0;
  for (int w=0; w<wv; ++w) base += wsum[w];
  u32 excl = base + incl - sum;
  off[b_hi] = excl;
  off[b_lo] = excl + h_hi;
}

// ---------------- zero: contiguous workspace region -----------------------
__global__ void kZero(u32* z, int nwords) {
  for (int i = blockIdx.x*256 + threadIdx.x; i < nwords; i += gridDim.x*256)
    z[i] = 0u;
}

// ---------------- A: MDN moments + hist0 — float2 (2 anchors/thread) ------
// R15 post-mortem: launch-bounds lever exhausted — (256,2) gave VGPR 84,
// no spill, but kA stayed ~48 us. Real limit: grid 1136 blocks = 4.4/CU,
// ~18 waves/CU available, occ 15% — too few waves to hide ~900cy HBM
// latency. Fix: 2 anchors/thread (float2), 188 main blocks/img -> 1888
// blocks total (~30 waves/CU), per-thread state halves. Same per-anchor
// arithmetic. No min-waves attribute (R12 spill lesson).
// blocks [0, ACHUNK): main body; [ACHUNK, ACHUNK+NBLK): fused L1 best-gt.
__global__ __launch_bounds__(256) void kA_mdn(
    const float* __restrict__ pi, const float* __restrict__ mu,
    const float* __restrict__ sigma, float* __restrict__ logits,
    float* __restrict__ epis, float* __restrict__ alea,
    u32* __restrict__ hist0,
    const float* __restrict__ anchors, const float* __restrict__ gt,
    int* __restrict__ best) {
  __shared__ u32 s_h[2048];
  __shared__ float s_gt[NGT*4];
  __shared__ float s_ga[NGT];
  __shared__ int s_best[NGT];
  int tid = threadIdx.x;
  int img = blockIdx.y;

  if (blockIdx.x >= ACHUNK) {
    // ---------------- fused L1 body (block-uniform branch) ----------------
    int bx = blockIdx.x - ACHUNK;
    if (tid < NGT*4) s_gt[tid] = gt[img*NGT*4 + tid];
    if (tid < NGT){
      const float* g4 = gt + img*NGT*4 + tid*4;
      s_ga[tid] = (g4[2]-g4[0])*(g4[3]-g4[1]);
      s_best[tid] = 0;
    }
    __syncthreads();
    float4 an[8]; float aA[8];
#pragma unroll
    for (int q=0; q<8; ++q){
      int r = bx*256 + tid + q*(NBLK*256);
      an[q] = (r < R_ANCH) ? ((const float4*)anchors)[r]
                           : make_float4(0.f,0.f,0.f,0.f);   // IoU=0, inert
      aA[q] = (an[q].z-an[q].x)*(an[q].w-an[q].y);
    }
    float vmax[NGT];
#pragma unroll 2
    for (int g=0; g<NGT; ++g){
      float g0=s_gt[g*4], g1=s_gt[g*4+1], g2=s_gt[g*4+2], g3=s_gt[g*4+3];
      float ga=s_ga[g];
      float bi=0.0f, bu=1.0f;               // v=0 baseline
#pragma unroll
      for (int q=0; q<8; ++q){
        float lx=fmaxf(g0,an[q].x), ly=fmaxf(g1,an[q].y);
        float rx=fminf(g2,an[q].z), ry=fminf(g3,an[q].w);
        float iw=fmaxf(rx-lx,0.0f), ih=fmaxf(ry-ly,0.0f);
        float inter=iw*ih;
        float uni=fmaxf(ga+aA[q]-inter,1e-9f);
        if (inter*bu > bi*uni){ bi=inter; bu=uni; }
      }
      vmax[g] = bi/bu;
    }
    int lane = tid & 63;
#pragma unroll
    for (int g=0; g<NGT; ++g){
      float v = vmax[g];
      v = fmaxf(v, __shfl_xor(v, 1, 64));
      v = fmaxf(v, __shfl_xor(v, 2, 64));
      v = fmaxf(v, __shfl_xor(v, 4, 64));
      v = fmaxf(v, __shfl_xor(v, 8, 64));
      v = fmaxf(v, __shfl_xor(v,16, 64));
      v = fmaxf(v, __shfl_xor(v,32, 64));
      if (lane==0 && v > 0.0f) atomicMax(&s_best[g], __float_as_int(v));
    }
    __syncthreads();
    if (tid < NGT) atomicMax(&best[img*NGT + tid], s_best[tid]);
    return;
  }

  // ---------------- main MDN body: 2 anchors per thread ----------------
  int r2 = blockIdx.x*256 + tid;             // float2 index within image
  bool act = (r2 < R2);
  for (int b=tid; b<2048; b+=256) s_h[b]=0u;
  u64 keys[2];
  if (act){
    const float2* pi2 = (const float2*)pi;
    const float2* mu2 = (const float2*)mu;
    const float2* sg2 = (const float2*)sigma;
    size_t base = (size_t)img*KMIX*R2 + r2;
    float2 p2[KMIX], m2[KMIX], s2[KMIX];
#pragma unroll
    for (int k=0;k<KMIX;k++){
      p2[k]=pi2[base+(size_t)k*R2];
      m2[k]=mu2[base+(size_t)k*R2];
      s2[k]=sg2[base+(size_t)k*R2];
    }
    float lg_[2], ep_[2], al_[2];
#pragma unroll
    for (int j=0;j<2;++j){
      float p[KMIX], m[KMIX], s[KMIX];
#pragma unroll
      for (int k=0;k<KMIX;k++){
        p[k] = (&p2[k].x)[j];
        m[k] = (&m2[k].x)[j];
        s[k] = (&s2[k].x)[j];
      }
      float mx = p[0];
#pragma unroll
      for (int k=1;k<KMIX;k++) mx = fmaxf(mx,p[k]);
      float e[KMIX]; float sum = 0.0f;
#pragma unroll
      for (int k=0;k<KMIX;k++){ e[k]=expf(p[k]-mx); sum += e[k]; }
      float w[KMIX]; float lg = 0.0f;
#pragma unroll
      for (int k=0;k<KMIX;k++){ w[k]=e[k]/sum; lg += w[k]*m[k]; }
      float ep = 0.0f, al = 0.0f;
#pragma unroll
      for (int k=0;k<KMIX;k++){ float d=m[k]-lg; ep += w[k]*d*d; al += w[k]*s[k]*s[k]; }
      lg_[j]=lg; ep_[j]=ep; al_[j]=al;
      keys[j] = make_key(lg, r2*2 + j);
    }
    size_t o2 = (size_t)img*R2 + r2;
    ((float2*)logits)[o2] = make_float2(lg_[0],lg_[1]);
    ((float2*)epis)[o2]   = make_float2(ep_[0],ep_[1]);
    ((float2*)alea)[o2]   = make_float2(al_[0],al_[1]);
  }
  __syncthreads();                           // s_h zero complete
  if (act){
#pragma unroll
    for (int j=0;j<2;++j)
      atomicAdd(&s_h[(u32)(keys[j]>>53)], 1u);
  }
  __syncthreads();
  for (int b=tid; b<2048; b+=256){ u32 v=s_h[b]; if(v) atomicAdd(&hist0[img*2048+b], v); }
}

// ---------------- P1: refine level-1 histogram (rare: c0 > CAP_BIN) -------
__global__ __launch_bounds__(256) void kP1(const float* __restrict__ logits,
                                           const u32* __restrict__ hist0,
                                           u32* __restrict__ hist1) {
  __shared__ u32 s_h[2048];
  __shared__ int s_i[8]; __shared__ u32 s_u[3];
  int img = blockIdx.y, tid = threadIdx.x;
  int d0,k0; u32 c0;
  pick2048(hist0 + img*2048, PRE, s_i, s_u, d0,k0,c0);
  if (c0 <= CAP_BIN) return;                 // block-uniform (common case)
  for (int b=tid; b<2048; b+=256) s_h[b]=0u;
  __syncthreads();
  const float* sc = logits + (size_t)img*R_ANCH;
  for (int r = blockIdx.x*256 + tid; r < R_ANCH; r += NBLK*256){
    u64 key = make_key(sc[r], r);
    if ((int)(key>>53) == d0) atomicAdd(&s_h[(u32)(key>>42)&2047u], 1u);
  }
  __syncthreads();
  for (int b=tid; b<2048; b+=256){ u32 v=s_h[b]; if(v) atomicAdd(&hist1[img*2048+b], v); }
}

// ---------------- P2: refine level-2 histogram (essentially never) --------
__global__ __launch_bounds__(256) void kP2(const float* __restrict__ logits,
                                           const u32* __restrict__ hist0,
                                           const u32* __restrict__ hist1,
                                           u32* __restrict__ hist2) {
  __shared__ u32 s_h[2048];
  __shared__ int s_i[8]; __shared__ u32 s_u[3];
  int img = blockIdx.y, tid = threadIdx.x;
  int d0,k0; u32 c0;
  pick2048(hist0 + img*2048, PRE, s_i, s_u, d0,k0,c0);
  if (c0 <= CAP_BIN) return;
  int d1,k1; u32 c1;
  pick2048(hist1 + img*2048, k0, s_i, s_u, d1,k1,c1);
  if (c1 <= CAP_BIN) return;
  u64 p1 = ((u64)d0<<11) | (u64)d1;
  for (int b=tid; b<2048; b+=256) s_h[b]=0u;
  __syncthreads();
  const float* sc = logits + (size_t)img*R_ANCH;
  for (int r = blockIdx.x*256 + tid; r < R_ANCH; r += NBLK*256){
    u64 key = make_key(sc[r], r);
    if ((key>>42) == p1) atomicAdd(&s_h[(u32)(key>>31)&2047u], 1u);
  }
  __syncthreads();
  for (int b=tid; b<2048; b+=256){ u32 v=s_h[b]; if(v) atomicAdd(&hist2[img*2048+b], v); }
}

// ---------------- G: gather candidates, block-compacted (parallel) --------
__global__ __launch_bounds__(256) void kGather(const float* __restrict__ logits,
    const u32* __restrict__ hist0, const u32* __restrict__ hist1,
    const u32* __restrict__ hist2, u64* __restrict__ cand, u32* __restrict__ gcnt) {
  __shared__ int s_i[8]; __shared__ u32 s_u[3];
  __shared__ u64 s_cand[2048];               // 16 KB staging (block take <= 2048)
  __shared__ u32 s_cnt, s_base;
  int img = blockIdx.y, tid = threadIdx.x;
  if (tid==0) s_cnt = 0u;
  int d,kk; u32 c;
  pick2048(hist0 + img*2048, PRE, s_i, s_u, d,kk,c);   // has syncthreads
  u64 p = (u64)d; int L = 0;
  if (c > CAP_BIN){
    pick2048(hist1 + img*2048, kk, s_i, s_u, d,kk,c);
    p = (p<<11)|(u64)d; L = 1;
    if (c > CAP_BIN){
      pick2048(hist2 + img*2048, kk, s_i, s_u, d,kk,c);
      p = (p<<11)|(u64)d; L = 2;
    }
  }
  u64 T = p << (64 - 11*(L+1));              // total candidates <= 8143
  const float* sc = logits + (size_t)img*R_ANCH;
  int lane = tid & 63;
  for (int r = blockIdx.x*256 + tid; r < R_ANCH; r += NBLK*256){
    u64 key = make_key(sc[r], r);
    bool take = (key >= T);
    u64 b = __ballot(take);
    if (b){
      u32 base = 0;
      if (lane==0) base = atomicAdd(&s_cnt, (u32)__popcll(b));   // LDS atomic
      base = (u32)__shfl((int)base, 0, 64);
      if (take){
        u32 pos = base + (u32)__popcll(b & ((1ull<<lane)-1ull));
        if (pos < 2048u) s_cand[pos] = key;
        else {                               // correctness net (block take > 2048)
          u32 gp = atomicAdd(&gcnt[img*GC_STRIDE], 1u);
          if (gp < CAND_CAP) cand[(size_t)img*CAND_CAP + gp] = key;
        }
      }
    }
  }
  __syncthreads();
  u32 n = s_cnt < 2048u ? s_cnt : 2048u;
  if (tid==0) s_base = atomicAdd(&gcnt[img*GC_STRIDE], n);  // 1 atomic/block
  __syncthreads();
  u32 gb = s_base;
  for (u32 i=tid; i<n; i+=256)
    cand[(size_t)img*CAND_CAP + gb + i] = s_cand[i];
}

// ---------------- R: hierarchical exact bucket-rank + epilogue ------------
// Bins > BIG_TH members get a sequential level-1 split by digit1 (bits
// 52..42) -> sub-bins of ~1-3; compare loops trivial. Bins with base >= PRE
// pruned. Exact. Capacity 8192 (CAP_BIN=6144 + PRE-1 = 8143 max).
__global__ __launch_bounds__(1024) void kRank(
    const u64* __restrict__ cand, const u32* __restrict__ gcnt,
    const float* __restrict__ epis, const float* __restrict__ alea,
    const float* __restrict__ deltas, const float* __restrict__ anchors,
    float* __restrict__ tb, float* __restrict__ tu, float* __restrict__ ts) {
  __shared__ u64 s_key[CAND_CAP];            // 64 KB
  __shared__ u16 s_idx0[CAND_CAP];           // 16 KB
  __shared__ u16 s_idx1[CAND_CAP];           // 16 KB (per big bin, reused)
  __shared__ u32 s_h0[2048];                 // 8 KB
  __shared__ u32 s_off0[2048];               // 8 KB (excl; scatter makes base+size)
  __shared__ u32 s_h1[2048];                 // 8 KB
  __shared__ u32 s_off1[2048];               // 8 KB
  __shared__ u32 s_wsum[16];
  __shared__ u32 s_nbig;
  __shared__ u16 s_big[128];
  int tid = threadIdx.x, img = blockIdx.x;
  u32 cnt = gcnt[img*GC_STRIDE];
  if (cnt > (u32)CAND_CAP) cnt = CAND_CAP;
  const u64* cp = cand + (size_t)img*CAND_CAP;
  for (int i=tid; i<CAND_CAP; i+=1024) s_key[i] = (i < (int)cnt) ? cp[i] : 0ull;
  for (int b=tid; b<2048; b+=1024){ s_h0[b] = 0u; }
  if (tid==0) s_nbig = 0u;
  __syncthreads();
  for (int i=tid; i<(int)cnt; i+=1024)
    atomicAdd(&s_h0[(u32)(s_key[i]>>53)], 1u);
  __syncthreads();
  scan2048_desc(s_h0, s_off0, s_wsum, tid);
  __syncthreads();
  // collect big bins that can contribute ranks < PRE
  for (int b=tid; b<2048; b+=1024){
    u32 sz = s_h0[b];
    if (sz > BIG_TH && s_off0[b] < PRE){
      u32 q = atomicAdd(&s_nbig, 1u);
      if (q < 128u) s_big[q] = (u16)b;
    }
  }
  __syncthreads();                           // collect/scatter ordering
  // scatter candidates into digit0-bucket order
  for (int i=tid; i<(int)cnt; i+=1024){
    u32 d = (u32)(s_key[i]>>53);
    u32 slot = atomicAdd(&s_off0[d], 1u);    // post: s_off0[d] = base + size
    s_idx0[slot] = (u16)i;
  }
  __syncthreads();
  // epilogue writer
  auto emit = [&](u64 my, u32 rank){
    if (rank < PRE){
      int p = (int)rank;
      u32 idx = 0xFFFFFFFFu - (u32)(my & 0xFFFFFFFFull);
      ts[img*PRE + p] = dec_score(my);
      float4 a = ((const float4*)anchors)[idx];
      float4 dd = ((const float4*)deltas)[(size_t)img*R_ANCH + idx];
      float w = a.z - a.x, h = a.w - a.y;
      float cx = a.x + 0.5f*w, cy = a.y + 0.5f*h;
      float dw = fminf(dd.z, SCALE_CLAMP_F), dh = fminf(dd.w, SCALE_CLAMP_F);
      float pcx = dd.x*w + cx, pcy = dd.y*h + cy;
      float pw = expf(dw)*w, ph = expf(dh)*h;
      float x0 = fminf(fmaxf(pcx - 0.5f*pw, 0.0f), IMG_SZ);
      float y0 = fminf(fmaxf(pcy - 0.5f*ph, 0.0f), IMG_SZ);
      float x1 = fminf(fmaxf(pcx + 0.5f*pw, 0.0f), IMG_SZ);
      float y1 = fminf(fmaxf(pcy + 0.5f*ph, 0.0f), IMG_SZ);
      ((float4*)tb)[(size_t)img*PRE + p] = make_float4(x0,y0,x1,y1);
      size_t o = (size_t)img*R_ANCH + idx;
      ((float2*)tu)[(size_t)img*PRE + p] = make_float2(epis[o], alea[o]);
    }
  };
  // small bins: direct compare loop (size <= BIG_TH)
  for (int i=tid; i<(int)cnt; i+=1024){
    u64 my = s_key[i];
    u32 d = (u32)(my>>53);
    u32 size = s_h0[d];
    if (size > BIG_TH) continue;             // handled below
    u32 bs = s_off0[d] - size;
    if (bs >= PRE) continue;                 // cannot produce rank < PRE
    u32 rank = bs;
    for (u32 q=bs; q<bs+size; ++q)
      rank += (s_key[s_idx0[q]] > my) ? 1u : 0u;
    emit(my, rank);
  }
  __syncthreads();
  u32 nbig = s_nbig < 128u ? s_nbig : 128u;
  for (u32 bb=0; bb<nbig; ++bb){             // block-uniform sequential loop
    u32 B = s_big[bb];
    u32 size = s_h0[B];
    u32 base0 = s_off0[B] - size;
    for (int b=tid; b<2048; b+=1024) s_h1[b] = 0u;
    __syncthreads();
    for (u32 q=tid; q<size; q+=1024){
      u64 k = s_key[s_idx0[base0+q]];
      atomicAdd(&s_h1[(u32)(k>>42)&2047u], 1u);
    }
    __syncthreads();
    scan2048_desc(s_h1, s_off1, s_wsum, tid);
    __syncthreads();
    for (u32 q=tid; q<size; q+=1024){
      u16 ci = s_idx0[base0+q];
      u64 k = s_key[ci];
      u32 slot = atomicAdd(&s_off1[(u32)(k>>42)&2047u], 1u);
      s_idx1[slot] = ci;
    }
    __syncthreads();
    for (u32 q=tid; q<size; q+=1024){
      u16 ci = s_idx1[q];
      u64 my = s_key[ci];
      u32 d1 = (u32)(my>>42)&2047u;
      u32 ssz = s_h1[d1];
      u32 sbs = s_off1[d1] - ssz;            // sub-bin base (within bin)
      u32 rank = base0 + sbs;
      for (u32 t2=sbs; t2<sbs+ssz; ++t2)
        rank += (s_key[s_idx1[t2]] > my) ? 1u : 0u;
      emit(my, rank);
    }
    __syncthreads();                         // s_h1/s_off1/s_idx1 reuse
  }
}

// ---------------- D: masks + sparse suppressor lists (EXACT IoU) ----------
__global__ __launch_bounds__(1024) void kD_mask(const float* __restrict__ tb,
                                                u64* __restrict__ maskLT,
                                                u32* __restrict__ scnt,
                                                u16* __restrict__ slist) {
  __shared__ float4 s_tile[64];
  int tid = threadIdx.x;
  int a = blockIdx.x, img = blockIdx.y;
  const float4* tbi = (const float4*)tb + (size_t)img*PRE;
  if (tid < 64){
    int i = a*64 + tid;
    s_tile[tid] = (i < PRE) ? tbi[i] : make_float4(0.f,0.f,0.f,0.f);
  }
  __syncthreads();
  u64* outp = maskLT + ((size_t)img*32 + a)*MROW;
  u32* cnts = scnt + (size_t)img*2048;
  u16* lst  = slist + (size_t)img*2048*SCAP;
  int bmax = min(64, PRE - a*64);
  for (int j = a*64 + tid; j < MROW; j += 1024){
    u64 m = 0ull;
    if (j < PRE){
      float4 B = tbi[j];
      int blim = min(bmax, j - a*64);        // only b with a*64+b < j
      for (int b = 0; b < blim; ++b){
        float4 A = s_tile[b];
        float v = iou_pair(A.x,A.y,A.z,A.w, B.x,B.y,B.z,B.w);
        m |= (u64)(v > NMS_T) << b;
      }
    }
    outp[j] = m;
    u64 mm = m;
    while (mm){
      int b = __builtin_ctzll(mm); mm &= mm - 1ull;
      u32 slot = atomicAdd(&cnts[j], 1u);
      if (slot < SCAP) lst[(size_t)j*SCAP + slot] = (u16)(a*64 + b);
    }
  }
}

// ---------------- EF: greedy NMS fixpoint + final compaction + losses -----
__global__ __launch_bounds__(1024) void kEF_nms(const u64* __restrict__ maskLT,
    const u32* __restrict__ scnt, const u16* __restrict__ slist,
    const float* __restrict__ tb, const float* __restrict__ tu,
    const float* __restrict__ ts, const float* __restrict__ acc,
    float* __restrict__ out) {
  __shared__ u64 s_list64[2048*SCAP/4];      // 64 KB staged lists
  __shared__ u16 s_cnt[2048];                // 4 KB
  __shared__ u8  kbuf[2][2048];              // 4 KB
  __shared__ u64 s_kw[32];
  __shared__ int s_change, s_ovf;
  __shared__ int s_wk[16], s_wn[16];
  __shared__ int s_kc, s_runk, s_runn;
  int img = blockIdx.x, tid = threadIdx.x;
  int lane = tid & 63, wid = tid >> 6;
  const u64* gl = (const u64*)(slist + (size_t)img*2048*SCAP);
  for (int i=tid; i<2048*SCAP/4; i+=1024) s_list64[i] = gl[i];
  const u32* gc = scnt + (size_t)img*2048;
  for (int i=tid; i<2048; i+=1024) s_cnt[i] = (u16)gc[i];
  if (tid==0){ s_change = 0; s_ovf = 0; }
  __syncthreads();
  bool myovf = false;
#pragma unroll
  for (int q=0; q<2; ++q){
    int j = tid + q*1024;
    if (s_cnt[j] > SCAP) myovf = true;
    kbuf[0][j] = (j < PRE) ? 1 : 0;
  }
  if (myovf) s_ovf = 1;                      // benign race
  __syncthreads();
  const u64* MT = maskLT + (size_t)img*32*MROW;
  int cur = 0;
  for (int iter=0; iter<2048; ++iter){
    bool ovf = (s_ovf != 0);                 // stable after init barrier
    if (ovf && tid < 32){
      u64 w = 0ull;
      for (int b=0; b<64; ++b) w |= (u64)(kbuf[cur][tid*64+b] & 1) << b;
      s_kw[tid] = w;
    }
    __syncthreads();                         // A: s_change reset + kw visible
    bool changed = false;
#pragma unroll
    for (int q=0; q<2; ++q){
      int j = tid + q*1024;
      u8 old = kbuf[cur][j];
      u8 nk = (j < PRE) ? 1 : 0;
      if (nk){
        int cnt = s_cnt[j];
        if (cnt <= SCAP){
          const u16* lp = (const u16*)&s_list64[j*(SCAP/4)];
          for (int i=0; i<cnt; ++i){
            if (kbuf[cur][lp[i]]){ nk = 0; break; }
          }
        } else {
          int amax = j >> 6;
          for (int a=0; a<=amax; ++a){
            if (MT[(size_t)a*MROW + j] & s_kw[a]){ nk = 0; break; }
          }
        }
      }
      kbuf[1-cur][j] = nk;
      changed |= (nk != old);
    }
    if (changed) s_change = 1;
    __syncthreads();                         // B: all writes done
    int ch = s_change;
    __syncthreads();                         // C: all have read ch
    if (tid==0) s_change = 0;                // reset (visible by next A)
    if (!ch) break;                          // uniform
    cur ^= 1;
  }
  // ---- compaction (old kF), keep bits live in kbuf[cur] ----
  __syncthreads();
  const float4* tbi = (const float4*)tb + (size_t)img*PRE;
  const float NEG_INF = __uint_as_float(0xff800000u);
  u8* kf = kbuf[1-cur];                      // free buffer: keep&valid flags
#pragma unroll
  for (int cch=0; cch<2; ++cch){
    int pp = cch*1024 + tid;
    bool kp = false;
    if (pp < PRE && kbuf[cur][pp]){
      float4 b = tbi[pp];
      kp = (b.z > b.x) && (b.w > b.y);
    }
    kf[pp] = kp ? 1 : 0;
  }
  __syncthreads();
  {
    int cc = (int)kf[tid] + (int)kf[1024 + tid];
    for (int of=32; of>0; of>>=1) cc += __shfl_down(cc, of, 64);
    if (lane==0) s_wk[wid] = cc;
  }
  __syncthreads();
  if (tid==0){
    int t=0; for (int w=0; w<16; ++w) t += s_wk[w];
    s_kc = t; s_runk = 0; s_runn = 0;
  }
  __syncthreads();
  int kc = s_kc;
#pragma unroll
  for (int cch=0; cch<2; ++cch){
    int pp = cch*1024 + tid;
    bool kp = kf[pp] != 0;
    u64 bk = __ballot(kp), bn = __ballot(!kp);
    if (lane==0){ s_wk[wid]=__popcll(bk); s_wn[wid]=__popcll(bn); }
    __syncthreads();
    int pk = s_runk, pn = s_runn;
    for (int w=0; w<wid; ++w){ pk += s_wk[w]; pn += s_wn[w]; }
    u64 lm = (1ull<<lane) - 1ull;
    pk += __popcll(bk & lm);
    pn += __popcll(bn & lm);
    int slot = kp ? pk : (kc + pn);
    if (slot < POST && pp < PRE){
      ((float4*)out)[img*POST + slot] = tbi[pp];
      out[32000 + img*POST + slot] = kp ? ts[img*PRE + pp] : NEG_INF;
      ((float2*)(out + 40000))[img*POST + slot] = ((const float2*)tu)[(size_t)img*PRE + pp];
    }
    __syncthreads();
    if (tid==0){
      int tk=0, tn=0;
      for (int w=0; w<16; ++w){ tk += s_wk[w]; tn += s_wn[w]; }
      s_runk += tk; s_runn += tn;
    }
    __syncthreads();
  }
  if (img==0 && tid<2) out[56000+tid] = acc[tid] * (1.0f/2048.0f);
}

// ---------------- L2lite: labels (division-light) + chunk counts ----------
__global__ __launch_bounds__(256) void kL2_label(
    const float* __restrict__ anchors, const float* __restrict__ gt,
    const int* __restrict__ best,
    signed char* __restrict__ label, int* __restrict__ cpos, int* __restrict__ cneg) {
  __shared__ float s_gt[NGT*4];
  __shared__ float s_ga[NGT];
  __shared__ float s_bg[NGT];
  __shared__ int s_w[8];
  int tid = threadIdx.x, img = blockIdx.y;
  int r = blockIdx.x*256 + tid;
  if (tid < NGT*4) s_gt[tid] = gt[img*NGT*4 + tid];
  if (tid < NGT){
    const float* g4 = gt + img*NGT*4 + tid*4;
    s_ga[tid] = (g4[2]-g4[0])*(g4[3]-g4[1]);
    s_bg[tid] = __int_as_float(best[img*NGT + tid]);
  }
  __syncthreads();
  float4 a = ((const float4*)anchors)[r];
  float aA = (a.z-a.x)*(a.w-a.y);
  float bi=-1.0f, bu=1.0f; bool lq = false;
#pragma unroll 4
  for (int g=0; g<NGT; ++g){
    float g0=s_gt[g*4], g1=s_gt[g*4+1], g2=s_gt[g*4+2], g3=s_gt[g*4+3];
    float lx=fmaxf(g0,a.x), ly=fmaxf(g1,a.y);
    float rx=fminf(g2,a.z), ry=fminf(g3,a.w);
    float iw=fmaxf(rx-lx,0.0f), ih=fmaxf(ry-ly,0.0f);
    float inter=iw*ih;
    float uni = fmaxf(s_ga[g] + aA - inter, 1e-9f);
    if (inter*bu > bi*uni){ bi=inter; bu=uni; }
    float bg = s_bg[g];
    lq = lq || ((inter >= (bg - 1e-7f)*uni) && (bg > 0.0f));
  }
  float vbest = bi/bu;
  int lab = lq ? 1 : (vbest >= 0.7f ? 1 : (vbest >= 0.3f ? -1 : 0));
  label[(size_t)img*R_ANCH + r] = (signed char)lab;
  u64 bp = __ballot(lab==1), bn = __ballot(lab==0);
  int wid = tid>>6, lane = tid&63;
  if (lane==0){ s_w[wid*2]=__popcll(bp); s_w[wid*2+1]=__popcll(bn); }
  __syncthreads();
  if (tid==0){
    cpos[img*NCHUNK + blockIdx.x] = s_w[0]+s_w[2]+s_w[4]+s_w[6];
    cneg[img*NCHUNK + blockIdx.x] = s_w[1]+s_w[3]+s_w[5]+s_w[7];
  }
}

// ---------------- L4: quota sampling + ON-DEMAND loss for kept anchors ----
// NLL/loc computed only for the <=256 kept anchors per image (0.27% of the
// old full-grid cost). Arithmetic verbatim from the original kA body.
__global__ __launch_bounds__(256) void kL4_accum(
    const signed char* __restrict__ label,
    const float* __restrict__ pi, const float* __restrict__ mu,
    const float* __restrict__ sigma, const float* __restrict__ anchors,
    const float* __restrict__ gt, const float* __restrict__ deltas,
    const int* __restrict__ cpos, const int* __restrict__ cneg,
    float* __restrict__ acc) {
  __shared__ int s_wp[4], s_wn[4];
  __shared__ int s_r[12];
  __shared__ float s_red[8];
  __shared__ float s_gt[NGT*4];
  int tid = threadIdx.x, img = blockIdx.y, bx = blockIdx.x;
  int lane = tid & 63, wid = tid >> 6;
  if (tid < NGT*4) s_gt[tid] = gt[img*NGT*4 + tid];
  // inline prefix over chunks: vp/vn = counts before this chunk; tp = total pos
  int vp=0, vn=0, tp=0;
  for (int k=tid; k<NCHUNK; k+=256){
    int cp = cpos[img*NCHUNK + k];
    int cn = cneg[img*NCHUNK + k];
    tp += cp;
    if (k < bx){ vp += cp; vn += cn; }
  }
  for (int of=32; of>0; of>>=1){
    vp += __shfl_down(vp, of, 64);
    vn += __shfl_down(vn, of, 64);
    tp += __shfl_down(tp, of, 64);
  }
  if (lane==0){ s_r[wid]=vp; s_r[4+wid]=vn; s_r[8+wid]=tp; }
  __syncthreads();                           // also covers s_gt
  int pre_p = s_r[0]+s_r[1]+s_r[2]+s_r[3];
  int pre_n = s_r[4]+s_r[5]+s_r[6]+s_r[7];
  int totp  = s_r[8]+s_r[9]+s_r[10]+s_r[11];
  int np = totp < 128 ? totp : 128;
  int nn = 256 - np;
  int r = bx*256 + tid;
  size_t o = (size_t)img*R_ANCH + r;
  int lab = label[o];
  bool pos = (lab==1), neg = (lab==0);
  u64 bp = __ballot(pos), bn = __ballot(neg);
  if (lane==0){ s_wp[wid]=__popcll(bp); s_wn[wid]=__popcll(bn); }
  __syncthreads();
  for (int w=0; w<wid; ++w){ pre_p += s_wp[w]; pre_n += s_wn[w]; }
  u64 lm = (1ull<<lane) - 1ull;
  pre_p += __popcll(bp & lm);
  pre_n += __popcll(bn & lm);
  bool kp = pos && (pre_p < np);
  bool kn = neg && (pre_n < nn);
  float c_cls = 0.0f, c_loc = 0.0f;
  if (kp || kn){
    // ---- per-anchor best IoU (verbatim old-kA arithmetic) ----
    float4 a = ((const float4*)anchors)[r];
    float aA = (a.z-a.x)*(a.w-a.y);
    float bi = -1.0f, bu = 1.0f; int idx = 0;
#pragma unroll 4
    for (int g=0; g<NGT; ++g){
      float g0=s_gt[g*4], g1=s_gt[g*4+1], g2=s_gt[g*4+2], g3=s_gt[g*4+3];
      float ga=(g2-g0)*(g3-g1);
      float lx=fmaxf(g0,a.x), ly=fmaxf(g1,a.y);
      float rx=fminf(g2,a.z), ry=fminf(g3,a.w);
      float iw=fmaxf(rx-lx,0.0f), ih=fmaxf(ry-ly,0.0f);
      float inter=iw*ih;
      float uni = fmaxf(ga + aA - inter, 1e-9f);
      if (inter*bu > bi*uni){ bi=inter; bu=uni; idx=g; }
    }
    float vbest = bi/bu;
    // ---- NLL (verbatim old-kA arithmetic) ----
    size_t base = (size_t)img*KMIX*R_ANCH + r;
    float p[KMIX], m[KMIX], s[KMIX];
#pragma unroll
    for (int k=0;k<KMIX;k++){
      p[k]=pi[base+(size_t)k*R_ANCH];
      m[k]=mu[base+(size_t)k*R_ANCH];
      s[k]=sigma[base+(size_t)k*R_ANCH];
    }
    float mx = p[0];
#pragma unroll
    for (int k=1;k<KMIX;k++) mx = fmaxf(mx,p[k]);
    float e[KMIX]; float sum = 0.0f;
#pragma unroll
    for (int k=0;k<KMIX;k++){ e[k]=expf(p[k]-mx); sum += e[k]; }
    float lsum = logf(sum);
    float t_ = fminf(fmaxf(vbest, 0.0f), 1.0f);
    float comp[KMIX];
#pragma unroll
    for (int k=0;k<KMIX;k++){
      float z = (t_ - m[k]) / s[k];
      comp[k] = (p[k]-mx-lsum) - 0.5f*z*z - logf(s[k]) - HALF_L2PI;
    }
    float cm = comp[0];
#pragma unroll
    for (int k=1;k<KMIX;k++) cm = fmaxf(cm, comp[k]);
    float se = 0.0f;
#pragma unroll
    for (int k=0;k<KMIX;k++) se += expf(comp[k]-cm);
    c_cls = -(cm + logf(se));
    if (kp){
      // ---- loc L1 vs matched gt (verbatim old-kA arithmetic) ----
      const float* gb = &s_gt[idx*4];
      float sw = a.z-a.x, sh = a.w-a.y;
      float scx = a.x+0.5f*sw, scy = a.y+0.5f*sh;
      float tw = gb[2]-gb[0], th = gb[3]-gb[1];
      float tcx = gb[0]+0.5f*tw, tcy = gb[1]+0.5f*th;
      float4 d = ((const float4*)deltas)[(size_t)img*R_ANCH + r];
      c_loc = fabsf(d.x-(tcx-scx)/sw) + fabsf(d.y-(tcy-scy)/sh)
            + fabsf(d.z-logf(tw/sw)) + fabsf(d.w-logf(th/sh));
    }
  }
  for (int of=32; of>0; of>>=1){
    c_cls += __shfl_down(c_cls, of, 64);
    c_loc += __shfl_down(c_loc, of, 64);
  }
  if (lane==0){ s_red[wid]=c_cls; s_red[4+wid]=c_loc; }
  __syncthreads();
  if (tid==0){
    float a = s_red[0]+s_red[1]+s_red[2]+s_red[3];
    float b = s_red[4]+s_red[5]+s_red[6]+s_red[7];
    if (a != 0.0f) atomicAdd(&acc[0], a);
    if (b != 0.0f) atomicAdd(&acc[1], b);
  }
}

// ---------------- host-side launch ----------------------------------------
extern "C" void kernel_launch(void* const* d_in, const int* in_sizes, int n_in,
                              void* d_out, int out_size, void* d_ws, size_t ws_size,
                              hipStream_t stream) {
  const float* anchors = (const float*)d_in[0];
  const float* pi      = (const float*)d_in[1];
  const float* mu      = (const float*)d_in[2];
  const float* sigma   = (const float*)d_in[3];
  const float* deltas  = (const float*)d_in[4];
  const float* gt      = (const float*)d_in[5];
  float* out = (float*)d_out;

  char* ws = (char*)d_ws;
  size_t off = 0;
  auto alloc = [&](size_t bytes) -> void* {
    void* p = (void*)(ws + off);
    off += (bytes + 255) & ~(size_t)255;
    return p;
  };
  float* logits = (float*)alloc((size_t)NIMG*R_ANCH*4);
  float* epis   = (float*)alloc((size_t)NIMG*R_ANCH*4);
  float* alea   = (float*)alloc((size_t)NIMG*R_ANCH*4);
  float* tb     = (float*)alloc((size_t)NIMG*PRE*4*4);
  float* tu     = (float*)alloc((size_t)NIMG*PRE*2*4);
  float* ts     = (float*)alloc((size_t)NIMG*PRE*4);
  u64*   maskLT = (u64*)  alloc((size_t)NIMG*32*MROW*8);
  u16*   slist  = (u16*)  alloc((size_t)NIMG*2048*SCAP*2);
  u64*   cand   = (u64*)  alloc((size_t)NIMG*CAND_CAP*8);
  int*   cpos   = (int*)  alloc((size_t)NIMG*NCHUNK*4);
  int*   cneg   = (int*)  alloc((size_t)NIMG*NCHUNK*4);
  // ---- contiguous zero region ----
  size_t zstart = off;
  u32*   hist0  = (u32*)  alloc((size_t)NIMG*2048*4);
  u32*   hist1  = (u32*)  alloc((size_t)NIMG*2048*4);
  u32*   hist2  = (u32*)  alloc((size_t)NIMG*2048*4);
  u32*   gcnt   = (u32*)  alloc((size_t)NIMG*GC_STRIDE*4);
  int*   best   = (int*)  alloc((size_t)NIMG*NGT*4);
  u32*   scnt   = (u32*)  alloc((size_t)NIMG*2048*4);
  float* acc    = (float*)alloc(8);
  int zwords = (int)((off - zstart) / 4);
  // label aliases logits: logits last read in kGather; kL2 runs after it.
  signed char* label = (signed char*)logits;

  kZero<<<dim3(64), dim3(256), 0, stream>>>((u32*)(ws + zstart), zwords);
  kA_mdn<<<dim3(ACHUNK+NBLK, NIMG), dim3(256), 0, stream>>>(pi, mu, sigma, logits, epis, alea,
                                                            hist0, anchors, gt, best);
  kP1<<<dim3(NBLK, NIMG), dim3(256), 0, stream>>>(logits, hist0, hist1);
  kP2<<<dim3(NBLK, NIMG), dim3(256), 0, stream>>>(logits, hist0, hist1, hist2);
  kGather<<<dim3(NBLK, NIMG), dim3(256), 0, stream>>>(logits, hist0, hist1, hist2, cand, gcnt);
  kRank<<<dim3(NIMG), dim3(1024), 0, stream>>>(cand, gcnt, epis, alea, deltas, anchors, tb, tu, ts);
  kD_mask<<<dim3(32, NIMG), dim3(1024), 0, stream>>>(tb, maskLT, scnt, slist);
  kL2_label<<<dim3(NCHUNK, NIMG), dim3(256), 0, stream>>>(anchors, gt, best, label, cpos, cneg);
  kL4_accum<<<dim3(NCHUNK, NIMG), dim3(256), 0, stream>>>(label, pi, mu, sigma, anchors, gt, deltas,
                                                          cpos, cneg, acc);
  kEF_nms<<<dim3(NIMG), dim3(1024), 0, stream>>>(maskLT, scnt, slist, tb, tu, ts, acc, out);
}

// Round 18
// 259.870 us; speedup vs baseline: 1.2322x; 1.0352x over previous
//
#include <hip/hip_runtime.h>
#include <cstdint>
#include <cstddef>

typedef unsigned long long u64;
typedef unsigned int u32;
typedef unsigned short u16;
typedef unsigned char u8;

#define R_ANCH 96000
#define R4     24000 // R_ANCH / 4 (float4 units)
#define NIMG   8
#define KMIX   5
#define PRE    2000
#define POST   1000
#define NGT    32
#define NCHUNK 375   // R_ANCH / 256 (label/loss kernels)
#define ACHUNK 94    // ceil(R4 / 256) — kA main blocks (4 anchors/thread)
#define NBLK   48    // blocks per image for parallel scan kernels
#define MROW   2048  // maskLT row stride (padded PRE)
#define SCAP   16    // per-row suppressor-list capacity (overflow -> dense path)
#define BIG_TH 64    // kRank: bins larger than this get level-1 split
#define CAP_BIN 6144 // refinement trigger: crossing-bin count above this -> refine
#define CAND_CAP 8192// global/LDS candidate capacity (PRE-1 + CAP_BIN = 8143 max)
#define GC_STRIDE 16 // gcnt padding: 64 B per image

#define IMG_SZ        1280.0f
#define NMS_T         0.7f
#define SCALE_CLAMP_F 4.135166556742356f
#define HALF_L2PI     0.9189385332046727f

__device__ __forceinline__ u64 make_key(float s, int r) {
  u32 u = __float_as_uint(s);
  u = (u & 0x80000000u) ? ~u : (u | 0x80000000u);
  return ((u64)u << 32) | (u64)(0xFFFFFFFFu - (u32)r);
}

__device__ __forceinline__ float dec_score(u64 key) {
  u32 o = (u32)(key >> 32);
  u32 bits = (o & 0x80000000u) ? (o ^ 0x80000000u) : ~o;
  return __uint_as_float(bits);
}

// EXACT-PATH IoU (NMS only): must match reference bit-for-bit since NMS
// decisions select whole boxes. Label-path code uses division-free
// cross-multiplied compares (loss-only, high tolerance).
__device__ __forceinline__ float iou_pair(float a0,float a1,float a2,float a3,
                                          float b0,float b1,float b2,float b3) {
#pragma clang fp contract(off)
  float areaA = (a2-a0)*(a3-a1);
  float areaB = (b2-b0)*(b3-b1);
  float lx=fmaxf(a0,b0), ly=fmaxf(a1,b1);
  float rx=fminf(a2,b2), ry=fminf(a3,b3);
  float iw=fmaxf(rx-lx,0.0f), ih=fmaxf(ry-ly,0.0f);
  float inter=iw*ih;
  return inter / fmaxf(areaA+areaB-inter, 1e-9f);
}

// pick: from a 2048-bin histogram (bin d high = higher keys), find the bin
// containing the k-th largest key. 256 threads. s_i >= 8 ints, s_u >= 3 u32.
__device__ __forceinline__ void pick2048(const u32* __restrict__ hist, int k,
                                         int* s_i, u32* s_u,
                                         int& d_out, int& k_out, u32& cnt_out) {
  int tid = threadIdx.x;
  int lane = tid & 63, w = tid >> 6;
  u32 h[8]; u32 ssum = 0;
#pragma unroll
  for (int i=0;i<8;++i){ h[i] = hist[2047 - (tid*8 + i)]; ssum += h[i]; }
  u32 incl = ssum;
  for (int off=1; off<64; off<<=1){
    u32 t = (u32)__shfl_up((int)incl, off, 64);
    if (lane >= off) incl += t;
  }
  if (lane==63) s_i[w] = (int)incl;
  __syncthreads();
  u32 base = 0;
  for (int ww=0; ww<w; ++ww) base += (u32)s_i[ww];
  u32 run = base + incl - ssum;              // exclusive prefix (descending keys)
#pragma unroll
  for (int i=0;i<8;++i){
    u32 nr = run + h[i];
    if (run < (u32)k && nr >= (u32)k){       // unique crossing thread
      s_u[0] = (u32)(2047 - (tid*8+i));
      s_u[1] = (u32)k - run;
      s_u[2] = h[i];
    }
    run = nr;
  }
  __syncthreads();
  d_out = (int)s_u[0]; k_out = (int)s_u[1]; cnt_out = s_u[2];
  __syncthreads();
}

// descending exclusive prefix over 2048 bins, 1024 threads (2 bins/thread).
// Caller must __syncthreads() before (h ready) and after (off ready).
__device__ __forceinline__ void scan2048_desc(const u32* __restrict__ h,
                                              u32* __restrict__ off,
                                              u32* __restrict__ wsum, int tid) {
  int b_hi = 2047 - 2*tid, b_lo = b_hi - 1;
  u32 h_hi = h[b_hi], h_lo = h[b_lo];
  u32 sum = h_hi + h_lo;
  u32 incl = sum;
  int lane = tid & 63, wv = tid >> 6;
  for (int o=1; o<64; o<<=1){
    u32 t = (u32)__shfl_up((int)incl, o, 64);
    if (lane >= o) incl += t;
  }
  if (lane==63) wsum[wv] = incl;
  __syncthreads();
  u32 base = 0;
  for (int w=0; w<wv; ++w) base += wsum[w];
  u32 excl = base + incl - sum;
  off[b_hi] = excl;
  off[b_lo] = excl + h_hi;
}

// ---------------- zero: contiguous workspace region -----------------------
__global__ void kZero(u32* z, int nwords) {
  for (int i = blockIdx.x*256 + threadIdx.x; i < nwords; i += gridDim.x*256)
    z[i] = 0u;
}

// ---------------- A: MDN moments + hist0 — float4 (4 anchors/thread) ------
// R16 post-mortem: kA floor ~46-49 us across float4/launch-bounds/float2
// variants — structural. Reverted to the best-measured variant (R9 float4,
// 263.4 us total). kA optimization retired; this round hides kL2/kL4.
// blocks [0, ACHUNK): main body; [ACHUNK, ACHUNK+NBLK): fused L1 best-gt.
__global__ __launch_bounds__(256) void kA_mdn(
    const float* __restrict__ pi, const float* __restrict__ mu,
    const float* __restrict__ sigma, float* __restrict__ logits,
    float* __restrict__ epis, float* __restrict__ alea,
    u32* __restrict__ hist0,
    const float* __restrict__ anchors, const float* __restrict__ gt,
    int* __restrict__ best) {
  __shared__ u32 s_h[2048];
  __shared__ float s_gt[NGT*4];
  __shared__ float s_ga[NGT];
  __shared__ int s_best[NGT];
  int tid = threadIdx.x;
  int img = blockIdx.y;

  if (blockIdx.x >= ACHUNK) {
    // ---------------- fused L1 body (block-uniform branch) ----------------
    int bx = blockIdx.x - ACHUNK;
    if (tid < NGT*4) s_gt[tid] = gt[img*NGT*4 + tid];
    if (tid < NGT){
      const float* g4 = gt + img*NGT*4 + tid*4;
      s_ga[tid] = (g4[2]-g4[0])*(g4[3]-g4[1]);
      s_best[tid] = 0;
    }
    __syncthreads();
    float4 an[8]; float aA[8];
#pragma unroll
    for (int q=0; q<8; ++q){
      int r = bx*256 + tid + q*(NBLK*256);
      an[q] = (r < R_ANCH) ? ((const float4*)anchors)[r]
                           : make_float4(0.f,0.f,0.f,0.f);   // IoU=0, inert
      aA[q] = (an[q].z-an[q].x)*(an[q].w-an[q].y);
    }
    float vmax[NGT];
#pragma unroll 2
    for (int g=0; g<NGT; ++g){
      float g0=s_gt[g*4], g1=s_gt[g*4+1], g2=s_gt[g*4+2], g3=s_gt[g*4+3];
      float ga=s_ga[g];
      float bi=0.0f, bu=1.0f;               // v=0 baseline
#pragma unroll
      for (int q=0; q<8; ++q){
        float lx=fmaxf(g0,an[q].x), ly=fmaxf(g1,an[q].y);
        float rx=fminf(g2,an[q].z), ry=fminf(g3,an[q].w);
        float iw=fmaxf(rx-lx,0.0f), ih=fmaxf(ry-ly,0.0f);
        float inter=iw*ih;
        float uni=fmaxf(ga+aA[q]-inter,1e-9f);
        if (inter*bu > bi*uni){ bi=inter; bu=uni; }
      }
      vmax[g] = bi/bu;
    }
    int lane = tid & 63;
#pragma unroll
    for (int g=0; g<NGT; ++g){
      float v = vmax[g];
      v = fmaxf(v, __shfl_xor(v, 1, 64));
      v = fmaxf(v, __shfl_xor(v, 2, 64));
      v = fmaxf(v, __shfl_xor(v, 4, 64));
      v = fmaxf(v, __shfl_xor(v, 8, 64));
      v = fmaxf(v, __shfl_xor(v,16, 64));
      v = fmaxf(v, __shfl_xor(v,32, 64));
      if (lane==0 && v > 0.0f) atomicMax(&s_best[g], __float_as_int(v));
    }
    __syncthreads();
    if (tid < NGT) atomicMax(&best[img*NGT + tid], s_best[tid]);
    return;
  }

  // ---------------- main MDN body: 4 anchors per thread ----------------
  int r4 = blockIdx.x*256 + tid;             // float4 index within image
  bool act = (r4 < R4);
  for (int b=tid; b<2048; b+=256) s_h[b]=0u;
  float4 lg4, ep4, al4;
  u64 keys[4];
  if (act){
    const float4* pi4 = (const float4*)pi;
    const float4* mu4 = (const float4*)mu;
    const float4* sg4 = (const float4*)sigma;
    size_t base = (size_t)img*KMIX*R4 + r4;
    float4 p4[KMIX], m4[KMIX], s4[KMIX];
#pragma unroll
    for (int k=0;k<KMIX;k++){
      p4[k]=pi4[base+(size_t)k*R4];
      m4[k]=mu4[base+(size_t)k*R4];
      s4[k]=sg4[base+(size_t)k*R4];
    }
    float lg_[4], ep_[4], al_[4];
#pragma unroll
    for (int j=0;j<4;++j){
      float p[KMIX], m[KMIX], s[KMIX];
#pragma unroll
      for (int k=0;k<KMIX;k++){
        p[k] = (&p4[k].x)[j];
        m[k] = (&m4[k].x)[j];
        s[k] = (&s4[k].x)[j];
      }
      float mx = p[0];
#pragma unroll
      for (int k=1;k<KMIX;k++) mx = fmaxf(mx,p[k]);
      float e[KMIX]; float sum = 0.0f;
#pragma unroll
      for (int k=0;k<KMIX;k++){ e[k]=expf(p[k]-mx); sum += e[k]; }
      float w[KMIX]; float lg = 0.0f;
#pragma unroll
      for (int k=0;k<KMIX;k++){ w[k]=e[k]/sum; lg += w[k]*m[k]; }
      float ep = 0.0f, al = 0.0f;
#pragma unroll
      for (int k=0;k<KMIX;k++){ float d=m[k]-lg; ep += w[k]*d*d; al += w[k]*s[k]*s[k]; }
      lg_[j]=lg; ep_[j]=ep; al_[j]=al;
      keys[j] = make_key(lg, r4*4 + j);
    }
    lg4 = make_float4(lg_[0],lg_[1],lg_[2],lg_[3]);
    ep4 = make_float4(ep_[0],ep_[1],ep_[2],ep_[3]);
    al4 = make_float4(al_[0],al_[1],al_[2],al_[3]);
    size_t o4 = (size_t)img*R4 + r4;
    ((float4*)logits)[o4] = lg4;
    ((float4*)epis)[o4]   = ep4;
    ((float4*)alea)[o4]   = al4;
  }
  __syncthreads();                           // s_h zero complete
  if (act){
#pragma unroll
    for (int j=0;j<4;++j)
      atomicAdd(&s_h[(u32)(keys[j]>>53)], 1u);
  }
  __syncthreads();
  for (int b=tid; b<2048; b+=256){ u32 v=s_h[b]; if(v) atomicAdd(&hist0[img*2048+b], v); }
}

// ---------------- P1+L2: refine hist (rare) ++ labels ride along ----------
// blocks [0, NBLK): P1 body (early-exit ~2us in common case — idle CUs);
// blocks [NBLK, NBLK+NCHUNK): kL2 label body (independent of selection
// chain; needs only kA's `best`). label is a SEPARATE buffer now (not
// aliasing logits) since logits is still read by kP2/kGather afterwards.
__global__ __launch_bounds__(256) void kP1L2(const float* __restrict__ logits,
    const u32* __restrict__ hist0, u32* __restrict__ hist1,
    const float* __restrict__ anchors, const float* __restrict__ gt,
    const int* __restrict__ best,
    signed char* __restrict__ label, int* __restrict__ cpos, int* __restrict__ cneg) {
  int img = blockIdx.y, tid = threadIdx.x;

  if (blockIdx.x >= NBLK) {
    // ---------------- L2 label body (verbatim kL2_label) ----------------
    __shared__ float s_gt[NGT*4];
    __shared__ float s_ga[NGT];
    __shared__ float s_bg[NGT];
    __shared__ int s_w[8];
    int bx = blockIdx.x - NBLK;
    int r = bx*256 + tid;
    if (tid < NGT*4) s_gt[tid] = gt[img*NGT*4 + tid];
    if (tid < NGT){
      const float* g4 = gt + img*NGT*4 + tid*4;
      s_ga[tid] = (g4[2]-g4[0])*(g4[3]-g4[1]);
      s_bg[tid] = __int_as_float(best[img*NGT + tid]);
    }
    __syncthreads();
    float4 a = ((const float4*)anchors)[r];
    float aA = (a.z-a.x)*(a.w-a.y);
    float bi=-1.0f, bu=1.0f; bool lq = false;
#pragma unroll 4
    for (int g=0; g<NGT; ++g){
      float g0=s_gt[g*4], g1=s_gt[g*4+1], g2=s_gt[g*4+2], g3=s_gt[g*4+3];
      float lx=fmaxf(g0,a.x), ly=fmaxf(g1,a.y);
      float rx=fminf(g2,a.z), ry=fminf(g3,a.w);
      float iw=fmaxf(rx-lx,0.0f), ih=fmaxf(ry-ly,0.0f);
      float inter=iw*ih;
      float uni = fmaxf(s_ga[g] + aA - inter, 1e-9f);
      if (inter*bu > bi*uni){ bi=inter; bu=uni; }
      float bg = s_bg[g];
      lq = lq || ((inter >= (bg - 1e-7f)*uni) && (bg > 0.0f));
    }
    float vbest = bi/bu;
    int lab = lq ? 1 : (vbest >= 0.7f ? 1 : (vbest >= 0.3f ? -1 : 0));
    label[(size_t)img*R_ANCH + r] = (signed char)lab;
    u64 bp = __ballot(lab==1), bn = __ballot(lab==0);
    int wid = tid>>6, lane = tid&63;
    if (lane==0){ s_w[wid*2]=__popcll(bp); s_w[wid*2+1]=__popcll(bn); }
    __syncthreads();
    if (tid==0){
      cpos[img*NCHUNK + bx] = s_w[0]+s_w[2]+s_w[4]+s_w[6];
      cneg[img*NCHUNK + bx] = s_w[1]+s_w[3]+s_w[5]+s_w[7];
    }
    return;
  }

  // ---------------- P1 body (verbatim) ----------------
  __shared__ u32 s_h[2048];
  __shared__ int s_i[8]; __shared__ u32 s_u[3];
  int d0,k0; u32 c0;
  pick2048(hist0 + img*2048, PRE, s_i, s_u, d0,k0,c0);
  if (c0 <= CAP_BIN) return;                 // block-uniform (common case)
  for (int b=tid; b<2048; b+=256) s_h[b]=0u;
  __syncthreads();
  const float* sc = logits + (size_t)img*R_ANCH;
  for (int r = blockIdx.x*256 + tid; r < R_ANCH; r += NBLK*256){
    u64 key = make_key(sc[r], r);
    if ((int)(key>>53) == d0) atomicAdd(&s_h[(u32)(key>>42)&2047u], 1u);
  }
  __syncthreads();
  for (int b=tid; b<2048; b+=256){ u32 v=s_h[b]; if(v) atomicAdd(&hist1[img*2048+b], v); }
}

// ---------------- P2: refine level-2 histogram (essentially never) --------
__global__ __launch_bounds__(256) void kP2(const float* __restrict__ logits,
                                           const u32* __restrict__ hist0,
                                           const u32* __restrict__ hist1,
                                           u32* __restrict__ hist2) {
  __shared__ u32 s_h[2048];
  __shared__ int s_i[8]; __shared__ u32 s_u[3];
  int img = blockIdx.y, tid = threadIdx.x;
  int d0,k0; u32 c0;
  pick2048(hist0 + img*2048, PRE, s_i, s_u, d0,k0,c0);
  if (c0 <= CAP_BIN) return;
  int d1,k1; u32 c1;
  pick2048(hist1 + img*2048, k0, s_i, s_u, d1,k1,c1);
  if (c1 <= CAP_BIN) return;
  u64 p1 = ((u64)d0<<11) | (u64)d1;
  for (int b=tid; b<2048; b+=256) s_h[b]=0u;
  __syncthreads();
  const float* sc = logits + (size_t)img*R_ANCH;
  for (int r = blockIdx.x*256 + tid; r < R_ANCH; r += NBLK*256){
    u64 key = make_key(sc[r], r);
    if ((key>>42) == p1) atomicAdd(&s_h[(u32)(key>>31)&2047u], 1u);
  }
  __syncthreads();
  for (int b=tid; b<2048; b+=256){ u32 v=s_h[b]; if(v) atomicAdd(&hist2[img*2048+b], v); }
}

// ---------------- G+L4: gather candidates ++ loss accumulation ------------
// blocks [0, NBLK): gather body; [NBLK, NBLK+NCHUNK): kL4 body. L4 needs
// label/cpos/cneg from the P1L2 dispatch (2 boundaries earlier — safe) and
// fills CU bubbles during the gather scan. acc is read only by kEF (last).
__global__ __launch_bounds__(256) void kGatherL4(const float* __restrict__ logits,
    const u32* __restrict__ hist0, const u32* __restrict__ hist1,
    const u32* __restrict__ hist2, u64* __restrict__ cand, u32* __restrict__ gcnt,
    const signed char* __restrict__ label,
    const float* __restrict__ pi, const float* __restrict__ mu,
    const float* __restrict__ sigma, const float* __restrict__ anchors,
    const float* __restrict__ gt, const float* __restrict__ deltas,
    const int* __restrict__ cpos, const int* __restrict__ cneg,
    float* __restrict__ acc) {
  int img = blockIdx.y, tid = threadIdx.x;

  if (blockIdx.x >= NBLK) {
    // ---------------- L4 body (verbatim kL4_accum) ----------------
    __shared__ int s_wp[4], s_wn[4];
    __shared__ int s_r[12];
    __shared__ float s_red[8];
    __shared__ float s_gt[NGT*4];
    int bx = blockIdx.x - NBLK;
    int lane = tid & 63, wid = tid >> 6;
    if (tid < NGT*4) s_gt[tid] = gt[img*NGT*4 + tid];
    int vp=0, vn=0, tp=0;
    for (int k=tid; k<NCHUNK; k+=256){
      int cp = cpos[img*NCHUNK + k];
      int cn = cneg[img*NCHUNK + k];
      tp += cp;
      if (k < bx){ vp += cp; vn += cn; }
    }
    for (int of=32; of>0; of>>=1){
      vp += __shfl_down(vp, of, 64);
      vn += __shfl_down(vn, of, 64);
      tp += __shfl_down(tp, of, 64);
    }
    if (lane==0){ s_r[wid]=vp; s_r[4+wid]=vn; s_r[8+wid]=tp; }
    __syncthreads();                         // also covers s_gt
    int pre_p = s_r[0]+s_r[1]+s_r[2]+s_r[3];
    int pre_n = s_r[4]+s_r[5]+s_r[6]+s_r[7];
    int totp  = s_r[8]+s_r[9]+s_r[10]+s_r[11];
    int np = totp < 128 ? totp : 128;
    int nn = 256 - np;
    int r = bx*256 + tid;
    size_t o = (size_t)img*R_ANCH + r;
    int lab = label[o];
    bool pos = (lab==1), neg = (lab==0);
    u64 bp = __ballot(pos), bn = __ballot(neg);
    if (lane==0){ s_wp[wid]=__popcll(bp); s_wn[wid]=__popcll(bn); }
    __syncthreads();
    for (int w=0; w<wid; ++w){ pre_p += s_wp[w]; pre_n += s_wn[w]; }
    u64 lm = (1ull<<lane) - 1ull;
    pre_p += __popcll(bp & lm);
    pre_n += __popcll(bn & lm);
    bool kp = pos && (pre_p < np);
    bool kn = neg && (pre_n < nn);
    float c_cls = 0.0f, c_loc = 0.0f;
    if (kp || kn){
      float4 a = ((const float4*)anchors)[r];
      float aA = (a.z-a.x)*(a.w-a.y);
      float bi = -1.0f, bu = 1.0f; int idx = 0;
#pragma unroll 4
      for (int g=0; g<NGT; ++g){
        float g0=s_gt[g*4], g1=s_gt[g*4+1], g2=s_gt[g*4+2], g3=s_gt[g*4+3];
        float ga=(g2-g0)*(g3-g1);
        float lx=fmaxf(g0,a.x), ly=fmaxf(g1,a.y);
        float rx=fminf(g2,a.z), ry=fminf(g3,a.w);
        float iw=fmaxf(rx-lx,0.0f), ih=fmaxf(ry-ly,0.0f);
        float inter=iw*ih;
        float uni = fmaxf(ga + aA - inter, 1e-9f);
        if (inter*bu > bi*uni){ bi=inter; bu=uni; idx=g; }
      }
      float vbest = bi/bu;
      size_t base = (size_t)img*KMIX*R_ANCH + r;
      float p[KMIX], m[KMIX], s[KMIX];
#pragma unroll
      for (int k=0;k<KMIX;k++){
        p[k]=pi[base+(size_t)k*R_ANCH];
        m[k]=mu[base+(size_t)k*R_ANCH];
        s[k]=sigma[base+(size_t)k*R_ANCH];
      }
      float mx = p[0];
#pragma unroll
      for (int k=1;k<KMIX;k++) mx = fmaxf(mx,p[k]);
      float e[KMIX]; float sum = 0.0f;
#pragma unroll
      for (int k=0;k<KMIX;k++){ e[k]=expf(p[k]-mx); sum += e[k]; }
      float lsum = logf(sum);
      float t_ = fminf(fmaxf(vbest, 0.0f), 1.0f);
      float comp[KMIX];
#pragma unroll
      for (int k=0;k<KMIX;k++){
        float z = (t_ - m[k]) / s[k];
        comp[k] = (p[k]-mx-lsum) - 0.5f*z*z - logf(s[k]) - HALF_L2PI;
      }
      float cm = comp[0];
#pragma unroll
      for (int k=1;k<KMIX;k++) cm = fmaxf(cm, comp[k]);
      float se = 0.0f;
#pragma unroll
      for (int k=0;k<KMIX;k++) se += expf(comp[k]-cm);
      c_cls = -(cm + logf(se));
      if (kp){
        const float* gb = &s_gt[idx*4];
        float sw = a.z-a.x, sh = a.w-a.y;
        float scx = a.x+0.5f*sw, scy = a.y+0.5f*sh;
        float tw = gb[2]-gb[0], th = gb[3]-gb[1];
        float tcx = gb[0]+0.5f*tw, tcy = gb[1]+0.5f*th;
        float4 d = ((const float4*)deltas)[(size_t)img*R_ANCH + r];
        c_loc = fabsf(d.x-(tcx-scx)/sw) + fabsf(d.y-(tcy-scy)/sh)
              + fabsf(d.z-logf(tw/sw)) + fabsf(d.w-logf(th/sh));
      }
    }
    for (int of=32; of>0; of>>=1){
      c_cls += __shfl_down(c_cls, of, 64);
      c_loc += __shfl_down(c_loc, of, 64);
    }
    if (lane==0){ s_red[wid]=c_cls; s_red[4+wid]=c_loc; }
    __syncthreads();
    if (tid==0){
      float a = s_red[0]+s_red[1]+s_red[2]+s_red[3];
      float b = s_red[4]+s_red[5]+s_red[6]+s_red[7];
      if (a != 0.0f) atomicAdd(&acc[0], a);
      if (b != 0.0f) atomicAdd(&acc[1], b);
    }
    return;
  }

  // ---------------- gather body (verbatim kGather) ----------------
  __shared__ int s_i[8]; __shared__ u32 s_u[3];
  __shared__ u64 s_cand[2048];               // 16 KB staging (block take <= 2048)
  __shared__ u32 s_cnt, s_base;
  if (tid==0) s_cnt = 0u;
  int d,kk; u32 c;
  pick2048(hist0 + img*2048, PRE, s_i, s_u, d,kk,c);   // has syncthreads
  u64 p = (u64)d; int L = 0;
  if (c > CAP_BIN){
    pick2048(hist1 + img*2048, kk, s_i, s_u, d,kk,c);
    p = (p<<11)|(u64)d; L = 1;
    if (c > CAP_BIN){
      pick2048(hist2 + img*2048, kk, s_i, s_u, d,kk,c);
      p = (p<<11)|(u64)d; L = 2;
    }
  }
  u64 T = p << (64 - 11*(L+1));              // total candidates <= 8143
  const float* sc = logits + (size_t)img*R_ANCH;
  int lane = tid & 63;
  for (int r = blockIdx.x*256 + tid; r < R_ANCH; r += NBLK*256){
    u64 key = make_key(sc[r], r);
    bool take = (key >= T);
    u64 b = __ballot(take);
    if (b){
      u32 base = 0;
      if (lane==0) base = atomicAdd(&s_cnt, (u32)__popcll(b));   // LDS atomic
      base = (u32)__shfl((int)base, 0, 64);
      if (take){
        u32 pos = base + (u32)__popcll(b & ((1ull<<lane)-1ull));
        if (pos < 2048u) s_cand[pos] = key;
        else {                               // correctness net (block take > 2048)
          u32 gp = atomicAdd(&gcnt[img*GC_STRIDE], 1u);
          if (gp < CAND_CAP) cand[(size_t)img*CAND_CAP + gp] = key;
        }
      }
    }
  }
  __syncthreads();
  u32 n = s_cnt < 2048u ? s_cnt : 2048u;
  if (tid==0) s_base = atomicAdd(&gcnt[img*GC_STRIDE], n);  // 1 atomic/block
  __syncthreads();
  u32 gb = s_base;
  for (u32 i=tid; i<n; i+=256)
    cand[(size_t)img*CAND_CAP + gb + i] = s_cand[i];
}

// ---------------- R: hierarchical exact bucket-rank + epilogue ------------
// Bins > BIG_TH members get a sequential level-1 split by digit1 (bits
// 52..42) -> sub-bins of ~1-3; compare loops trivial. Bins with base >= PRE
// pruned. Exact. Capacity 8192 (CAP_BIN=6144 + PRE-1 = 8143 max).
__global__ __launch_bounds__(1024) void kRank(
    const u64* __restrict__ cand, const u32* __restrict__ gcnt,
    const float* __restrict__ epis, const float* __restrict__ alea,
    const float* __restrict__ deltas, const float* __restrict__ anchors,
    float* __restrict__ tb, float* __restrict__ tu, float* __restrict__ ts) {
  __shared__ u64 s_key[CAND_CAP];            // 64 KB
  __shared__ u16 s_idx0[CAND_CAP];           // 16 KB
  __shared__ u16 s_idx1[CAND_CAP];           // 16 KB (per big bin, reused)
  __shared__ u32 s_h0[2048];                 // 8 KB
  __shared__ u32 s_off0[2048];               // 8 KB (excl; scatter makes base+size)
  __shared__ u32 s_h1[2048];                 // 8 KB
  __shared__ u32 s_off1[2048];               // 8 KB
  __shared__ u32 s_wsum[16];
  __shared__ u32 s_nbig;
  __shared__ u16 s_big[128];
  int tid = threadIdx.x, img = blockIdx.x;
  u32 cnt = gcnt[img*GC_STRIDE];
  if (cnt > (u32)CAND_CAP) cnt = CAND_CAP;
  const u64* cp = cand + (size_t)img*CAND_CAP;
  for (int i=tid; i<CAND_CAP; i+=1024) s_key[i] = (i < (int)cnt) ? cp[i] : 0ull;
  for (int b=tid; b<2048; b+=1024){ s_h0[b] = 0u; }
  if (tid==0) s_nbig = 0u;
  __syncthreads();
  for (int i=tid; i<(int)cnt; i+=1024)
    atomicAdd(&s_h0[(u32)(s_key[i]>>53)], 1u);
  __syncthreads();
  scan2048_desc(s_h0, s_off0, s_wsum, tid);
  __syncthreads();
  // collect big bins that can contribute ranks < PRE
  for (int b=tid; b<2048; b+=1024){
    u32 sz = s_h0[b];
    if (sz > BIG_TH && s_off0[b] < PRE){
      u32 q = atomicAdd(&s_nbig, 1u);
      if (q < 128u) s_big[q] = (u16)b;
    }
  }
  __syncthreads();                           // collect/scatter ordering
  // scatter candidates into digit0-bucket order
  for (int i=tid; i<(int)cnt; i+=1024){
    u32 d = (u32)(s_key[i]>>53);
    u32 slot = atomicAdd(&s_off0[d], 1u);    // post: s_off0[d] = base + size
    s_idx0[slot] = (u16)i;
  }
  __syncthreads();
  // epilogue writer
  auto emit = [&](u64 my, u32 rank){
    if (rank < PRE){
      int p = (int)rank;
      u32 idx = 0xFFFFFFFFu - (u32)(my & 0xFFFFFFFFull);
      ts[img*PRE + p] = dec_score(my);
      float4 a = ((const float4*)anchors)[idx];
      float4 dd = ((const float4*)deltas)[(size_t)img*R_ANCH + idx];
      float w = a.z - a.x, h = a.w - a.y;
      float cx = a.x + 0.5f*w, cy = a.y + 0.5f*h;
      float dw = fminf(dd.z, SCALE_CLAMP_F), dh = fminf(dd.w, SCALE_CLAMP_F);
      float pcx = dd.x*w + cx, pcy = dd.y*h + cy;
      float pw = expf(dw)*w, ph = expf(dh)*h;
      float x0 = fminf(fmaxf(pcx - 0.5f*pw, 0.0f), IMG_SZ);
      float y0 = fminf(fmaxf(pcy - 0.5f*ph, 0.0f), IMG_SZ);
      float x1 = fminf(fmaxf(pcx + 0.5f*pw, 0.0f), IMG_SZ);
      float y1 = fminf(fmaxf(pcy + 0.5f*ph, 0.0f), IMG_SZ);
      ((float4*)tb)[(size_t)img*PRE + p] = make_float4(x0,y0,x1,y1);
      size_t o = (size_t)img*R_ANCH + idx;
      ((float2*)tu)[(size_t)img*PRE + p] = make_float2(epis[o], alea[o]);
    }
  };
  // small bins: direct compare loop (size <= BIG_TH)
  for (int i=tid; i<(int)cnt; i+=1024){
    u64 my = s_key[i];
    u32 d = (u32)(my>>53);
    u32 size = s_h0[d];
    if (size > BIG_TH) continue;             // handled below
    u32 bs = s_off0[d] - size;
    if (bs >= PRE) continue;                 // cannot produce rank < PRE
    u32 rank = bs;
    for (u32 q=bs; q<bs+size; ++q)
      rank += (s_key[s_idx0[q]] > my) ? 1u : 0u;
    emit(my, rank);
  }
  __syncthreads();
  u32 nbig = s_nbig < 128u ? s_nbig : 128u;
  for (u32 bb=0; bb<nbig; ++bb){             // block-uniform sequential loop
    u32 B = s_big[bb];
    u32 size = s_h0[B];
    u32 base0 = s_off0[B] - size;
    for (int b=tid; b<2048; b+=1024) s_h1[b] = 0u;
    __syncthreads();
    for (u32 q=tid; q<size; q+=1024){
      u64 k = s_key[s_idx0[base0+q]];
      atomicAdd(&s_h1[(u32)(k>>42)&2047u], 1u);
    }
    __syncthreads();
    scan2048_desc(s_h1, s_off1, s_wsum, tid);
    __syncthreads();
    for (u32 q=tid; q<size; q+=1024){
      u16 ci = s_idx0[base0+q];
      u64 k = s_key[ci];
      u32 slot = atomicAdd(&s_off1[(u32)(k>>42)&2047u], 1u);
      s_idx1[slot] = ci;
    }
    __syncthreads();
    for (u32 q=tid; q<size; q+=1024){
      u16 ci = s_idx1[q];
      u64 my = s_key[ci];
      u32 d1 = (u32)(my>>42)&2047u;
      u32 ssz = s_h1[d1];
      u32 sbs = s_off1[d1] - ssz;            // sub-bin base (within bin)
      u32 rank = base0 + sbs;
      for (u32 t2=sbs; t2<sbs+ssz; ++t2)
        rank += (s_key[s_idx1[t2]] > my) ? 1u : 0u;
      emit(my, rank);
    }
    __syncthreads();                         // s_h1/s_off1/s_idx1 reuse
  }
}

// ---------------- D: masks + sparse suppressor lists (EXACT IoU) ----------
__global__ __launch_bounds__(1024) void kD_mask(const float* __restrict__ tb,
                                                u64* __restrict__ maskLT,
                                                u32* __restrict__ scnt,
                                                u16* __restrict__ slist) {
  __shared__ float4 s_tile[64];
  int tid = threadIdx.x;
  int a = blockIdx.x, img = blockIdx.y;
  const float4* tbi = (const float4*)tb + (size_t)img*PRE;
  if (tid < 64){
    int i = a*64 + tid;
    s_tile[tid] = (i < PRE) ? tbi[i] : make_float4(0.f,0.f,0.f,0.f);
  }
  __syncthreads();
  u64* outp = maskLT + ((size_t)img*32 + a)*MROW;
  u32* cnts = scnt + (size_t)img*2048;
  u16* lst  = slist + (size_t)img*2048*SCAP;
  int bmax = min(64, PRE - a*64);
  for (int j = a*64 + tid; j < MROW; j += 1024){
    u64 m = 0ull;
    if (j < PRE){
      float4 B = tbi[j];
      int blim = min(bmax, j - a*64);        // only b with a*64+b < j
      for (int b = 0; b < blim; ++b){
        float4 A = s_tile[b];
        float v = iou_pair(A.x,A.y,A.z,A.w, B.x,B.y,B.z,B.w);
        m |= (u64)(v > NMS_T) << b;
      }
    }
    outp[j] = m;
    u64 mm = m;
    while (mm){
      int b = __builtin_ctzll(mm); mm &= mm - 1ull;
      u32 slot = atomicAdd(&cnts[j], 1u);
      if (slot < SCAP) lst[(size_t)j*SCAP + slot] = (u16)(a*64 + b);
    }
  }
}

// ---------------- EF: greedy NMS fixpoint + final compaction + losses -----
__global__ __launch_bounds__(1024) void kEF_nms(const u64* __restrict__ maskLT,
    const u32* __restrict__ scnt, const u16* __restrict__ slist,
    const float* __restrict__ tb, const float* __restrict__ tu,
    const float* __restrict__ ts, const float* __restrict__ acc,
    float* __restrict__ out) {
  __shared__ u64 s_list64[2048*SCAP/4];      // 64 KB staged lists
  __shared__ u16 s_cnt[2048];                // 4 KB
  __shared__ u8  kbuf[2][2048];              // 4 KB
  __shared__ u64 s_kw[32];
  __shared__ int s_change, s_ovf;
  __shared__ int s_wk[16], s_wn[16];
  __shared__ int s_kc, s_runk, s_runn;
  int img = blockIdx.x, tid = threadIdx.x;
  int lane = tid & 63, wid = tid >> 6;
  const u64* gl = (const u64*)(slist + (size_t)img*2048*SCAP);
  for (int i=tid; i<2048*SCAP/4; i+=1024) s_list64[i] = gl[i];
  const u32* gc = scnt + (size_t)img*2048;
  for (int i=tid; i<2048; i+=1024) s_cnt[i] = (u16)gc[i];
  if (tid==0){ s_change = 0; s_ovf = 0; }
  __syncthreads();
  bool myovf = false;
#pragma unroll
  for (int q=0; q<2; ++q){
    int j = tid + q*1024;
    if (s_cnt[j] > SCAP) myovf = true;
    kbuf[0][j] = (j < PRE) ? 1 : 0;
  }
  if (myovf) s_ovf = 1;                      // benign race
  __syncthreads();
  const u64* MT = maskLT + (size_t)img*32*MROW;
  int cur = 0;
  for (int iter=0; iter<2048; ++iter){
    bool ovf = (s_ovf != 0);                 // stable after init barrier
    if (ovf && tid < 32){
      u64 w = 0ull;
      for (int b=0; b<64; ++b) w |= (u64)(kbuf[cur][tid*64+b] & 1) << b;
      s_kw[tid] = w;
    }
    __syncthreads();                         // A: s_change reset + kw visible
    bool changed = false;
#pragma unroll
    for (int q=0; q<2; ++q){
      int j = tid + q*1024;
      u8 old = kbuf[cur][j];
      u8 nk = (j < PRE) ? 1 : 0;
      if (nk){
        int cnt = s_cnt[j];
        if (cnt <= SCAP){
          const u16* lp = (const u16*)&s_list64[j*(SCAP/4)];
          for (int i=0; i<cnt; ++i){
            if (kbuf[cur][lp[i]]){ nk = 0; break; }
          }
        } else {
          int amax = j >> 6;
          for (int a=0; a<=amax; ++a){
            if (MT[(size_t)a*MROW + j] & s_kw[a]){ nk = 0; break; }
          }
        }
      }
      kbuf[1-cur][j] = nk;
      changed |= (nk != old);
    }
    if (changed) s_change = 1;
    __syncthreads();                         // B: all writes done
    int ch = s_change;
    __syncthreads();                         // C: all have read ch
    if (tid==0) s_change = 0;                // reset (visible by next A)
    if (!ch) break;                          // uniform
    cur ^= 1;
  }
  // ---- compaction (old kF), keep bits live in kbuf[cur] ----
  __syncthreads();
  const float4* tbi = (const float4*)tb + (size_t)img*PRE;
  const float NEG_INF = __uint_as_float(0xff800000u);
  u8* kf = kbuf[1-cur];                      // free buffer: keep&valid flags
#pragma unroll
  for (int cch=0; cch<2; ++cch){
    int pp = cch*1024 + tid;
    bool kp = false;
    if (pp < PRE && kbuf[cur][pp]){
      float4 b = tbi[pp];
      kp = (b.z > b.x) && (b.w > b.y);
    }
    kf[pp] = kp ? 1 : 0;
  }
  __syncthreads();
  {
    int cc = (int)kf[tid] + (int)kf[1024 + tid];
    for (int of=32; of>0; of>>=1) cc += __shfl_down(cc, of, 64);
    if (lane==0) s_wk[wid] = cc;
  }
  __syncthreads();
  if (tid==0){
    int t=0; for (int w=0; w<16; ++w) t += s_wk[w];
    s_kc = t; s_runk = 0; s_runn = 0;
  }
  __syncthreads();
  int kc = s_kc;
#pragma unroll
  for (int cch=0; cch<2; ++cch){
    int pp = cch*1024 + tid;
    bool kp = kf[pp] != 0;
    u64 bk = __ballot(kp), bn = __ballot(!kp);
    if (lane==0){ s_wk[wid]=__popcll(bk); s_wn[wid]=__popcll(bn); }
    __syncthreads();
    int pk = s_runk, pn = s_runn;
    for (int w=0; w<wid; ++w){ pk += s_wk[w]; pn += s_wn[w]; }
    u64 lm = (1ull<<lane) - 1ull;
    pk += __popcll(bk & lm);
    pn += __popcll(bn & lm);
    int slot = kp ? pk : (kc + pn);
    if (slot < POST && pp < PRE){
      ((float4*)out)[img*POST + slot] = tbi[pp];
      out[32000 + img*POST + slot] = kp ? ts[img*PRE + pp] : NEG_INF;
      ((float2*)(out + 40000))[img*POST + slot] = ((const float2*)tu)[(size_t)img*PRE + pp];
    }
    __syncthreads();
    if (tid==0){
      int tk=0, tn=0;
      for (int w=0; w<16; ++w){ tk += s_wk[w]; tn += s_wn[w]; }
      s_runk += tk; s_runn += tn;
    }
    __syncthreads();
  }
  if (img==0 && tid<2) out[56000+tid] = acc[tid] * (1.0f/2048.0f);
}

// ---------------- host-side launch ----------------------------------------
extern "C" void kernel_launch(void* const* d_in, const int* in_sizes, int n_in,
                              void* d_out, int out_size, void* d_ws, size_t ws_size,
                              hipStream_t stream) {
  const float* anchors = (const float*)d_in[0];
  const float* pi      = (const float*)d_in[1];
  const float* mu      = (const float*)d_in[2];
  const float* sigma   = (const float*)d_in[3];
  const float* deltas  = (const float*)d_in[4];
  const float* gt      = (const float*)d_in[5];
  float* out = (float*)d_out;

  char* ws = (char*)d_ws;
  size_t off = 0;
  auto alloc = [&](size_t bytes) -> void* {
    void* p = (void*)(ws + off);
    off += (bytes + 255) & ~(size_t)255;
    return p;
  };
  float* logits = (float*)alloc((size_t)NIMG*R_ANCH*4);
  float* epis   = (float*)alloc((size_t)NIMG*R_ANCH*4);
  float* alea   = (float*)alloc((size_t)NIMG*R_ANCH*4);
  signed char* label = (signed char*)alloc((size_t)NIMG*R_ANCH);  // own buffer (L2 runs early now)
  float* tb     = (float*)alloc((size_t)NIMG*PRE*4*4);
  float* tu     = (float*)alloc((size_t)NIMG*PRE*2*4);
  float* ts     = (float*)alloc((size_t)NIMG*PRE*4);
  u64*   maskLT = (u64*)  alloc((size_t)NIMG*32*MROW*8);
  u16*   slist  = (u16*)  alloc((size_t)NIMG*2048*SCAP*2);
  u64*   cand   = (u64*)  alloc((size_t)NIMG*CAND_CAP*8);
  int*   cpos   = (int*)  alloc((size_t)NIMG*NCHUNK*4);
  int*   cneg   = (int*)  alloc((size_t)NIMG*NCHUNK*4);
  // ---- contiguous zero region ----
  size_t zstart = off;
  u32*   hist0  = (u32*)  alloc((size_t)NIMG*2048*4);
  u32*   hist1  = (u32*)  alloc((size_t)NIMG*2048*4);
  u32*   hist2  = (u32*)  alloc((size_t)NIMG*2048*4);
  u32*   gcnt   = (u32*)  alloc((size_t)NIMG*GC_STRIDE*4);
  int*   best   = (int*)  alloc((size_t)NIMG*NGT*4);
  u32*   scnt   = (u32*)  alloc((size_t)NIMG*2048*4);
  float* acc    = (float*)alloc(8);
  int zwords = (int)((off - zstart) / 4);

  kZero<<<dim3(64), dim3(256), 0, stream>>>((u32*)(ws + zstart), zwords);
  kA_mdn<<<dim3(ACHUNK+NBLK, NIMG), dim3(256), 0, stream>>>(pi, mu, sigma, logits, epis, alea,
                                                            hist0, anchors, gt, best);
  kP1L2<<<dim3(NBLK+NCHUNK, NIMG), dim3(256), 0, stream>>>(logits, hist0, hist1,
                                                           anchors, gt, best, label, cpos, cneg);
  kP2<<<dim3(NBLK, NIMG), dim3(256), 0, stream>>>(logits, hist0, hist1, hist2);
  kGatherL4<<<dim3(NBLK+NCHUNK, NIMG), dim3(256), 0, stream>>>(logits, hist0, hist1, hist2,
                                                               cand, gcnt, label, pi, mu, sigma,
                                                               anchors, gt, deltas, cpos, cneg, acc);
  kRank<<<dim3(NIMG), dim3(1024), 0, stream>>>(cand, gcnt, epis, alea, deltas, anchors, tb, tu, ts);
  kD_mask<<<dim3(32, NIMG), dim3(1024), 0, stream>>>(tb, maskLT, scnt, slist);
  kEF_nms<<<dim3(NIMG), dim3(1024), 0, stream>>>(maskLT, scnt, slist, tb, tu, ts, acc, out);
}

// Round 19
// 239.250 us; speedup vs baseline: 1.3384x; 1.0862x over previous
//
#include <hip/hip_runtime.h>
#include <cstdint>
#include <cstddef>

typedef unsigned long long u64;
typedef unsigned int u32;
typedef unsigned short u16;
typedef unsigned char u8;

#define R_ANCH 96000
#define R4     24000 // R_ANCH / 4 (float4 units)
#define NIMG   8
#define KMIX   5
#define PRE    2000
#define POST   1000
#define NGT    32
#define NCHUNK 375   // R_ANCH / 256 (label/loss kernels)
#define ACHUNK 94    // ceil(R4 / 256) — kA main blocks (4 anchors/thread)
#define NBLK   48    // blocks per image for parallel scan kernels
#define MROW   2048  // maskLT row stride (padded PRE)
#define SCAP   16    // per-row suppressor-list capacity (overflow -> dense path)
#define BIG_TH 64    // kRank: bins larger than this get level-1 split
#define CAP_BIN 6144 // refinement trigger: crossing-bin count above this -> refine
#define CAND_CAP 8192// global/LDS candidate capacity (PRE-1 + CAP_BIN = 8143 max)
#define GC_STRIDE 16 // gcnt padding: 64 B per image
#define RPART  32    // kRank partitions per image (replicated-state parallelism)

#define IMG_SZ        1280.0f
#define NMS_T         0.7f
#define SCALE_CLAMP_F 4.135166556742356f
#define HALF_L2PI     0.9189385332046727f

__device__ __forceinline__ u64 make_key(float s, int r) {
  u32 u = __float_as_uint(s);
  u = (u & 0x80000000u) ? ~u : (u | 0x80000000u);
  return ((u64)u << 32) | (u64)(0xFFFFFFFFu - (u32)r);
}

__device__ __forceinline__ float dec_score(u64 key) {
  u32 o = (u32)(key >> 32);
  u32 bits = (o & 0x80000000u) ? (o ^ 0x80000000u) : ~o;
  return __uint_as_float(bits);
}

// EXACT-PATH IoU (NMS only): must match reference bit-for-bit since NMS
// decisions select whole boxes. Label-path code uses division-free
// cross-multiplied compares (loss-only, high tolerance).
__device__ __forceinline__ float iou_pair(float a0,float a1,float a2,float a3,
                                          float b0,float b1,float b2,float b3) {
#pragma clang fp contract(off)
  float areaA = (a2-a0)*(a3-a1);
  float areaB = (b2-b0)*(b3-b1);
  float lx=fmaxf(a0,b0), ly=fmaxf(a1,b1);
  float rx=fminf(a2,b2), ry=fminf(a3,b3);
  float iw=fmaxf(rx-lx,0.0f), ih=fmaxf(ry-ly,0.0f);
  float inter=iw*ih;
  return inter / fmaxf(areaA+areaB-inter, 1e-9f);
}

// pick: from a 2048-bin histogram (bin d high = higher keys), find the bin
// containing the k-th largest key. 256 threads. s_i >= 8 ints, s_u >= 3 u32.
__device__ __forceinline__ void pick2048(const u32* __restrict__ hist, int k,
                                         int* s_i, u32* s_u,
                                         int& d_out, int& k_out, u32& cnt_out) {
  int tid = threadIdx.x;
  int lane = tid & 63, w = tid >> 6;
  u32 h[8]; u32 ssum = 0;
#pragma unroll
  for (int i=0;i<8;++i){ h[i] = hist[2047 - (tid*8 + i)]; ssum += h[i]; }
  u32 incl = ssum;
  for (int off=1; off<64; off<<=1){
    u32 t = (u32)__shfl_up((int)incl, off, 64);
    if (lane >= off) incl += t;
  }
  if (lane==63) s_i[w] = (int)incl;
  __syncthreads();
  u32 base = 0;
  for (int ww=0; ww<w; ++ww) base += (u32)s_i[ww];
  u32 run = base + incl - ssum;              // exclusive prefix (descending keys)
#pragma unroll
  for (int i=0;i<8;++i){
    u32 nr = run + h[i];
    if (run < (u32)k && nr >= (u32)k){       // unique crossing thread
      s_u[0] = (u32)(2047 - (tid*8+i));
      s_u[1] = (u32)k - run;
      s_u[2] = h[i];
    }
    run = nr;
  }
  __syncthreads();
  d_out = (int)s_u[0]; k_out = (int)s_u[1]; cnt_out = s_u[2];
  __syncthreads();
}

// descending exclusive prefix over 2048 bins, 1024 threads (2 bins/thread).
// Caller must __syncthreads() before (h ready) and after (off ready).
__device__ __forceinline__ void scan2048_desc(const u32* __restrict__ h,
                                              u32* __restrict__ off,
                                              u32* __restrict__ wsum, int tid) {
  int b_hi = 2047 - 2*tid, b_lo = b_hi - 1;
  u32 h_hi = h[b_hi], h_lo = h[b_lo];
  u32 sum = h_hi + h_lo;
  u32 incl = sum;
  int lane = tid & 63, wv = tid >> 6;
  for (int o=1; o<64; o<<=1){
    u32 t = (u32)__shfl_up((int)incl, o, 64);
    if (lane >= o) incl += t;
  }
  if (lane==63) wsum[wv] = incl;
  __syncthreads();
  u32 base = 0;
  for (int w=0; w<wv; ++w) base += wsum[w];
  u32 excl = base + incl - sum;
  off[b_hi] = excl;
  off[b_lo] = excl + h_hi;
}

// ---------------- zero: contiguous workspace region -----------------------
__global__ void kZero(u32* z, int nwords) {
  for (int i = blockIdx.x*256 + threadIdx.x; i < nwords; i += gridDim.x*256)
    z[i] = 0u;
}

// ---------------- A: MDN moments + hist0 — float4 (4 anchors/thread) ------
// kA floor ~46-49 us across float4/launch-bounds/float2 variants —
// structural (retired). blocks [0, ACHUNK): main; [ACHUNK,+NBLK): L1 best-gt.
__global__ __launch_bounds__(256) void kA_mdn(
    const float* __restrict__ pi, const float* __restrict__ mu,
    const float* __restrict__ sigma, float* __restrict__ logits,
    float* __restrict__ epis, float* __restrict__ alea,
    u32* __restrict__ hist0,
    const float* __restrict__ anchors, const float* __restrict__ gt,
    int* __restrict__ best) {
  __shared__ u32 s_h[2048];
  __shared__ float s_gt[NGT*4];
  __shared__ float s_ga[NGT];
  __shared__ int s_best[NGT];
  int tid = threadIdx.x;
  int img = blockIdx.y;

  if (blockIdx.x >= ACHUNK) {
    // ---------------- fused L1 body (block-uniform branch) ----------------
    int bx = blockIdx.x - ACHUNK;
    if (tid < NGT*4) s_gt[tid] = gt[img*NGT*4 + tid];
    if (tid < NGT){
      const float* g4 = gt + img*NGT*4 + tid*4;
      s_ga[tid] = (g4[2]-g4[0])*(g4[3]-g4[1]);
      s_best[tid] = 0;
    }
    __syncthreads();
    float4 an[8]; float aA[8];
#pragma unroll
    for (int q=0; q<8; ++q){
      int r = bx*256 + tid + q*(NBLK*256);
      an[q] = (r < R_ANCH) ? ((const float4*)anchors)[r]
                           : make_float4(0.f,0.f,0.f,0.f);   // IoU=0, inert
      aA[q] = (an[q].z-an[q].x)*(an[q].w-an[q].y);
    }
    float vmax[NGT];
#pragma unroll 2
    for (int g=0; g<NGT; ++g){
      float g0=s_gt[g*4], g1=s_gt[g*4+1], g2=s_gt[g*4+2], g3=s_gt[g*4+3];
      float ga=s_ga[g];
      float bi=0.0f, bu=1.0f;               // v=0 baseline
#pragma unroll
      for (int q=0; q<8; ++q){
        float lx=fmaxf(g0,an[q].x), ly=fmaxf(g1,an[q].y);
        float rx=fminf(g2,an[q].z), ry=fminf(g3,an[q].w);
        float iw=fmaxf(rx-lx,0.0f), ih=fmaxf(ry-ly,0.0f);
        float inter=iw*ih;
        float uni=fmaxf(ga+aA[q]-inter,1e-9f);
        if (inter*bu > bi*uni){ bi=inter; bu=uni; }
      }
      vmax[g] = bi/bu;
    }
    int lane = tid & 63;
#pragma unroll
    for (int g=0; g<NGT; ++g){
      float v = vmax[g];
      v = fmaxf(v, __shfl_xor(v, 1, 64));
      v = fmaxf(v, __shfl_xor(v, 2, 64));
      v = fmaxf(v, __shfl_xor(v, 4, 64));
      v = fmaxf(v, __shfl_xor(v, 8, 64));
      v = fmaxf(v, __shfl_xor(v,16, 64));
      v = fmaxf(v, __shfl_xor(v,32, 64));
      if (lane==0 && v > 0.0f) atomicMax(&s_best[g], __float_as_int(v));
    }
    __syncthreads();
    if (tid < NGT) atomicMax(&best[img*NGT + tid], s_best[tid]);
    return;
  }

  // ---------------- main MDN body: 4 anchors per thread ----------------
  int r4 = blockIdx.x*256 + tid;             // float4 index within image
  bool act = (r4 < R4);
  for (int b=tid; b<2048; b+=256) s_h[b]=0u;
  float4 lg4, ep4, al4;
  u64 keys[4];
  if (act){
    const float4* pi4 = (const float4*)pi;
    const float4* mu4 = (const float4*)mu;
    const float4* sg4 = (const float4*)sigma;
    size_t base = (size_t)img*KMIX*R4 + r4;
    float4 p4[KMIX], m4[KMIX], s4[KMIX];
#pragma unroll
    for (int k=0;k<KMIX;k++){
      p4[k]=pi4[base+(size_t)k*R4];
      m4[k]=mu4[base+(size_t)k*R4];
      s4[k]=sg4[base+(size_t)k*R4];
    }
    float lg_[4], ep_[4], al_[4];
#pragma unroll
    for (int j=0;j<4;++j){
      float p[KMIX], m[KMIX], s[KMIX];
#pragma unroll
      for (int k=0;k<KMIX;k++){
        p[k] = (&p4[k].x)[j];
        m[k] = (&m4[k].x)[j];
        s[k] = (&s4[k].x)[j];
      }
      float mx = p[0];
#pragma unroll
      for (int k=1;k<KMIX;k++) mx = fmaxf(mx,p[k]);
      float e[KMIX]; float sum = 0.0f;
#pragma unroll
      for (int k=0;k<KMIX;k++){ e[k]=expf(p[k]-mx); sum += e[k]; }
      float w[KMIX]; float lg = 0.0f;
#pragma unroll
      for (int k=0;k<KMIX;k++){ w[k]=e[k]/sum; lg += w[k]*m[k]; }
      float ep = 0.0f, al = 0.0f;
#pragma unroll
      for (int k=0;k<KMIX;k++){ float d=m[k]-lg; ep += w[k]*d*d; al += w[k]*s[k]*s[k]; }
      lg_[j]=lg; ep_[j]=ep; al_[j]=al;
      keys[j] = make_key(lg, r4*4 + j);
    }
    lg4 = make_float4(lg_[0],lg_[1],lg_[2],lg_[3]);
    ep4 = make_float4(ep_[0],ep_[1],ep_[2],ep_[3]);
    al4 = make_float4(al_[0],al_[1],al_[2],al_[3]);
    size_t o4 = (size_t)img*R4 + r4;
    ((float4*)logits)[o4] = lg4;
    ((float4*)epis)[o4]   = ep4;
    ((float4*)alea)[o4]   = al4;
  }
  __syncthreads();                           // s_h zero complete
  if (act){
#pragma unroll
    for (int j=0;j<4;++j)
      atomicAdd(&s_h[(u32)(keys[j]>>53)], 1u);
  }
  __syncthreads();
  for (int b=tid; b<2048; b+=256){ u32 v=s_h[b]; if(v) atomicAdd(&hist0[img*2048+b], v); }
}

// ---------------- P1+L2: refine hist (rare) ++ labels ride along ----------
// blocks [0, NBLK): P1 body (early-exit ~2us in common case — idle CUs);
// blocks [NBLK, NBLK+NCHUNK): kL2 label body (independent of selection
// chain; needs only kA's `best`). label is a SEPARATE buffer (not aliasing
// logits) since logits is still read by kP2/kGather afterwards.
__global__ __launch_bounds__(256) void kP1L2(const float* __restrict__ logits,
    const u32* __restrict__ hist0, u32* __restrict__ hist1,
    const float* __restrict__ anchors, const float* __restrict__ gt,
    const int* __restrict__ best,
    signed char* __restrict__ label, int* __restrict__ cpos, int* __restrict__ cneg) {
  int img = blockIdx.y, tid = threadIdx.x;

  if (blockIdx.x >= NBLK) {
    // ---------------- L2 label body (verbatim kL2_label) ----------------
    __shared__ float s_gt[NGT*4];
    __shared__ float s_ga[NGT];
    __shared__ float s_bg[NGT];
    __shared__ int s_w[8];
    int bx = blockIdx.x - NBLK;
    int r = bx*256 + tid;
    if (tid < NGT*4) s_gt[tid] = gt[img*NGT*4 + tid];
    if (tid < NGT){
      const float* g4 = gt + img*NGT*4 + tid*4;
      s_ga[tid] = (g4[2]-g4[0])*(g4[3]-g4[1]);
      s_bg[tid] = __int_as_float(best[img*NGT + tid]);
    }
    __syncthreads();
    float4 a = ((const float4*)anchors)[r];
    float aA = (a.z-a.x)*(a.w-a.y);
    float bi=-1.0f, bu=1.0f; bool lq = false;
#pragma unroll 4
    for (int g=0; g<NGT; ++g){
      float g0=s_gt[g*4], g1=s_gt[g*4+1], g2=s_gt[g*4+2], g3=s_gt[g*4+3];
      float lx=fmaxf(g0,a.x), ly=fmaxf(g1,a.y);
      float rx=fminf(g2,a.z), ry=fminf(g3,a.w);
      float iw=fmaxf(rx-lx,0.0f), ih=fmaxf(ry-ly,0.0f);
      float inter=iw*ih;
      float uni = fmaxf(s_ga[g] + aA - inter, 1e-9f);
      if (inter*bu > bi*uni){ bi=inter; bu=uni; }
      float bg = s_bg[g];
      lq = lq || ((inter >= (bg - 1e-7f)*uni) && (bg > 0.0f));
    }
    float vbest = bi/bu;
    int lab = lq ? 1 : (vbest >= 0.7f ? 1 : (vbest >= 0.3f ? -1 : 0));
    label[(size_t)img*R_ANCH + r] = (signed char)lab;
    u64 bp = __ballot(lab==1), bn = __ballot(lab==0);
    int wid = tid>>6, lane = tid&63;
    if (lane==0){ s_w[wid*2]=__popcll(bp); s_w[wid*2+1]=__popcll(bn); }
    __syncthreads();
    if (tid==0){
      cpos[img*NCHUNK + bx] = s_w[0]+s_w[2]+s_w[4]+s_w[6];
      cneg[img*NCHUNK + bx] = s_w[1]+s_w[3]+s_w[5]+s_w[7];
    }
    return;
  }

  // ---------------- P1 body (verbatim) ----------------
  __shared__ u32 s_h[2048];
  __shared__ int s_i[8]; __shared__ u32 s_u[3];
  int d0,k0; u32 c0;
  pick2048(hist0 + img*2048, PRE, s_i, s_u, d0,k0,c0);
  if (c0 <= CAP_BIN) return;                 // block-uniform (common case)
  for (int b=tid; b<2048; b+=256) s_h[b]=0u;
  __syncthreads();
  const float* sc = logits + (size_t)img*R_ANCH;
  for (int r = blockIdx.x*256 + tid; r < R_ANCH; r += NBLK*256){
    u64 key = make_key(sc[r], r);
    if ((int)(key>>53) == d0) atomicAdd(&s_h[(u32)(key>>42)&2047u], 1u);
  }
  __syncthreads();
  for (int b=tid; b<2048; b+=256){ u32 v=s_h[b]; if(v) atomicAdd(&hist1[img*2048+b], v); }
}

// ---------------- P2: refine level-2 histogram (essentially never) --------
__global__ __launch_bounds__(256) void kP2(const float* __restrict__ logits,
                                           const u32* __restrict__ hist0,
                                           const u32* __restrict__ hist1,
                                           u32* __restrict__ hist2) {
  __shared__ u32 s_h[2048];
  __shared__ int s_i[8]; __shared__ u32 s_u[3];
  int img = blockIdx.y, tid = threadIdx.x;
  int d0,k0; u32 c0;
  pick2048(hist0 + img*2048, PRE, s_i, s_u, d0,k0,c0);
  if (c0 <= CAP_BIN) return;
  int d1,k1; u32 c1;
  pick2048(hist1 + img*2048, k0, s_i, s_u, d1,k1,c1);
  if (c1 <= CAP_BIN) return;
  u64 p1 = ((u64)d0<<11) | (u64)d1;
  for (int b=tid; b<2048; b+=256) s_h[b]=0u;
  __syncthreads();
  const float* sc = logits + (size_t)img*R_ANCH;
  for (int r = blockIdx.x*256 + tid; r < R_ANCH; r += NBLK*256){
    u64 key = make_key(sc[r], r);
    if ((key>>42) == p1) atomicAdd(&s_h[(u32)(key>>31)&2047u], 1u);
  }
  __syncthreads();
  for (int b=tid; b<2048; b+=256){ u32 v=s_h[b]; if(v) atomicAdd(&hist2[img*2048+b], v); }
}

// ---------------- G+L4: gather candidates ++ loss accumulation ------------
// blocks [0, NBLK): gather body; [NBLK, NBLK+NCHUNK): kL4 body. L4 needs
// label/cpos/cneg from the P1L2 dispatch (2 boundaries earlier — safe) and
// fills CU bubbles during the gather scan. acc is read only by kEF (last).
__global__ __launch_bounds__(256) void kGatherL4(const float* __restrict__ logits,
    const u32* __restrict__ hist0, const u32* __restrict__ hist1,
    const u32* __restrict__ hist2, u64* __restrict__ cand, u32* __restrict__ gcnt,
    const signed char* __restrict__ label,
    const float* __restrict__ pi, const float* __restrict__ mu,
    const float* __restrict__ sigma, const float* __restrict__ anchors,
    const float* __restrict__ gt, const float* __restrict__ deltas,
    const int* __restrict__ cpos, const int* __restrict__ cneg,
    float* __restrict__ acc) {
  int img = blockIdx.y, tid = threadIdx.x;

  if (blockIdx.x >= NBLK) {
    // ---------------- L4 body (verbatim kL4_accum) ----------------
    __shared__ int s_wp[4], s_wn[4];
    __shared__ int s_r[12];
    __shared__ float s_red[8];
    __shared__ float s_gt[NGT*4];
    int bx = blockIdx.x - NBLK;
    int lane = tid & 63, wid = tid >> 6;
    if (tid < NGT*4) s_gt[tid] = gt[img*NGT*4 + tid];
    int vp=0, vn=0, tp=0;
    for (int k=tid; k<NCHUNK; k+=256){
      int cp = cpos[img*NCHUNK + k];
      int cn = cneg[img*NCHUNK + k];
      tp += cp;
      if (k < bx){ vp += cp; vn += cn; }
    }
    for (int of=32; of>0; of>>=1){
      vp += __shfl_down(vp, of, 64);
      vn += __shfl_down(vn, of, 64);
      tp += __shfl_down(tp, of, 64);
    }
    if (lane==0){ s_r[wid]=vp; s_r[4+wid]=vn; s_r[8+wid]=tp; }
    __syncthreads();                         // also covers s_gt
    int pre_p = s_r[0]+s_r[1]+s_r[2]+s_r[3];
    int pre_n = s_r[4]+s_r[5]+s_r[6]+s_r[7];
    int totp  = s_r[8]+s_r[9]+s_r[10]+s_r[11];
    int np = totp < 128 ? totp : 128;
    int nn = 256 - np;
    int r = bx*256 + tid;
    size_t o = (size_t)img*R_ANCH + r;
    int lab = label[o];
    bool pos = (lab==1), neg = (lab==0);
    u64 bp = __ballot(pos), bn = __ballot(neg);
    if (lane==0){ s_wp[wid]=__popcll(bp); s_wn[wid]=__popcll(bn); }
    __syncthreads();
    for (int w=0; w<wid; ++w){ pre_p += s_wp[w]; pre_n += s_wn[w]; }
    u64 lm = (1ull<<lane) - 1ull;
    pre_p += __popcll(bp & lm);
    pre_n += __popcll(bn & lm);
    bool kp = pos && (pre_p < np);
    bool kn = neg && (pre_n < nn);
    float c_cls = 0.0f, c_loc = 0.0f;
    if (kp || kn){
      float4 a = ((const float4*)anchors)[r];
      float aA = (a.z-a.x)*(a.w-a.y);
      float bi = -1.0f, bu = 1.0f; int idx = 0;
#pragma unroll 4
      for (int g=0; g<NGT; ++g){
        float g0=s_gt[g*4], g1=s_gt[g*4+1], g2=s_gt[g*4+2], g3=s_gt[g*4+3];
        float ga=(g2-g0)*(g3-g1);
        float lx=fmaxf(g0,a.x), ly=fmaxf(g1,a.y);
        float rx=fminf(g2,a.z), ry=fminf(g3,a.w);
        float iw=fmaxf(rx-lx,0.0f), ih=fmaxf(ry-ly,0.0f);
        float inter=iw*ih;
        float uni = fmaxf(ga + aA - inter, 1e-9f);
        if (inter*bu > bi*uni){ bi=inter; bu=uni; idx=g; }
      }
      float vbest = bi/bu;
      size_t base = (size_t)img*KMIX*R_ANCH + r;
      float p[KMIX], m[KMIX], s[KMIX];
#pragma unroll
      for (int k=0;k<KMIX;k++){
        p[k]=pi[base+(size_t)k*R_ANCH];
        m[k]=mu[base+(size_t)k*R_ANCH];
        s[k]=sigma[base+(size_t)k*R_ANCH];
      }
      float mx = p[0];
#pragma unroll
      for (int k=1;k<KMIX;k++) mx = fmaxf(mx,p[k]);
      float e[KMIX]; float sum = 0.0f;
#pragma unroll
      for (int k=0;k<KMIX;k++){ e[k]=expf(p[k]-mx); sum += e[k]; }
      float lsum = logf(sum);
      float t_ = fminf(fmaxf(vbest, 0.0f), 1.0f);
      float comp[KMIX];
#pragma unroll
      for (int k=0;k<KMIX;k++){
        float z = (t_ - m[k]) / s[k];
        comp[k] = (p[k]-mx-lsum) - 0.5f*z*z - logf(s[k]) - HALF_L2PI;
      }
      float cm = comp[0];
#pragma unroll
      for (int k=1;k<KMIX;k++) cm = fmaxf(cm, comp[k]);
      float se = 0.0f;
#pragma unroll
      for (int k=0;k<KMIX;k++) se += expf(comp[k]-cm);
      c_cls = -(cm + logf(se));
      if (kp){
        const float* gb = &s_gt[idx*4];
        float sw = a.z-a.x, sh = a.w-a.y;
        float scx = a.x+0.5f*sw, scy = a.y+0.5f*sh;
        float tw = gb[2]-gb[0], th = gb[3]-gb[1];
        float tcx = gb[0]+0.5f*tw, tcy = gb[1]+0.5f*th;
        float4 d = ((const float4*)deltas)[(size_t)img*R_ANCH + r];
        c_loc = fabsf(d.x-(tcx-scx)/sw) + fabsf(d.y-(tcy-scy)/sh)
              + fabsf(d.z-logf(tw/sw)) + fabsf(d.w-logf(th/sh));
      }
    }
    for (int of=32; of>0; of>>=1){
      c_cls += __shfl_down(c_cls, of, 64);
      c_loc += __shfl_down(c_loc, of, 64);
    }
    if (lane==0){ s_red[wid]=c_cls; s_red[4+wid]=c_loc; }
    __syncthreads();
    if (tid==0){
      float a = s_red[0]+s_red[1]+s_red[2]+s_red[3];
      float b = s_red[4]+s_red[5]+s_red[6]+s_red[7];
      if (a != 0.0f) atomicAdd(&acc[0], a);
      if (b != 0.0f) atomicAdd(&acc[1], b);
    }
    return;
  }

  // ---------------- gather body (verbatim kGather) ----------------
  __shared__ int s_i[8]; __shared__ u32 s_u[3];
  __shared__ u64 s_cand[2048];               // 16 KB staging (block take <= 2048)
  __shared__ u32 s_cnt, s_base;
  if (tid==0) s_cnt = 0u;
  int d,kk; u32 c;
  pick2048(hist0 + img*2048, PRE, s_i, s_u, d,kk,c);   // has syncthreads
  u64 p = (u64)d; int L = 0;
  if (c > CAP_BIN){
    pick2048(hist1 + img*2048, kk, s_i, s_u, d,kk,c);
    p = (p<<11)|(u64)d; L = 1;
    if (c > CAP_BIN){
      pick2048(hist2 + img*2048, kk, s_i, s_u, d,kk,c);
      p = (p<<11)|(u64)d; L = 2;
    }
  }
  u64 T = p << (64 - 11*(L+1));              // total candidates <= 8143
  const float* sc = logits + (size_t)img*R_ANCH;
  int lane = tid & 63;
  for (int r = blockIdx.x*256 + tid; r < R_ANCH; r += NBLK*256){
    u64 key = make_key(sc[r], r);
    bool take = (key >= T);
    u64 b = __ballot(take);
    if (b){
      u32 base = 0;
      if (lane==0) base = atomicAdd(&s_cnt, (u32)__popcll(b));   // LDS atomic
      base = (u32)__shfl((int)base, 0, 64);
      if (take){
        u32 pos = base + (u32)__popcll(b & ((1ull<<lane)-1ull));
        if (pos < 2048u) s_cand[pos] = key;
        else {                               // correctness net (block take > 2048)
          u32 gp = atomicAdd(&gcnt[img*GC_STRIDE], 1u);
          if (gp < CAND_CAP) cand[(size_t)img*CAND_CAP + gp] = key;
        }
      }
    }
  }
  __syncthreads();
  u32 n = s_cnt < 2048u ? s_cnt : 2048u;
  if (tid==0) s_base = atomicAdd(&gcnt[img*GC_STRIDE], n);  // 1 atomic/block
  __syncthreads();
  u32 gb = s_base;
  for (u32 i=tid; i<n; i+=256)
    cand[(size_t)img*CAND_CAP + gb + i] = s_cand[i];
}

// ---------------- R: hierarchical exact bucket-rank + epilogue ------------
// R18 post-mortem: kRank was 45.6 us at 1% occupancy (8 blocks total).
// Now RPART blocks/image with REPLICATED state: every block loads all keys
// and recomputes hist/scan/scatter (deterministic SET per bin — rank =
// bin-base + count(key > mine) is scatter-order-invariant), then processes
// only its contiguous 1/RPART slice of candidates and big bins with
// (B % RPART == part) — partition by bin id, not collection order.
__global__ __launch_bounds__(1024) void kRank(
    const u64* __restrict__ cand, const u32* __restrict__ gcnt,
    const float* __restrict__ epis, const float* __restrict__ alea,
    const float* __restrict__ deltas, const float* __restrict__ anchors,
    float* __restrict__ tb, float* __restrict__ tu, float* __restrict__ ts) {
  __shared__ u64 s_key[CAND_CAP];            // 64 KB
  __shared__ u16 s_idx0[CAND_CAP];           // 16 KB
  __shared__ u16 s_idx1[CAND_CAP];           // 16 KB (per big bin, reused)
  __shared__ u32 s_h0[2048];                 // 8 KB
  __shared__ u32 s_off0[2048];               // 8 KB (excl; scatter makes base+size)
  __shared__ u32 s_h1[2048];                 // 8 KB
  __shared__ u32 s_off1[2048];               // 8 KB
  __shared__ u32 s_wsum[16];
  __shared__ u32 s_nbig;
  __shared__ u16 s_big[128];
  int tid = threadIdx.x, part = blockIdx.x, img = blockIdx.y;
  u32 cnt = gcnt[img*GC_STRIDE];
  if (cnt > (u32)CAND_CAP) cnt = CAND_CAP;
  const u64* cp = cand + (size_t)img*CAND_CAP;
  for (int i=tid; i<CAND_CAP; i+=1024) s_key[i] = (i < (int)cnt) ? cp[i] : 0ull;
  for (int b=tid; b<2048; b+=1024){ s_h0[b] = 0u; }
  if (tid==0) s_nbig = 0u;
  __syncthreads();
  for (int i=tid; i<(int)cnt; i+=1024)
    atomicAdd(&s_h0[(u32)(s_key[i]>>53)], 1u);
  __syncthreads();
  scan2048_desc(s_h0, s_off0, s_wsum, tid);
  __syncthreads();
  // collect big bins for THIS partition (by bin id — deterministic)
  for (int b=tid; b<2048; b+=1024){
    u32 sz = s_h0[b];
    if (sz > BIG_TH && s_off0[b] < PRE && (b % RPART) == part){
      u32 q = atomicAdd(&s_nbig, 1u);
      if (q < 128u) s_big[q] = (u16)b;
    }
  }
  __syncthreads();                           // collect/scatter ordering
  // scatter candidates into digit0-bucket order (replicated, set-identical)
  for (int i=tid; i<(int)cnt; i+=1024){
    u32 d = (u32)(s_key[i]>>53);
    u32 slot = atomicAdd(&s_off0[d], 1u);    // post: s_off0[d] = base + size
    s_idx0[slot] = (u16)i;
  }
  __syncthreads();
  // epilogue writer
  auto emit = [&](u64 my, u32 rank){
    if (rank < PRE){
      int p = (int)rank;
      u32 idx = 0xFFFFFFFFu - (u32)(my & 0xFFFFFFFFull);
      ts[img*PRE + p] = dec_score(my);
      float4 a = ((const float4*)anchors)[idx];
      float4 dd = ((const float4*)deltas)[(size_t)img*R_ANCH + idx];
      float w = a.z - a.x, h = a.w - a.y;
      float cx = a.x + 0.5f*w, cy = a.y + 0.5f*h;
      float dw = fminf(dd.z, SCALE_CLAMP_F), dh = fminf(dd.w, SCALE_CLAMP_F);
      float pcx = dd.x*w + cx, pcy = dd.y*h + cy;
      float pw = expf(dw)*w, ph = expf(dh)*h;
      float x0 = fminf(fmaxf(pcx - 0.5f*pw, 0.0f), IMG_SZ);
      float y0 = fminf(fmaxf(pcy - 0.5f*ph, 0.0f), IMG_SZ);
      float x1 = fminf(fmaxf(pcx + 0.5f*pw, 0.0f), IMG_SZ);
      float y1 = fminf(fmaxf(pcy + 0.5f*ph, 0.0f), IMG_SZ);
      ((float4*)tb)[(size_t)img*PRE + p] = make_float4(x0,y0,x1,y1);
      size_t o = (size_t)img*R_ANCH + idx;
      ((float2*)tu)[(size_t)img*PRE + p] = make_float2(epis[o], alea[o]);
    }
  };
  // small bins: this partition's contiguous candidate slice only
  {
    int lo = (int)(((long long)cnt * part) / RPART);
    int hi = (int)(((long long)cnt * (part+1)) / RPART);
    for (int i=lo+tid; i<hi; i+=1024){
      u64 my = s_key[i];
      u32 d = (u32)(my>>53);
      u32 size = s_h0[d];
      if (size > BIG_TH) continue;           // handled by the bin's partition
      u32 bs = s_off0[d] - size;
      if (bs >= PRE) continue;               // cannot produce rank < PRE
      u32 rank = bs;
      for (u32 q=bs; q<bs+size; ++q)
        rank += (s_key[s_idx0[q]] > my) ? 1u : 0u;
      emit(my, rank);
    }
  }
  __syncthreads();
  u32 nbig = s_nbig < 128u ? s_nbig : 128u;
  for (u32 bb=0; bb<nbig; ++bb){             // block-uniform sequential loop
    u32 B = s_big[bb];
    u32 size = s_h0[B];
    u32 base0 = s_off0[B] - size;
    for (int b=tid; b<2048; b+=1024) s_h1[b] = 0u;
    __syncthreads();
    for (u32 q=tid; q<size; q+=1024){
      u64 k = s_key[s_idx0[base0+q]];
      atomicAdd(&s_h1[(u32)(k>>42)&2047u], 1u);
    }
    __syncthreads();
    scan2048_desc(s_h1, s_off1, s_wsum, tid);
    __syncthreads();
    for (u32 q=tid; q<size; q+=1024){
      u16 ci = s_idx0[base0+q];
      u64 k = s_key[ci];
      u32 slot = atomicAdd(&s_off1[(u32)(k>>42)&2047u], 1u);
      s_idx1[slot] = ci;
    }
    __syncthreads();
    for (u32 q=tid; q<size; q+=1024){
      u16 ci = s_idx1[q];
      u64 my = s_key[ci];
      u32 d1 = (u32)(my>>42)&2047u;
      u32 ssz = s_h1[d1];
      u32 sbs = s_off1[d1] - ssz;            // sub-bin base (within bin)
      u32 rank = base0 + sbs;
      for (u32 t2=sbs; t2<sbs+ssz; ++t2)
        rank += (s_key[s_idx1[t2]] > my) ? 1u : 0u;
      emit(my, rank);
    }
    __syncthreads();                         // s_h1/s_off1/s_idx1 reuse
  }
}

// ---------------- D: masks + sparse suppressor lists (EXACT IoU) ----------
__global__ __launch_bounds__(1024) void kD_mask(const float* __restrict__ tb,
                                                u64* __restrict__ maskLT,
                                                u32* __restrict__ scnt,
                                                u16* __restrict__ slist) {
  __shared__ float4 s_tile[64];
  int tid = threadIdx.x;
  int a = blockIdx.x, img = blockIdx.y;
  const float4* tbi = (const float4*)tb + (size_t)img*PRE;
  if (tid < 64){
    int i = a*64 + tid;
    s_tile[tid] = (i < PRE) ? tbi[i] : make_float4(0.f,0.f,0.f,0.f);
  }
  __syncthreads();
  u64* outp = maskLT + ((size_t)img*32 + a)*MROW;
  u32* cnts = scnt + (size_t)img*2048;
  u16* lst  = slist + (size_t)img*2048*SCAP;
  int bmax = min(64, PRE - a*64);
  for (int j = a*64 + tid; j < MROW; j += 1024){
    u64 m = 0ull;
    if (j < PRE){
      float4 B = tbi[j];
      int blim = min(bmax, j - a*64);        // only b with a*64+b < j
      for (int b = 0; b < blim; ++b){
        float4 A = s_tile[b];
        float v = iou_pair(A.x,A.y,A.z,A.w, B.x,B.y,B.z,B.w);
        m |= (u64)(v > NMS_T) << b;
      }
    }
    outp[j] = m;
    u64 mm = m;
    while (mm){
      int b = __builtin_ctzll(mm); mm &= mm - 1ull;
      u32 slot = atomicAdd(&cnts[j], 1u);
      if (slot < SCAP) lst[(size_t)j*SCAP + slot] = (u16)(a*64 + b);
    }
  }
}

// ---------------- EF: greedy NMS fixpoint + final compaction + losses -----
__global__ __launch_bounds__(1024) void kEF_nms(const u64* __restrict__ maskLT,
    const u32* __restrict__ scnt, const u16* __restrict__ slist,
    const float* __restrict__ tb, const float* __restrict__ tu,
    const float* __restrict__ ts, const float* __restrict__ acc,
    float* __restrict__ out) {
  __shared__ u64 s_list64[2048*SCAP/4];      // 64 KB staged lists
  __shared__ u16 s_cnt[2048];                // 4 KB
  __shared__ u8  kbuf[2][2048];              // 4 KB
  __shared__ u64 s_kw[32];
  __shared__ int s_change, s_ovf;
  __shared__ int s_wk[16], s_wn[16];
  __shared__ int s_kc, s_runk, s_runn;
  int img = blockIdx.x, tid = threadIdx.x;
  int lane = tid & 63, wid = tid >> 6;
  const u64* gl = (const u64*)(slist + (size_t)img*2048*SCAP);
  for (int i=tid; i<2048*SCAP/4; i+=1024) s_list64[i] = gl[i];
  const u32* gc = scnt + (size_t)img*2048;
  for (int i=tid; i<2048; i+=1024) s_cnt[i] = (u16)gc[i];
  if (tid==0){ s_change = 0; s_ovf = 0; }
  __syncthreads();
  bool myovf = false;
#pragma unroll
  for (int q=0; q<2; ++q){
    int j = tid + q*1024;
    if (s_cnt[j] > SCAP) myovf = true;
    kbuf[0][j] = (j < PRE) ? 1 : 0;
  }
  if (myovf) s_ovf = 1;                      // benign race
  __syncthreads();
  const u64* MT = maskLT + (size_t)img*32*MROW;
  int cur = 0;
  for (int iter=0; iter<2048; ++iter){
    bool ovf = (s_ovf != 0);                 // stable after init barrier
    if (ovf && tid < 32){
      u64 w = 0ull;
      for (int b=0; b<64; ++b) w |= (u64)(kbuf[cur][tid*64+b] & 1) << b;
      s_kw[tid] = w;
    }
    __syncthreads();                         // A: s_change reset + kw visible
    bool changed = false;
#pragma unroll
    for (int q=0; q<2; ++q){
      int j = tid + q*1024;
      u8 old = kbuf[cur][j];
      u8 nk = (j < PRE) ? 1 : 0;
      if (nk){
        int cnt = s_cnt[j];
        if (cnt <= SCAP){
          const u16* lp = (const u16*)&s_list64[j*(SCAP/4)];
          for (int i=0; i<cnt; ++i){
            if (kbuf[cur][lp[i]]){ nk = 0; break; }
          }
        } else {
          int amax = j >> 6;
          for (int a=0; a<=amax; ++a){
            if (MT[(size_t)a*MROW + j] & s_kw[a]){ nk = 0; break; }
          }
        }
      }
      kbuf[1-cur][j] = nk;
      changed |= (nk != old);
    }
    if (changed) s_change = 1;
    __syncthreads();                         // B: all writes done
    int ch = s_change;
    __syncthreads();                         // C: all have read ch
    if (tid==0) s_change = 0;                // reset (visible by next A)
    if (!ch) break;                          // uniform
    cur ^= 1;
  }
  // ---- compaction (old kF), keep bits live in kbuf[cur] ----
  __syncthreads();
  const float4* tbi = (const float4*)tb + (size_t)img*PRE;
  const float NEG_INF = __uint_as_float(0xff800000u);
  u8* kf = kbuf[1-cur];                      // free buffer: keep&valid flags
#pragma unroll
  for (int cch=0; cch<2; ++cch){
    int pp = cch*1024 + tid;
    bool kp = false;
    if (pp < PRE && kbuf[cur][pp]){
      float4 b = tbi[pp];
      kp = (b.z > b.x) && (b.w > b.y);
    }
    kf[pp] = kp ? 1 : 0;
  }
  __syncthreads();
  {
    int cc = (int)kf[tid] + (int)kf[1024 + tid];
    for (int of=32; of>0; of>>=1) cc += __shfl_down(cc, of, 64);
    if (lane==0) s_wk[wid] = cc;
  }
  __syncthreads();
  if (tid==0){
    int t=0; for (int w=0; w<16; ++w) t += s_wk[w];
    s_kc = t; s_runk = 0; s_runn = 0;
  }
  __syncthreads();
  int kc = s_kc;
#pragma unroll
  for (int cch=0; cch<2; ++cch){
    int pp = cch*1024 + tid;
    bool kp = kf[pp] != 0;
    u64 bk = __ballot(kp), bn = __ballot(!kp);
    if (lane==0){ s_wk[wid]=__popcll(bk); s_wn[wid]=__popcll(bn); }
    __syncthreads();
    int pk = s_runk, pn = s_runn;
    for (int w=0; w<wid; ++w){ pk += s_wk[w]; pn += s_wn[w]; }
    u64 lm = (1ull<<lane) - 1ull;
    pk += __popcll(bk & lm);
    pn += __popcll(bn & lm);
    int slot = kp ? pk : (kc + pn);
    if (slot < POST && pp < PRE){
      ((float4*)out)[img*POST + slot] = tbi[pp];
      out[32000 + img*POST + slot] = kp ? ts[img*PRE + pp] : NEG_INF;
      ((float2*)(out + 40000))[img*POST + slot] = ((const float2*)tu)[(size_t)img*PRE + pp];
    }
    __syncthreads();
    if (tid==0){
      int tk=0, tn=0;
      for (int w=0; w<16; ++w){ tk += s_wk[w]; tn += s_wn[w]; }
      s_runk += tk; s_runn += tn;
    }
    __syncthreads();
  }
  if (img==0 && tid<2) out[56000+tid] = acc[tid] * (1.0f/2048.0f);
}

// ---------------- host-side launch ----------------------------------------
extern "C" void kernel_launch(void* const* d_in, const int* in_sizes, int n_in,
                              void* d_out, int out_size, void* d_ws, size_t ws_size,
                              hipStream_t stream) {
  const float* anchors = (const float*)d_in[0];
  const float* pi      = (const float*)d_in[1];
  const float* mu      = (const float*)d_in[2];
  const float* sigma   = (const float*)d_in[3];
  const float* deltas  = (const float*)d_in[4];
  const float* gt      = (const float*)d_in[5];
  float* out = (float*)d_out;

  char* ws = (char*)d_ws;
  size_t off = 0;
  auto alloc = [&](size_t bytes) -> void* {
    void* p = (void*)(ws + off);
    off += (bytes + 255) & ~(size_t)255;
    return p;
  };
  float* logits = (float*)alloc((size_t)NIMG*R_ANCH*4);
  float* epis   = (float*)alloc((size_t)NIMG*R_ANCH*4);
  float* alea   = (float*)alloc((size_t)NIMG*R_ANCH*4);
  signed char* label = (signed char*)alloc((size_t)NIMG*R_ANCH);  // own buffer (L2 runs early)
  float* tb     = (float*)alloc((size_t)NIMG*PRE*4*4);
  float* tu     = (float*)alloc((size_t)NIMG*PRE*2*4);
  float* ts     = (float*)alloc((size_t)NIMG*PRE*4);
  u64*   maskLT = (u64*)  alloc((size_t)NIMG*32*MROW*8);
  u16*   slist  = (u16*)  alloc((size_t)NIMG*2048*SCAP*2);
  u64*   cand   = (u64*)  alloc((size_t)NIMG*CAND_CAP*8);
  int*   cpos   = (int*)  alloc((size_t)NIMG*NCHUNK*4);
  int*   cneg   = (int*)  alloc((size_t)NIMG*NCHUNK*4);
  // ---- contiguous zero region ----
  size_t zstart = off;
  u32*   hist0  = (u32*)  alloc((size_t)NIMG*2048*4);
  u32*   hist1  = (u32*)  alloc((size_t)NIMG*2048*4);
  u32*   hist2  = (u32*)  alloc((size_t)NIMG*2048*4);
  u32*   gcnt   = (u32*)  alloc((size_t)NIMG*GC_STRIDE*4);
  int*   best   = (int*)  alloc((size_t)NIMG*NGT*4);
  u32*   scnt   = (u32*)  alloc((size_t)NIMG*2048*4);
  float* acc    = (float*)alloc(8);
  int zwords = (int)((off - zstart) / 4);

  kZero<<<dim3(64), dim3(256), 0, stream>>>((u32*)(ws + zstart), zwords);
  kA_mdn<<<dim3(ACHUNK+NBLK, NIMG), dim3(256), 0, stream>>>(pi, mu, sigma, logits, epis, alea,
                                                            hist0, anchors, gt, best);
  kP1L2<<<dim3(NBLK+NCHUNK, NIMG), dim3(256), 0, stream>>>(logits, hist0, hist1,
                                                           anchors, gt, best, label, cpos, cneg);
  kP2<<<dim3(NBLK, NIMG), dim3(256), 0, stream>>>(logits, hist0, hist1, hist2);
  kGatherL4<<<dim3(NBLK+NCHUNK, NIMG), dim3(256), 0, stream>>>(logits, hist0, hist1, hist2,
                                                               cand, gcnt, label, pi, mu, sigma,
                                                               anchors, gt, deltas, cpos, cneg, acc);
  kRank<<<dim3(RPART, NIMG), dim3(1024), 0, stream>>>(cand, gcnt, epis, alea, deltas, anchors, tb, tu, ts);
  kD_mask<<<dim3(32, NIMG), dim3(1024), 0, stream>>>(tb, maskLT, scnt, slist);
  kEF_nms<<<dim3(NIMG), dim3(1024), 0, stream>>>(maskLT, scnt, slist, tb, tu, ts, acc, out);
}